// Round 1
// 848.709 us; speedup vs baseline: 1.0636x; 1.0636x over previous
//
#include <hip/hip_runtime.h>
#include <cstdint>

#define HID 128
#define HC  130
#define NIO 128
#define DENSW 64     // dense ELL width (max in-degree ~45 for Poisson(16))
#define BCAP 768     // per-(xcd,bucket) capacity; mean ~256, 3x margin

typedef _Float16 f16;
typedef _Float16 f16x2 __attribute__((ext_vector_type(2)));
typedef _Float16 f16x8 __attribute__((ext_vector_type(8)));
typedef float    f32x4 __attribute__((ext_vector_type(4)));

__device__ __forceinline__ float sigm(float z) {
  return 1.0f / (1.0f + __expf(-z));
}

__device__ __forceinline__ int xcc_id() {
  int x;
  asm volatile("s_getreg_b32 %0, hwreg(HW_REG_XCC_ID)" : "=s"(x));
  return x & 7;
}

// ---------------- graph build: two-level binning ----------------
__global__ void zero_int_kernel(int* __restrict__ p, int n) {
  int i = blockIdx.x * blockDim.x + threadIdx.x;
  if (i < n) p[i] = 0;
}

// Pass 1: bin edges into per-(XCD, bucket=c>>7) append buffers. Cursor-append
// fills 64B lines densely from a single XCD -> writeback ~ data size (6.4 MB),
// not line footprint (R4/R5 direct ELL scatter: 93-96 MB writeback).
__global__ void binscatter_kernel(const int* __restrict__ row, const int* __restrict__ col,
    int* __restrict__ bcnt, unsigned* __restrict__ bucket, int e, int nb) {
  const int xcd = xcc_id();
  int i = blockIdx.x * blockDim.x + threadIdx.x;
  if (i >= e) return;
  int c = col[i], r = row[i];
  int b = c >> 7;
  int cur = atomicAdd(&bcnt[xcd * nb + b], 1);
  if (cur < BCAP)
    bucket[((size_t)xcd * nb + b) * BCAP + cur] = ((unsigned)r << 7) | (unsigned)(c & 127);
}

// Pass 2: one block per bucket. LDS-count c_local, scatter rows straight into
// the bucket's 32 KB dense-ELL region (L2-resident, lines filled). Fuses
// ncnt + dinv.
__global__ __launch_bounds__(256) void build_kernel(const int* __restrict__ bcnt,
    const unsigned* __restrict__ bucket, int* __restrict__ ncnt,
    int* __restrict__ dense, float* __restrict__ dinv, int n, int nb) {
  __shared__ int lcnt[128];
  const int b = blockIdx.x;
  const int t = threadIdx.x;
  if (t < 128) lcnt[t] = 0;
  __syncthreads();
  #pragma unroll 1
  for (int g = 0; g < 8; ++g) {
    const int cntg = min(bcnt[g * nb + b], BCAP);
    const unsigned* __restrict__ src = bucket + ((size_t)g * nb + b) * BCAP;
    for (int idx = t; idx < cntg; idx += 256) {
      unsigned ev = src[idx];
      int cl = (int)(ev & 127u);
      int r  = (int)(ev >> 7);
      int s = atomicAdd(&lcnt[cl], 1);
      if (s < DENSW) dense[(size_t)((b << 7) + cl) * DENSW + s] = r;
    }
  }
  __syncthreads();
  if (t < 128) {
    int c = (b << 7) + t;
    if (c < n) {
      int cc = min(lcnt[t], DENSW);
      ncnt[c] = cc;
      dinv[c] = rsqrtf((float)(cc + 1));  // +1 self-loop
    }
  }
}

// ---------------- prep: weights -> frag-ordered fp16 ----------------
struct WDesc { const float* src; f16* dst; int K, NC, Kpad, NCpad; };
struct WAll { WDesc m[9]; };

__global__ __launch_bounds__(256) void wprep_kernel(WAll wa) {
  const WDesc d = wa.m[blockIdx.y];
  const int KST = d.Kpad >> 5;
  const int total = (d.NCpad >> 4) * KST * 64;
  int idx = blockIdx.x * 256 + threadIdx.x;
  if (idx >= total) return;
  int nt  = idx / (KST * 64);
  int rem = idx - nt * (KST * 64);
  int ks  = rem >> 6;
  int l   = rem & 63;
  int n   = nt * 16 + (l & 15);
  int k0  = ks * 32 + (l >> 4) * 8;
  f16x8 o;
  #pragma unroll
  for (int j = 0; j < 8; ++j) {
    int k = k0 + j;
    float v = (k < d.K && n < d.NC) ? d.src[(size_t)k * d.NC + n] : 0.0f;
    o[j] = (f16)v;
  }
  *((f16x8*)d.dst + idx) = o;
}

__global__ void xprep_kernel(const float* __restrict__ x, f16* __restrict__ x16,
                             f16* __restrict__ xg, int n) {
  int idx = blockIdx.x * blockDim.x + threadIdx.x;
  if (idx >= n * 160) return;
  int r = idx / 160, c = idx - r * 160;
  x16[idx] = (f16)((c < 130) ? x[(size_t)r * 130 + c] : 0.0f);
  if (c >= 130) xg[idx] = (f16)0.0f;
}

// ---------------- MFMA matmul ----------------
// Y[N,NC] = X[N,K] @ W[K,NC], fp16 in / fp32 acc / fp16 out, fused epilogue.
// MODE 0: Y = sigmoid(acc+bias); MODE 1: forget-gate mix (NC=130, Y stride 160);
// MODE 2: Y = acc * dinv[row].
// Epilogue via LDS transpose; PSTR % 16 == 4 -> conflict-free acc scatter.
// MODE 1 reads the mix input from the f16 x16 copy (row stride 160),
// prefetched into registers BEFORE the transpose barrier so the epilogue's
// global latency hides under the MFMA main loop (was: 64 scalar f32 loads
// per thread after the barrier -> latency-bound, 101 us).
template<int KPAD, int RS, int NCPAD, int NC, int MODE>
__global__ __launch_bounds__(256, 4) void mm_mfma(
    const f16* __restrict__ X, const f16* __restrict__ Wt,
    const float* __restrict__ bias, f16* __restrict__ Y,
    const float* __restrict__ dinv, const f16* __restrict__ xor16,
    const float* __restrict__ initial, int n, int ngrid)
{
  constexpr int KST = KPAD / 32;
  constexpr int NT  = NCPAD / 16;
  constexpr int YRS = (MODE == 1) ? 160 : 128;
  constexpr int PSTR = (NCPAD == 128) ? 132 : 148;  // %16 == 4
  constexpr int LDSH = (NCPAD * KPAD > 128 * PSTR) ? NCPAD * KPAD : 128 * PSTR;
  __shared__ f16 Bs[LDSH];

  const int t = threadIdx.x;
  constexpr int BSW = NCPAD * KPAD / 8;
  #pragma unroll
  for (int i = 0; i < (BSW + 255) / 256; ++i) {
    int idx = t + i * 256;
    if (BSW % 256 == 0 || idx < BSW)
      ((f16x8*)Bs)[idx] = ((const f16x8*)Wt)[idx];
  }

  // --- MODE 1: prefetch the x-mix row chunk into registers (16B aligned,
  // rows padded to NP so OOB rows are readable garbage; stores are guarded).
  f16x8 xo[8];
  f16x2 xo2;
  if constexpr (MODE == 1) {
    const int r_ep  = t >> 1;
    const int hf_ep = t & 1;
    const f16* xp = xor16 + (size_t)(blockIdx.x * 128 + r_ep) * 160;
    #pragma unroll
    for (int c8 = 0; c8 < 8; ++c8)
      xo[c8] = *(const f16x8*)(xp + hf_ep * 64 + c8 * 8);
    xo2 = *(const f16x2*)(xp + 128);
  }

  __syncthreads();

  const int wid  = t >> 6;
  const int l    = t & 63;
  const int m15  = l & 15;
  const int quad = l >> 4;
  const int rw   = blockIdx.x * 128 + wid * 32;

  f32x4 acc[2][NT];
  #pragma unroll
  for (int mt = 0; mt < 2; ++mt)
    #pragma unroll
    for (int nt = 0; nt < NT; ++nt)
      acc[mt][nt] = (f32x4){0.f, 0.f, 0.f, 0.f};

  const f16* Xr0 = X + (size_t)(rw + m15) * RS;
  const f16* Xr1 = X + (size_t)(rw + 16 + m15) * RS;

  #pragma unroll
  for (int ks = 0; ks < KST; ++ks) {
    const int off = ks * 32 + quad * 8;
    f16x8 a0 = *(const f16x8*)(Xr0 + off);
    f16x8 a1 = *(const f16x8*)(Xr1 + off);
    #pragma unroll
    for (int nt = 0; nt < NT; ++nt) {
      f16x8 b = *((const f16x8*)Bs + (nt * KST + ks) * 64 + l);
      acc[0][nt] = __builtin_amdgcn_mfma_f32_16x16x32_f16(a0, b, acc[0][nt], 0, 0, 0);
      acc[1][nt] = __builtin_amdgcn_mfma_f32_16x16x32_f16(a1, b, acc[1][nt], 0, 0, 0);
    }
  }

  __syncthreads();  // done reading Bs; reuse as transpose tile

  #pragma unroll
  for (int mt = 0; mt < 2; ++mt) {
    #pragma unroll
    for (int reg = 0; reg < 4; ++reg) {
      const int rl = wid * 32 + mt * 16 + quad * 4 + reg;
      #pragma unroll
      for (int nt = 0; nt < NT; ++nt)
        Bs[rl * PSTR + nt * 16 + m15] = (f16)acc[mt][nt][reg];
    }
  }
  __syncthreads();

  const int r  = t >> 1;
  const int hf = t & 1;
  const int gr = blockIdx.x * 128 + r;
  if (gr < n) {
    if constexpr (MODE == 0 || MODE == 2) {
      float dv = 0.0f;
      if constexpr (MODE == 2) dv = dinv[gr];
      #pragma unroll
      for (int c8 = 0; c8 < 8; ++c8) {
        const int c0 = hf * 64 + c8 * 8;
        f16x8 v = *(const f16x8*)&Bs[r * PSTR + c0];
        f16x8 o;
        #pragma unroll
        for (int j = 0; j < 8; ++j) {
          float a = (float)v[j];
          if constexpr (MODE == 0) o[j] = (f16)sigm(a + bias[c0 + j]);
          else                     o[j] = (f16)(a * dv);
        }
        *(f16x8*)&Y[(size_t)gr * YRS + c0] = o;
      }
    } else {  // MODE 1, NC=130
      const bool hasInit = (gr >= ngrid);
      #pragma unroll
      for (int c8 = 0; c8 < 8; ++c8) {
        const int c0 = hf * 64 + c8 * 8;
        f16x8 v = *(const f16x8*)&Bs[r * PSTR + c0];
        f16x8 o;
        #pragma unroll
        for (int j = 0; j < 8; ++j) {
          const int col = c0 + j;
          float fv = sigm((float)v[j] + bias[col]);
          float xov = (float)xo[c8][j];
          float ip = hasInit ? initial[(size_t)(gr - ngrid) * 128 + col] : 0.0f;
          o[j] = (f16)(xov * fv + (1.0f - fv) * ip);
        }
        *(f16x8*)&Y[(size_t)gr * YRS + c0] = o;
      }
      if (hf) {
        #pragma unroll
        for (int k = 0; k < 2; ++k) {
          const int col = 128 + k;
          float fv = sigm((float)Bs[r * PSTR + col] + bias[col]);
          Y[(size_t)gr * YRS + col] = (f16)((float)xo2[k] * fv);
        }
      }
    }
  }
}

// ---------------- aggregation (lane-group batched gather) ----------------
// One wave per dest; 16 lanes x 16 B per row -> 4 rows per vmem instr.
// 2-way interleaved batches (dual accumulator) -> up to 32 lines in flight.
// Tail padded with the self row (max-idempotent).
template<int MODE>
__global__ __launch_bounds__(256) void agg_kernel(
    const f16* __restrict__ G, const int* __restrict__ ncnt,
    const int* __restrict__ dense,
    const float* __restrict__ dinv, const float* __restrict__ bias,
    const float* __restrict__ gamma, const float* __restrict__ beta,
    const f16* __restrict__ xg, const f16* __restrict__ u,
    void* __restrict__ out, int n)
{
  const int wid = threadIdx.x >> 6, lane = threadIdx.x & 63;
  const int c = blockIdx.x * 4 + wid;
  if (c >= n) return;
  const int li = lane & 15, grp = lane >> 4;

  union F8 { f16x8 h; int4 i; };
  F8 m; m.h = *(const f16x8*)(G + (size_t)c * 128 + li * 8);  // self-loop
  F8 m2; m2.h = m.h;
  const int nc = min(ncnt[c], DENSW);
  const int* __restrict__ lst = dense + (size_t)c * DENSW;
  const int B = (nc + 3) >> 2;
  int b = 0;
  for (; b + 1 < B; b += 2) {
    int p0 = b * 4 + grp, p1 = p0 + 4;
    int i0 = lst[p0], i1 = lst[p1];   // in-bounds reads; value junk if p>=nc
    int r0 = (p0 < nc) ? i0 : c;
    int r1 = (p1 < nc) ? i1 : c;
    F8 v0; v0.h = *(const f16x8*)(G + (size_t)r0 * 128 + li * 8);
    F8 v1; v1.h = *(const f16x8*)(G + (size_t)r1 * 128 + li * 8);
    #pragma unroll
    for (int j = 0; j < 8; ++j) {
      m.h[j]  = (v0.h[j] > m.h[j])  ? v0.h[j] : m.h[j];
      m2.h[j] = (v1.h[j] > m2.h[j]) ? v1.h[j] : m2.h[j];
    }
  }
  if (b < B) {
    int p = b * 4 + grp;
    int idx = lst[p];
    int r = (p < nc) ? idx : c;
    F8 v; v.h = *(const f16x8*)(G + (size_t)r * 128 + li * 8);
    #pragma unroll
    for (int j = 0; j < 8; ++j) m.h[j] = (v.h[j] > m.h[j]) ? v.h[j] : m.h[j];
  }
  #pragma unroll
  for (int j = 0; j < 8; ++j) m.h[j] = (m2.h[j] > m.h[j]) ? m2.h[j] : m.h[j];

  #pragma unroll
  for (int st = 16; st <= 32; st <<= 1) {
    F8 o;
    #pragma unroll
    for (int d = 0; d < 4; ++d) o.i[d] = __shfl_xor(m.i[d], st, 64);
    #pragma unroll
    for (int j = 0; j < 8; ++j) m.h[j] = (o.h[j] > m.h[j]) ? o.h[j] : m.h[j];
  }

  const float dc = dinv[c];
  float v[8];
  float s = 0.f, sq = 0.f;
  #pragma unroll
  for (int j = 0; j < 8; ++j) {
    v[j] = (float)m.h[j] * dc + bias[li * 8 + j];
    s += v[j]; sq += v[j] * v[j];
  }

  if constexpr (MODE == 2) {
    if (grp == 0) {
      f16x8 xv = *(const f16x8*)(xg + (size_t)c * 160 + li * 8);
      f16x8 uv = *(const f16x8*)(u  + (size_t)c * 128 + li * 8);
      float o[8];
      #pragma unroll
      for (int j = 0; j < 8; ++j) o[j] = (float)xv[j] + v[j] * (float)uv[j];
      float* op = (float*)out + (size_t)c * 128 + li * 8;
      *(float4*)op       = make_float4(o[0], o[1], o[2], o[3]);
      *(float4*)(op + 4) = make_float4(o[4], o[5], o[6], o[7]);
    }
  } else {
    #pragma unroll
    for (int st = 1; st <= 8; st <<= 1) {
      s  += __shfl_xor(s, st, 64);
      sq += __shfl_xor(sq, st, 64);
    }
    float mu  = s * (1.0f / 128.0f);
    float var = sq * (1.0f / 128.0f) - mu * mu;
    float rstd = rsqrtf(var + 1e-5f);
    if (grp == 0) {
      f16x8 ov;
      #pragma unroll
      for (int j = 0; j < 8; ++j) {
        float o = (v[j] - mu) * rstd * gamma[li * 8 + j] + beta[li * 8 + j];
        if constexpr (MODE == 0) o = fmaxf(o, 0.0f);
        ov[j] = (f16)o;
      }
      *(f16x8*)((f16*)out + (size_t)c * 128 + li * 8) = ov;
    }
  }
}

extern "C" void kernel_launch(void* const* d_in, const int* in_sizes, int n_in,
                              void* d_out, int out_size, void* d_ws, size_t ws_size,
                              hipStream_t stream) {
  (void)n_in; (void)out_size; (void)ws_size;
  const float* x       = (const float*)d_in[0];
  const int*   ei      = (const int*)d_in[1];
  const float* initial = (const float*)d_in[2];
  const float* Wf1 = (const float*)d_in[3];  const float* bf1 = (const float*)d_in[4];
  const float* Wf2 = (const float*)d_in[5];  const float* bf2 = (const float*)d_in[6];
  const float* Wu1 = (const float*)d_in[7];  const float* bu1 = (const float*)d_in[8];
  const float* Wu2 = (const float*)d_in[9];  const float* bu2 = (const float*)d_in[10];
  const float* Wc1 = (const float*)d_in[11]; const float* bc1 = (const float*)d_in[12];
  const float* Wc2 = (const float*)d_in[13]; const float* bc2 = (const float*)d_in[14];
  const float* Wc3 = (const float*)d_in[15]; const float* bc3 = (const float*)d_in[16];
  const float* Wc4 = (const float*)d_in[17]; const float* bc4 = (const float*)d_in[18];
  const float* Wco = (const float*)d_in[19]; const float* bco = (const float*)d_in[20];
  const float* g3  = (const float*)d_in[21]; const float* bn3 = (const float*)d_in[22];
  const float* g6  = (const float*)d_in[23]; const float* bn6 = (const float*)d_in[24];
  const float* g7  = (const float*)d_in[25]; const float* bn7 = (const float*)d_in[26];

  const int N  = in_sizes[0] / HC;   // 100000
  const int E  = in_sizes[1] / 2;    // 1600000
  const int NG = N - NIO;            // 99872
  const int NP = N + 128;            // padded rows for OOB-safe A-frag loads
  const int NB = (N + 127) / 128;    // 782 coarse buckets

  char* w = (char*)d_ws;
  auto carve = [&](size_t bytes) {
    char* p = w; w += (bytes + 255) & ~(size_t)255; return p;
  };
  int*      bcnt   = (int*)     carve((size_t)NB * 8 * 4);
  unsigned* bucket = (unsigned*)carve((size_t)NB * 8 * BCAP * 4);  // 19.2 MB
  int*      ncnt   = (int*)     carve((size_t)N * 4);
  int*      dense  = (int*)     carve((size_t)N * DENSW * 4);      // 25.6 MB
  float*    dinv   = (float*)   carve((size_t)N * 4);
  f16*      x16    = (f16*)     carve((size_t)NP * 160 * 2);
  f16*      S      = (f16*)     carve((size_t)NP * 128 * 2);
  f16*      xg     = (f16*)     carve((size_t)NP * 160 * 2);
  f16*      u      = (f16*)     carve((size_t)N  * 128 * 2);
  f16*      G      = (f16*)     carve((size_t)N  * 128 * 2);
  f16*      H      = (f16*)     carve((size_t)NP * 128 * 2);
  f16*      Wt_f1  = (f16*)     carve(160 * 128 * 2);
  f16*      Wt_f2  = (f16*)     carve(128 * 144 * 2);
  f16*      Wt_u1  = (f16*)     carve(160 * 128 * 2);
  f16*      Wt_u2  = (f16*)     carve(128 * 128 * 2);
  f16*      Wt_c1  = (f16*)     carve(160 * 128 * 2);
  f16*      Wt_c2  = (f16*)     carve(128 * 128 * 2);
  f16*      Wt_c3  = (f16*)     carve(128 * 128 * 2);
  f16*      Wt_c4  = (f16*)     carve(128 * 128 * 2);
  f16*      Wt_co  = (f16*)     carve(128 * 128 * 2);

  const int* erow = ei;
  const int* ecol = ei + E;

  const int gE = (E + 255) / 256;
  const int gM = (N + 127) / 128;
  const int gA = (N + 3) / 4;

  // weight/x prep
  WAll wa;
  wa.m[0] = {Wf1, Wt_f1, HC,  HID, 160, 128};
  wa.m[1] = {Wf2, Wt_f2, HID, HC,  128, 144};
  wa.m[2] = {Wu1, Wt_u1, HC,  HID, 160, 128};
  wa.m[3] = {Wu2, Wt_u2, HID, HID, 128, 128};
  wa.m[4] = {Wc1, Wt_c1, HC,  HID, 160, 128};
  wa.m[5] = {Wc2, Wt_c2, HID, HID, 128, 128};
  wa.m[6] = {Wc3, Wt_c3, HID, HID, 128, 128};
  wa.m[7] = {Wc4, Wt_c4, HID, HID, 128, 128};
  wa.m[8] = {Wco, Wt_co, HID, HID, 128, 128};
  wprep_kernel<<<dim3(10, 9), 256, 0, stream>>>(wa);
  xprep_kernel<<<(N * 160 + 255) / 256, 256, 0, stream>>>(x, x16, xg, N);

  // graph build (two-level binning)
  zero_int_kernel<<<(NB * 8 + 255) / 256, 256, 0, stream>>>(bcnt, NB * 8);
  binscatter_kernel<<<gE, 256, 0, stream>>>(erow, ecol, bcnt, bucket, E, NB);
  build_kernel<<<NB, 256, 0, stream>>>(bcnt, bucket, ncnt, dense, dinv, N, NB);

  // forget gate
  mm_mfma<160, 160, 128, 128, 0><<<gM, 256, 0, stream>>>(x16, Wt_f1, bf1, S,  nullptr, nullptr, nullptr, N, NG);
  mm_mfma<128, 128, 144, 130, 1><<<gM, 256, 0, stream>>>(S,   Wt_f2, bf2, xg, nullptr, x16, initial, N, NG);
  // update gate
  mm_mfma<160, 160, 128, 128, 0><<<gM, 256, 0, stream>>>(xg,  Wt_u1, bu1, S,  nullptr, nullptr, nullptr, N, NG);
  mm_mfma<128, 128, 128, 128, 0><<<gM, 256, 0, stream>>>(S,   Wt_u2, bu2, u,  nullptr, nullptr, nullptr, N, NG);

  // gcn1: relu(LN(..., g3, bn3))
  mm_mfma<160, 160, 128, 128, 2><<<gM, 256, 0, stream>>>(xg, Wt_c1, nullptr, G, dinv, nullptr, nullptr, N, NG);
  agg_kernel<0><<<gA, 256, 0, stream>>>(G, ncnt, dense, dinv, bc1, g3, bn3, nullptr, nullptr, H, N);
  // gcn2: LN(..., g3, bn3)
  mm_mfma<128, 128, 128, 128, 2><<<gM, 256, 0, stream>>>(H, Wt_c2, nullptr, G, dinv, nullptr, nullptr, N, NG);
  agg_kernel<1><<<gA, 256, 0, stream>>>(G, ncnt, dense, dinv, bc2, g3, bn3, nullptr, nullptr, H, N);
  // gcn3: LN(..., g6, bn6)
  mm_mfma<128, 128, 128, 128, 2><<<gM, 256, 0, stream>>>(H, Wt_c3, nullptr, G, dinv, nullptr, nullptr, N, NG);
  agg_kernel<1><<<gA, 256, 0, stream>>>(G, ncnt, dense, dinv, bc3, g6, bn6, nullptr, nullptr, H, N);
  // gcn4: LN(..., g7, bn7)
  mm_mfma<128, 128, 128, 128, 2><<<gM, 256, 0, stream>>>(H, Wt_c4, nullptr, G, dinv, nullptr, nullptr, N, NG);
  agg_kernel<1><<<gA, 256, 0, stream>>>(G, ncnt, dense, dinv, bc4, g7, bn7, nullptr, nullptr, H, N);
  // gcn5 + final: out = xg[:, :128] + (agg + bco) * u
  mm_mfma<128, 128, 128, 128, 2><<<gM, 256, 0, stream>>>(H, Wt_co, nullptr, G, dinv, nullptr, nullptr, N, NG);
  agg_kernel<2><<<gA, 256, 0, stream>>>(G, ncnt, dense, dinv, bco, nullptr, nullptr, xg, u, d_out, N);
}

// Round 3
// 813.793 us; speedup vs baseline: 1.1092x; 1.0429x over previous
//
#include <hip/hip_runtime.h>
#include <cstdint>

#define HID 128
#define HC  130
#define NIO 128
#define DENSW 64     // dense ELL width (max in-degree ~45 for Poisson(16))
#define SUBB 8       // sub-cursors per (xcd,bucket): kills same-address atomic serialization
#define BCAP_S 160   // per-(xcd,sub,bucket) capacity; mean ~32, 5x margin

typedef _Float16 f16;
typedef _Float16 f16x2 __attribute__((ext_vector_type(2)));
typedef _Float16 f16x8 __attribute__((ext_vector_type(8)));
typedef float    f32x4 __attribute__((ext_vector_type(4)));

__device__ __forceinline__ float sigm(float z) {
  return 1.0f / (1.0f + __expf(-z));
}

__device__ __forceinline__ int xcc_id() {
  int x;
  asm volatile("s_getreg_b32 %0, hwreg(HW_REG_XCC_ID)" : "=s"(x));
  return x & 7;
}

// ---------------- graph build: two-level binning ----------------
__global__ void zero_int_kernel(int* __restrict__ p, int n) {
  int i = blockIdx.x * blockDim.x + threadIdx.x;
  if (i < n) p[i] = 0;
}

// Pass 1: bin edges into per-(XCD,sub, bucket=c>>7) append buffers.
// sub = (blockIdx.x>>3)&7 is DEcorrelated from xcc_id (dispatch is ~round-robin
// in blockIdx, so blockIdx&7 ~ xcd -- R2's bug: only the diagonal segments
// filled, overflowed cap, dropped edges). 64 segments: ~32 colliding atomics
// per counter (was ~256 at 8 segments) and a 200 KB counter window spread over
// all channels (was 25 KB).
__global__ void binscatter_kernel(const int* __restrict__ row, const int* __restrict__ col,
    int* __restrict__ bcnt, unsigned* __restrict__ bucket, int e, int nb) {
  const int g0 = xcc_id() * SUBB + ((blockIdx.x >> 3) & (SUBB - 1));
  int i = blockIdx.x * blockDim.x + threadIdx.x;
  if (i >= e) return;
  int c = col[i], r = row[i];
  int b = c >> 7;
  int cur = atomicAdd(&bcnt[g0 * nb + b], 1);
  if (cur < BCAP_S)
    bucket[((size_t)g0 * nb + b) * BCAP_S + cur] = ((unsigned)r << 7) | (unsigned)(c & 127);
}

// Pass 2: one block per bucket. Each of the 4 waves independently drains 16 of
// the 64 segments (LDS atomics; no inter-segment barriers). Scatter rows into
// the bucket's 32 KB dense-ELL region (L2-resident, lines filled). Fuses
// ncnt + dinv.
__global__ __launch_bounds__(256) void build_kernel(const int* __restrict__ bcnt,
    const unsigned* __restrict__ bucket, int* __restrict__ ncnt,
    int* __restrict__ dense, float* __restrict__ dinv, int n, int nb) {
  __shared__ int lcnt[128];
  const int b = blockIdx.x;
  const int t = threadIdx.x;
  if (t < 128) lcnt[t] = 0;
  __syncthreads();
  const int wv = t >> 6, ln = t & 63;
  #pragma unroll 1
  for (int g = wv * 16; g < wv * 16 + 16; ++g) {
    const int cntg = min(bcnt[g * nb + b], BCAP_S);
    const unsigned* __restrict__ src = bucket + ((size_t)g * nb + b) * BCAP_S;
    for (int idx = ln; idx < cntg; idx += 64) {
      unsigned ev = src[idx];
      int cl = (int)(ev & 127u);
      int r  = (int)(ev >> 7);
      int s = atomicAdd(&lcnt[cl], 1);
      if (s < DENSW) dense[(size_t)((b << 7) + cl) * DENSW + s] = r;
    }
  }
  __syncthreads();
  if (t < 128) {
    int c = (b << 7) + t;
    if (c < n) {
      int cc = min(lcnt[t], DENSW);
      ncnt[c] = cc;
      dinv[c] = rsqrtf((float)(cc + 1));  // +1 self-loop
    }
  }
}

// ---------------- prep: weights -> frag-ordered fp16 ----------------
struct WDesc { const float* src; f16* dst; int K, NC, Kpad, NCpad; };
struct WAll { WDesc m[9]; };

__global__ __launch_bounds__(256) void wprep_kernel(WAll wa) {
  const WDesc d = wa.m[blockIdx.y];
  const int KST = d.Kpad >> 5;
  const int total = (d.NCpad >> 4) * KST * 64;
  int idx = blockIdx.x * 256 + threadIdx.x;
  if (idx >= total) return;
  int nt  = idx / (KST * 64);
  int rem = idx - nt * (KST * 64);
  int ks  = rem >> 6;
  int l   = rem & 63;
  int n   = nt * 16 + (l & 15);
  int k0  = ks * 32 + (l >> 4) * 8;
  f16x8 o;
  #pragma unroll
  for (int j = 0; j < 8; ++j) {
    int k = k0 + j;
    float v = (k < d.K && n < d.NC) ? d.src[(size_t)k * d.NC + n] : 0.0f;
    o[j] = (f16)v;
  }
  *((f16x8*)d.dst + idx) = o;
}

__global__ void xprep_kernel(const float* __restrict__ x, f16* __restrict__ x16,
                             f16* __restrict__ xg, int n) {
  int idx = blockIdx.x * blockDim.x + threadIdx.x;
  if (idx >= n * 160) return;
  int r = idx / 160, c = idx - r * 160;
  x16[idx] = (f16)((c < 130) ? x[(size_t)r * 130 + c] : 0.0f);
  if (c >= 130) xg[idx] = (f16)0.0f;
}

// ---------------- MFMA matmul ----------------
// Y[N,NC] = X[N,K] @ W[K,NC], fp16 in / fp32 acc / fp16 out, fused epilogue.
// MODE 0: Y = sigmoid(acc+bias); MODE 1: forget-gate mix (NC=130, Y stride 160);
// MODE 2: Y = acc * dinv[row].
// Epilogue via LDS transpose; PSTR % 16 == 4 -> conflict-free acc scatter.
// MODE 1 reads the mix input from the f16 x16 copy (row stride 160),
// prefetched into registers BEFORE the transpose barrier so the epilogue's
// global latency hides under the MFMA main loop (was: 64 scalar f32 loads
// per thread after the barrier -> latency-bound, 101 us).
template<int KPAD, int RS, int NCPAD, int NC, int MODE>
__global__ __launch_bounds__(256, 4) void mm_mfma(
    const f16* __restrict__ X, const f16* __restrict__ Wt,
    const float* __restrict__ bias, f16* __restrict__ Y,
    const float* __restrict__ dinv, const f16* __restrict__ xor16,
    const float* __restrict__ initial, int n, int ngrid)
{
  constexpr int KST = KPAD / 32;
  constexpr int NT  = NCPAD / 16;
  constexpr int YRS = (MODE == 1) ? 160 : 128;
  constexpr int PSTR = (NCPAD == 128) ? 132 : 148;  // %16 == 4
  constexpr int LDSH = (NCPAD * KPAD > 128 * PSTR) ? NCPAD * KPAD : 128 * PSTR;
  __shared__ f16 Bs[LDSH];

  const int t = threadIdx.x;
  constexpr int BSW = NCPAD * KPAD / 8;
  #pragma unroll
  for (int i = 0; i < (BSW + 255) / 256; ++i) {
    int idx = t + i * 256;
    if (BSW % 256 == 0 || idx < BSW)
      ((f16x8*)Bs)[idx] = ((const f16x8*)Wt)[idx];
  }

  // --- MODE 1: prefetch the x-mix row chunk into registers (16B aligned,
  // rows padded to NP so OOB rows are readable garbage; stores are guarded).
  f16x8 xo[8];
  f16x2 xo2;
  if constexpr (MODE == 1) {
    const int r_ep  = t >> 1;
    const int hf_ep = t & 1;
    const f16* xp = xor16 + (size_t)(blockIdx.x * 128 + r_ep) * 160;
    #pragma unroll
    for (int c8 = 0; c8 < 8; ++c8)
      xo[c8] = *(const f16x8*)(xp + hf_ep * 64 + c8 * 8);
    xo2 = *(const f16x2*)(xp + 128);
  }

  __syncthreads();

  const int wid  = t >> 6;
  const int l    = t & 63;
  const int m15  = l & 15;
  const int quad = l >> 4;
  const int rw   = blockIdx.x * 128 + wid * 32;

  f32x4 acc[2][NT];
  #pragma unroll
  for (int mt = 0; mt < 2; ++mt)
    #pragma unroll
    for (int nt = 0; nt < NT; ++nt)
      acc[mt][nt] = (f32x4){0.f, 0.f, 0.f, 0.f};

  const f16* Xr0 = X + (size_t)(rw + m15) * RS;
  const f16* Xr1 = X + (size_t)(rw + 16 + m15) * RS;

  #pragma unroll
  for (int ks = 0; ks < KST; ++ks) {
    const int off = ks * 32 + quad * 8;
    f16x8 a0 = *(const f16x8*)(Xr0 + off);
    f16x8 a1 = *(const f16x8*)(Xr1 + off);
    #pragma unroll
    for (int nt = 0; nt < NT; ++nt) {
      f16x8 b = *((const f16x8*)Bs + (nt * KST + ks) * 64 + l);
      acc[0][nt] = __builtin_amdgcn_mfma_f32_16x16x32_f16(a0, b, acc[0][nt], 0, 0, 0);
      acc[1][nt] = __builtin_amdgcn_mfma_f32_16x16x32_f16(a1, b, acc[1][nt], 0, 0, 0);
    }
  }

  __syncthreads();  // done reading Bs; reuse as transpose tile

  #pragma unroll
  for (int mt = 0; mt < 2; ++mt) {
    #pragma unroll
    for (int reg = 0; reg < 4; ++reg) {
      const int rl = wid * 32 + mt * 16 + quad * 4 + reg;
      #pragma unroll
      for (int nt = 0; nt < NT; ++nt)
        Bs[rl * PSTR + nt * 16 + m15] = (f16)acc[mt][nt][reg];
    }
  }
  __syncthreads();

  const int r  = t >> 1;
  const int hf = t & 1;
  const int gr = blockIdx.x * 128 + r;
  if (gr < n) {
    if constexpr (MODE == 0 || MODE == 2) {
      float dv = 0.0f;
      if constexpr (MODE == 2) dv = dinv[gr];
      #pragma unroll
      for (int c8 = 0; c8 < 8; ++c8) {
        const int c0 = hf * 64 + c8 * 8;
        f16x8 v = *(const f16x8*)&Bs[r * PSTR + c0];
        f16x8 o;
        #pragma unroll
        for (int j = 0; j < 8; ++j) {
          float a = (float)v[j];
          if constexpr (MODE == 0) o[j] = (f16)sigm(a + bias[c0 + j]);
          else                     o[j] = (f16)(a * dv);
        }
        *(f16x8*)&Y[(size_t)gr * YRS + c0] = o;
      }
    } else {  // MODE 1, NC=130
      const bool hasInit = (gr >= ngrid);
      #pragma unroll
      for (int c8 = 0; c8 < 8; ++c8) {
        const int c0 = hf * 64 + c8 * 8;
        f16x8 v = *(const f16x8*)&Bs[r * PSTR + c0];
        f16x8 o;
        #pragma unroll
        for (int j = 0; j < 8; ++j) {
          const int col = c0 + j;
          float fv = sigm((float)v[j] + bias[col]);
          float xov = (float)xo[c8][j];
          float ip = hasInit ? initial[(size_t)(gr - ngrid) * 128 + col] : 0.0f;
          o[j] = (f16)(xov * fv + (1.0f - fv) * ip);
        }
        *(f16x8*)&Y[(size_t)gr * YRS + c0] = o;
      }
      if (hf) {
        #pragma unroll
        for (int k = 0; k < 2; ++k) {
          const int col = 128 + k;
          float fv = sigm((float)Bs[r * PSTR + col] + bias[col]);
          Y[(size_t)gr * YRS + col] = (f16)((float)xo2[k] * fv);
        }
      }
    }
  }
}

// ---------------- aggregation (lane-group batched gather) ----------------
// One wave per dest; 16 lanes x 16 B per row -> 4 rows per vmem instr.
// 2-way interleaved batches (dual accumulator) -> up to 32 lines in flight.
// Tail padded with the self row (max-idempotent).
template<int MODE>
__global__ __launch_bounds__(256) void agg_kernel(
    const f16* __restrict__ G, const int* __restrict__ ncnt,
    const int* __restrict__ dense,
    const float* __restrict__ dinv, const float* __restrict__ bias,
    const float* __restrict__ gamma, const float* __restrict__ beta,
    const f16* __restrict__ xg, const f16* __restrict__ u,
    void* __restrict__ out, int n)
{
  const int wid = threadIdx.x >> 6, lane = threadIdx.x & 63;
  const int c = blockIdx.x * 4 + wid;
  if (c >= n) return;
  const int li = lane & 15, grp = lane >> 4;

  union F8 { f16x8 h; int4 i; };
  F8 m; m.h = *(const f16x8*)(G + (size_t)c * 128 + li * 8);  // self-loop
  F8 m2; m2.h = m.h;
  const int nc = min(ncnt[c], DENSW);
  const int* __restrict__ lst = dense + (size_t)c * DENSW;
  const int B = (nc + 3) >> 2;
  int b = 0;
  for (; b + 1 < B; b += 2) {
    int p0 = b * 4 + grp, p1 = p0 + 4;
    int i0 = lst[p0], i1 = lst[p1];   // in-bounds reads; value junk if p>=nc
    int r0 = (p0 < nc) ? i0 : c;
    int r1 = (p1 < nc) ? i1 : c;
    F8 v0; v0.h = *(const f16x8*)(G + (size_t)r0 * 128 + li * 8);
    F8 v1; v1.h = *(const f16x8*)(G + (size_t)r1 * 128 + li * 8);
    #pragma unroll
    for (int j = 0; j < 8; ++j) {
      m.h[j]  = (v0.h[j] > m.h[j])  ? v0.h[j] : m.h[j];
      m2.h[j] = (v1.h[j] > m2.h[j]) ? v1.h[j] : m2.h[j];
    }
  }
  if (b < B) {
    int p = b * 4 + grp;
    int idx = lst[p];
    int r = (p < nc) ? idx : c;
    F8 v; v.h = *(const f16x8*)(G + (size_t)r * 128 + li * 8);
    #pragma unroll
    for (int j = 0; j < 8; ++j) m.h[j] = (v.h[j] > m.h[j]) ? v.h[j] : m.h[j];
  }
  #pragma unroll
  for (int j = 0; j < 8; ++j) m.h[j] = (m2.h[j] > m.h[j]) ? m2.h[j] : m.h[j];

  #pragma unroll
  for (int st = 16; st <= 32; st <<= 1) {
    F8 o;
    #pragma unroll
    for (int d = 0; d < 4; ++d) o.i[d] = __shfl_xor(m.i[d], st, 64);
    #pragma unroll
    for (int j = 0; j < 8; ++j) m.h[j] = (o.h[j] > m.h[j]) ? o.h[j] : m.h[j];
  }

  const float dc = dinv[c];
  float v[8];
  float s = 0.f, sq = 0.f;
  #pragma unroll
  for (int j = 0; j < 8; ++j) {
    v[j] = (float)m.h[j] * dc + bias[li * 8 + j];
    s += v[j]; sq += v[j] * v[j];
  }

  if constexpr (MODE == 2) {
    if (grp == 0) {
      f16x8 xv = *(const f16x8*)(xg + (size_t)c * 160 + li * 8);
      f16x8 uv = *(const f16x8*)(u  + (size_t)c * 128 + li * 8);
      float o[8];
      #pragma unroll
      for (int j = 0; j < 8; ++j) o[j] = (float)xv[j] + v[j] * (float)uv[j];
      float* op = (float*)out + (size_t)c * 128 + li * 8;
      *(float4*)op       = make_float4(o[0], o[1], o[2], o[3]);
      *(float4*)(op + 4) = make_float4(o[4], o[5], o[6], o[7]);
    }
  } else {
    #pragma unroll
    for (int st = 1; st <= 8; st <<= 1) {
      s  += __shfl_xor(s, st, 64);
      sq += __shfl_xor(sq, st, 64);
    }
    float mu  = s * (1.0f / 128.0f);
    float var = sq * (1.0f / 128.0f) - mu * mu;
    float rstd = rsqrtf(var + 1e-5f);
    if (grp == 0) {
      f16x8 ov;
      #pragma unroll
      for (int j = 0; j < 8; ++j) {
        float o = (v[j] - mu) * rstd * gamma[li * 8 + j] + beta[li * 8 + j];
        if constexpr (MODE == 0) o = fmaxf(o, 0.0f);
        ov[j] = (f16)o;
      }
      *(f16x8*)((f16*)out + (size_t)c * 128 + li * 8) = ov;
    }
  }
}

extern "C" void kernel_launch(void* const* d_in, const int* in_sizes, int n_in,
                              void* d_out, int out_size, void* d_ws, size_t ws_size,
                              hipStream_t stream) {
  (void)n_in; (void)out_size; (void)ws_size;
  const float* x       = (const float*)d_in[0];
  const int*   ei      = (const int*)d_in[1];
  const float* initial = (const float*)d_in[2];
  const float* Wf1 = (const float*)d_in[3];  const float* bf1 = (const float*)d_in[4];
  const float* Wf2 = (const float*)d_in[5];  const float* bf2 = (const float*)d_in[6];
  const float* Wu1 = (const float*)d_in[7];  const float* bu1 = (const float*)d_in[8];
  const float* Wu2 = (const float*)d_in[9];  const float* bu2 = (const float*)d_in[10];
  const float* Wc1 = (const float*)d_in[11]; const float* bc1 = (const float*)d_in[12];
  const float* Wc2 = (const float*)d_in[13]; const float* bc2 = (const float*)d_in[14];
  const float* Wc3 = (const float*)d_in[15]; const float* bc3 = (const float*)d_in[16];
  const float* Wc4 = (const float*)d_in[17]; const float* bc4 = (const float*)d_in[18];
  const float* Wco = (const float*)d_in[19]; const float* bco = (const float*)d_in[20];
  const float* g3  = (const float*)d_in[21]; const float* bn3 = (const float*)d_in[22];
  const float* g6  = (const float*)d_in[23]; const float* bn6 = (const float*)d_in[24];
  const float* g7  = (const float*)d_in[25]; const float* bn7 = (const float*)d_in[26];

  const int N  = in_sizes[0] / HC;   // 100000
  const int E  = in_sizes[1] / 2;    // 1600000
  const int NG = N - NIO;            // 99872
  const int NP = N + 128;            // padded rows for OOB-safe A-frag loads
  const int NB = (N + 127) / 128;    // 782 coarse buckets
  const int NSEG = 8 * SUBB;         // 64 append segments per bucket

  char* w = (char*)d_ws;
  auto carve = [&](size_t bytes) {
    char* p = w; w += (bytes + 255) & ~(size_t)255; return p;
  };
  int*      bcnt   = (int*)     carve((size_t)NB * NSEG * 4);
  unsigned* bucket = (unsigned*)carve((size_t)NB * NSEG * BCAP_S * 4);  // 32 MB
  int*      ncnt   = (int*)     carve((size_t)N * 4);
  int*      dense  = (int*)     carve((size_t)N * DENSW * 4);      // 25.6 MB
  float*    dinv   = (float*)   carve((size_t)N * 4);
  f16*      x16    = (f16*)     carve((size_t)NP * 160 * 2);
  f16*      S      = (f16*)     carve((size_t)NP * 128 * 2);
  f16*      xg     = (f16*)     carve((size_t)NP * 160 * 2);
  f16*      u      = (f16*)     carve((size_t)N  * 128 * 2);
  f16*      G      = (f16*)     carve((size_t)N  * 128 * 2);
  f16*      H      = (f16*)     carve((size_t)NP * 128 * 2);
  f16*      Wt_f1  = (f16*)     carve(160 * 128 * 2);
  f16*      Wt_f2  = (f16*)     carve(128 * 144 * 2);
  f16*      Wt_u1  = (f16*)     carve(160 * 128 * 2);
  f16*      Wt_u2  = (f16*)     carve(128 * 128 * 2);
  f16*      Wt_c1  = (f16*)     carve(160 * 128 * 2);
  f16*      Wt_c2  = (f16*)     carve(128 * 128 * 2);
  f16*      Wt_c3  = (f16*)     carve(128 * 128 * 2);
  f16*      Wt_c4  = (f16*)     carve(128 * 128 * 2);
  f16*      Wt_co  = (f16*)     carve(128 * 128 * 2);

  const int* erow = ei;
  const int* ecol = ei + E;

  const int gE = (E + 255) / 256;
  const int gM = (N + 127) / 128;
  const int gA = (N + 3) / 4;

  // weight/x prep
  WAll wa;
  wa.m[0] = {Wf1, Wt_f1, HC,  HID, 160, 128};
  wa.m[1] = {Wf2, Wt_f2, HID, HC,  128, 144};
  wa.m[2] = {Wu1, Wt_u1, HC,  HID, 160, 128};
  wa.m[3] = {Wu2, Wt_u2, HID, HID, 128, 128};
  wa.m[4] = {Wc1, Wt_c1, HC,  HID, 160, 128};
  wa.m[5] = {Wc2, Wt_c2, HID, HID, 128, 128};
  wa.m[6] = {Wc3, Wt_c3, HID, HID, 128, 128};
  wa.m[7] = {Wc4, Wt_c4, HID, HID, 128, 128};
  wa.m[8] = {Wco, Wt_co, HID, HID, 128, 128};
  wprep_kernel<<<dim3(10, 9), 256, 0, stream>>>(wa);
  xprep_kernel<<<(N * 160 + 255) / 256, 256, 0, stream>>>(x, x16, xg, N);

  // graph build (two-level binning)
  zero_int_kernel<<<(NB * NSEG + 255) / 256, 256, 0, stream>>>(bcnt, NB * NSEG);
  binscatter_kernel<<<gE, 256, 0, stream>>>(erow, ecol, bcnt, bucket, E, NB);
  build_kernel<<<NB, 256, 0, stream>>>(bcnt, bucket, ncnt, dense, dinv, N, NB);

  // forget gate
  mm_mfma<160, 160, 128, 128, 0><<<gM, 256, 0, stream>>>(x16, Wt_f1, bf1, S,  nullptr, nullptr, nullptr, N, NG);
  mm_mfma<128, 128, 144, 130, 1><<<gM, 256, 0, stream>>>(S,   Wt_f2, bf2, xg, nullptr, x16, initial, N, NG);
  // update gate
  mm_mfma<160, 160, 128, 128, 0><<<gM, 256, 0, stream>>>(xg,  Wt_u1, bu1, S,  nullptr, nullptr, nullptr, N, NG);
  mm_mfma<128, 128, 128, 128, 0><<<gM, 256, 0, stream>>>(S,   Wt_u2, bu2, u,  nullptr, nullptr, nullptr, N, NG);

  // gcn1: relu(LN(..., g3, bn3))
  mm_mfma<160, 160, 128, 128, 2><<<gM, 256, 0, stream>>>(xg, Wt_c1, nullptr, G, dinv, nullptr, nullptr, N, NG);
  agg_kernel<0><<<gA, 256, 0, stream>>>(G, ncnt, dense, dinv, bc1, g3, bn3, nullptr, nullptr, H, N);
  // gcn2: LN(..., g3, bn3)
  mm_mfma<128, 128, 128, 128, 2><<<gM, 256, 0, stream>>>(H, Wt_c2, nullptr, G, dinv, nullptr, nullptr, N, NG);
  agg_kernel<1><<<gA, 256, 0, stream>>>(G, ncnt, dense, dinv, bc2, g3, bn3, nullptr, nullptr, H, N);
  // gcn3: LN(..., g6, bn6)
  mm_mfma<128, 128, 128, 128, 2><<<gM, 256, 0, stream>>>(H, Wt_c3, nullptr, G, dinv, nullptr, nullptr, N, NG);
  agg_kernel<1><<<gA, 256, 0, stream>>>(G, ncnt, dense, dinv, bc3, g6, bn6, nullptr, nullptr, H, N);
  // gcn4: LN(..., g7, bn7)
  mm_mfma<128, 128, 128, 128, 2><<<gM, 256, 0, stream>>>(H, Wt_c4, nullptr, G, dinv, nullptr, nullptr, N, NG);
  agg_kernel<1><<<gA, 256, 0, stream>>>(G, ncnt, dense, dinv, bc4, g7, bn7, nullptr, nullptr, H, N);
  // gcn5 + final: out = xg[:, :128] + (agg + bco) * u
  mm_mfma<128, 128, 128, 128, 2><<<gM, 256, 0, stream>>>(H, Wt_co, nullptr, G, dinv, nullptr, nullptr, N, NG);
  agg_kernel<2><<<gA, 256, 0, stream>>>(G, ncnt, dense, dinv, bco, nullptr, nullptr, xg, u, d_out, N);
}

// Round 4
// 795.138 us; speedup vs baseline: 1.1352x; 1.0235x over previous
//
#include <hip/hip_runtime.h>
#include <cstdint>

#define HID 128
#define HC  130
#define NIO 128
#define DENSW 64     // dense ELL width (max in-degree ~45 for Poisson(16))
#define SUBB 8       // sub-cursors per (xcd,bucket): kills same-address atomic serialization
#define BCAP_S 160   // per-(xcd,sub,bucket) capacity; mean ~32, 5x margin

typedef _Float16 f16;
typedef _Float16 f16x2 __attribute__((ext_vector_type(2)));
typedef _Float16 f16x8 __attribute__((ext_vector_type(8)));
typedef float    f32x4 __attribute__((ext_vector_type(4)));

__device__ __forceinline__ float sigm(float z) {
  return 1.0f / (1.0f + __expf(-z));
}

__device__ __forceinline__ int xcc_id() {
  int x;
  asm volatile("s_getreg_b32 %0, hwreg(HW_REG_XCC_ID)" : "=s"(x));
  return x & 7;
}

// Packed f16 max: v_pk_max_f16 does 2 elements/op. The C ternary lowers to
// v_cmp+v_cndmask (2 ops/element) -> 4x the VALU. Inputs are finite
// (sigmoid/LN outputs), so fmax semantics are safe.
__device__ __forceinline__ f16x8 max8(f16x8 a, f16x8 b) {
  union P { f16x8 h; f16x2 p[4]; } A, B, O;
  A.h = a; B.h = b;
  #pragma unroll
  for (int i = 0; i < 4; ++i)
    asm("v_pk_max_f16 %0, %1, %2" : "=v"(O.p[i]) : "v"(A.p[i]), "v"(B.p[i]));
  return O.h;
}

// ---------------- graph build: two-level binning ----------------
__global__ void zero_int_kernel(int* __restrict__ p, int n) {
  int i = blockIdx.x * blockDim.x + threadIdx.x;
  if (i < n) p[i] = 0;
}

// Pass 1: bin edges into per-(XCD,sub, bucket=c>>7) append buffers.
// sub = (blockIdx.x>>3)&7 is DEcorrelated from xcc_id (dispatch is ~round-robin
// in blockIdx). 64 segments: ~32 colliding atomics per counter and a 200 KB
// counter window spread over all channels.
__global__ void binscatter_kernel(const int* __restrict__ row, const int* __restrict__ col,
    int* __restrict__ bcnt, unsigned* __restrict__ bucket, int e, int nb) {
  const int g0 = xcc_id() * SUBB + ((blockIdx.x >> 3) & (SUBB - 1));
  int i = blockIdx.x * blockDim.x + threadIdx.x;
  if (i >= e) return;
  int c = col[i], r = row[i];
  int b = c >> 7;
  int cur = atomicAdd(&bcnt[g0 * nb + b], 1);
  if (cur < BCAP_S)
    bucket[((size_t)g0 * nb + b) * BCAP_S + cur] = ((unsigned)r << 7) | (unsigned)(c & 127);
}

// Pass 2: one block per bucket. Each of the 4 waves independently drains 16 of
// the 64 segments (LDS atomics; no inter-segment barriers). Fuses ncnt + dinv.
__global__ __launch_bounds__(256) void build_kernel(const int* __restrict__ bcnt,
    const unsigned* __restrict__ bucket, int* __restrict__ ncnt,
    int* __restrict__ dense, float* __restrict__ dinv, int n, int nb) {
  __shared__ int lcnt[128];
  const int b = blockIdx.x;
  const int t = threadIdx.x;
  if (t < 128) lcnt[t] = 0;
  __syncthreads();
  const int wv = t >> 6, ln = t & 63;
  #pragma unroll 1
  for (int g = wv * 16; g < wv * 16 + 16; ++g) {
    const int cntg = min(bcnt[g * nb + b], BCAP_S);
    const unsigned* __restrict__ src = bucket + ((size_t)g * nb + b) * BCAP_S;
    for (int idx = ln; idx < cntg; idx += 64) {
      unsigned ev = src[idx];
      int cl = (int)(ev & 127u);
      int r  = (int)(ev >> 7);
      int s = atomicAdd(&lcnt[cl], 1);
      if (s < DENSW) dense[(size_t)((b << 7) + cl) * DENSW + s] = r;
    }
  }
  __syncthreads();
  if (t < 128) {
    int c = (b << 7) + t;
    if (c < n) {
      int cc = min(lcnt[t], DENSW);
      ncnt[c] = cc;
      dinv[c] = rsqrtf((float)(cc + 1));  // +1 self-loop
    }
  }
}

// ---------------- prep: weights -> frag-ordered fp16 ----------------
struct WDesc { const float* src; f16* dst; int K, NC, Kpad, NCpad; };
struct WAll { WDesc m[9]; };

__global__ __launch_bounds__(256) void wprep_kernel(WAll wa) {
  const WDesc d = wa.m[blockIdx.y];
  const int KST = d.Kpad >> 5;
  const int total = (d.NCpad >> 4) * KST * 64;
  int idx = blockIdx.x * 256 + threadIdx.x;
  if (idx >= total) return;
  int nt  = idx / (KST * 64);
  int rem = idx - nt * (KST * 64);
  int ks  = rem >> 6;
  int l   = rem & 63;
  int n   = nt * 16 + (l & 15);
  int k0  = ks * 32 + (l >> 4) * 8;
  f16x8 o;
  #pragma unroll
  for (int j = 0; j < 8; ++j) {
    int k = k0 + j;
    float v = (k < d.K && n < d.NC) ? d.src[(size_t)k * d.NC + n] : 0.0f;
    o[j] = (f16)v;
  }
  *((f16x8*)d.dst + idx) = o;
}

__global__ void xprep_kernel(const float* __restrict__ x, f16* __restrict__ x16,
                             f16* __restrict__ xg, int n) {
  int idx = blockIdx.x * blockDim.x + threadIdx.x;
  if (idx >= n * 160) return;
  int r = idx / 160, c = idx - r * 160;
  x16[idx] = (f16)((c < 130) ? x[(size_t)r * 130 + c] : 0.0f);
  if (c >= 130) xg[idx] = (f16)0.0f;
}

// ---------------- MFMA matmul ----------------
// Y[N,NC] = X[N,K] @ W[K,NC], fp16 in / fp32 acc / fp16 out, fused epilogue.
// MODE 0: Y = sigmoid(acc+bias); MODE 1: forget-gate mix (NC=130, Y stride 160);
// MODE 2: Y = acc * dinv[row].
// Epilogue via LDS transpose; PSTR % 16 == 4 -> conflict-free acc scatter.
// MODE 1 reads the mix input from the f16 x16 copy, prefetched into registers
// BEFORE the transpose barrier so its latency hides under the MFMA main loop.
template<int KPAD, int RS, int NCPAD, int NC, int MODE>
__global__ __launch_bounds__(256, 4) void mm_mfma(
    const f16* __restrict__ X, const f16* __restrict__ Wt,
    const float* __restrict__ bias, f16* __restrict__ Y,
    const float* __restrict__ dinv, const f16* __restrict__ xor16,
    const float* __restrict__ initial, int n, int ngrid)
{
  constexpr int KST = KPAD / 32;
  constexpr int NT  = NCPAD / 16;
  constexpr int YRS = (MODE == 1) ? 160 : 128;
  constexpr int PSTR = (NCPAD == 128) ? 132 : 148;  // %16 == 4
  constexpr int LDSH = (NCPAD * KPAD > 128 * PSTR) ? NCPAD * KPAD : 128 * PSTR;
  __shared__ f16 Bs[LDSH];

  const int t = threadIdx.x;
  constexpr int BSW = NCPAD * KPAD / 8;
  #pragma unroll
  for (int i = 0; i < (BSW + 255) / 256; ++i) {
    int idx = t + i * 256;
    if (BSW % 256 == 0 || idx < BSW)
      ((f16x8*)Bs)[idx] = ((const f16x8*)Wt)[idx];
  }

  // --- MODE 1: prefetch the x-mix row chunk into registers (16B aligned,
  // rows padded to NP so OOB rows are readable garbage; stores are guarded).
  f16x8 xo[8];
  f16x2 xo2;
  if constexpr (MODE == 1) {
    const int r_ep  = t >> 1;
    const int hf_ep = t & 1;
    const f16* xp = xor16 + (size_t)(blockIdx.x * 128 + r_ep) * 160;
    #pragma unroll
    for (int c8 = 0; c8 < 8; ++c8)
      xo[c8] = *(const f16x8*)(xp + hf_ep * 64 + c8 * 8);
    xo2 = *(const f16x2*)(xp + 128);
  }

  __syncthreads();

  const int wid  = t >> 6;
  const int l    = t & 63;
  const int m15  = l & 15;
  const int quad = l >> 4;
  const int rw   = blockIdx.x * 128 + wid * 32;

  f32x4 acc[2][NT];
  #pragma unroll
  for (int mt = 0; mt < 2; ++mt)
    #pragma unroll
    for (int nt = 0; nt < NT; ++nt)
      acc[mt][nt] = (f32x4){0.f, 0.f, 0.f, 0.f};

  const f16* Xr0 = X + (size_t)(rw + m15) * RS;
  const f16* Xr1 = X + (size_t)(rw + 16 + m15) * RS;

  #pragma unroll
  for (int ks = 0; ks < KST; ++ks) {
    const int off = ks * 32 + quad * 8;
    f16x8 a0 = *(const f16x8*)(Xr0 + off);
    f16x8 a1 = *(const f16x8*)(Xr1 + off);
    #pragma unroll
    for (int nt = 0; nt < NT; ++nt) {
      f16x8 b = *((const f16x8*)Bs + (nt * KST + ks) * 64 + l);
      acc[0][nt] = __builtin_amdgcn_mfma_f32_16x16x32_f16(a0, b, acc[0][nt], 0, 0, 0);
      acc[1][nt] = __builtin_amdgcn_mfma_f32_16x16x32_f16(a1, b, acc[1][nt], 0, 0, 0);
    }
  }

  __syncthreads();  // done reading Bs; reuse as transpose tile

  #pragma unroll
  for (int mt = 0; mt < 2; ++mt) {
    #pragma unroll
    for (int reg = 0; reg < 4; ++reg) {
      const int rl = wid * 32 + mt * 16 + quad * 4 + reg;
      #pragma unroll
      for (int nt = 0; nt < NT; ++nt)
        Bs[rl * PSTR + nt * 16 + m15] = (f16)acc[mt][nt][reg];
    }
  }
  __syncthreads();

  const int r  = t >> 1;
  const int hf = t & 1;
  const int gr = blockIdx.x * 128 + r;
  if (gr < n) {
    if constexpr (MODE == 0 || MODE == 2) {
      float dv = 0.0f;
      if constexpr (MODE == 2) dv = dinv[gr];
      #pragma unroll
      for (int c8 = 0; c8 < 8; ++c8) {
        const int c0 = hf * 64 + c8 * 8;
        f16x8 v = *(const f16x8*)&Bs[r * PSTR + c0];
        f16x8 o;
        #pragma unroll
        for (int j = 0; j < 8; ++j) {
          float a = (float)v[j];
          if constexpr (MODE == 0) o[j] = (f16)sigm(a + bias[c0 + j]);
          else                     o[j] = (f16)(a * dv);
        }
        *(f16x8*)&Y[(size_t)gr * YRS + c0] = o;
      }
    } else {  // MODE 1, NC=130
      const bool hasInit = (gr >= ngrid);
      #pragma unroll
      for (int c8 = 0; c8 < 8; ++c8) {
        const int c0 = hf * 64 + c8 * 8;
        f16x8 v = *(const f16x8*)&Bs[r * PSTR + c0];
        f16x8 o;
        #pragma unroll
        for (int j = 0; j < 8; ++j) {
          const int col = c0 + j;
          float fv = sigm((float)v[j] + bias[col]);
          float xov = (float)xo[c8][j];
          float ip = hasInit ? initial[(size_t)(gr - ngrid) * 128 + col] : 0.0f;
          o[j] = (f16)(xov * fv + (1.0f - fv) * ip);
        }
        *(f16x8*)&Y[(size_t)gr * YRS + c0] = o;
      }
      if (hf) {
        #pragma unroll
        for (int k = 0; k < 2; ++k) {
          const int col = 128 + k;
          float fv = sigm((float)Bs[r * PSTR + col] + bias[col]);
          Y[(size_t)gr * YRS + col] = (f16)((float)xo2[k] * fv);
        }
      }
    }
  }
}

// ---------------- aggregation (lane-group batched gather) ----------------
// One wave per dest; 16 lanes x 16 B per row -> 4 rows per vmem instr.
// 2-way interleaved batches (dual accumulator) -> up to 32 lines in flight.
// Tail padded with the self row (max-idempotent). All maxes via v_pk_max_f16.
template<int MODE>
__global__ __launch_bounds__(256) void agg_kernel(
    const f16* __restrict__ G, const int* __restrict__ ncnt,
    const int* __restrict__ dense,
    const float* __restrict__ dinv, const float* __restrict__ bias,
    const float* __restrict__ gamma, const float* __restrict__ beta,
    const f16* __restrict__ xg, const f16* __restrict__ u,
    void* __restrict__ out, int n)
{
  const int wid = threadIdx.x >> 6, lane = threadIdx.x & 63;
  const int c = blockIdx.x * 4 + wid;
  if (c >= n) return;
  const int li = lane & 15, grp = lane >> 4;

  union F8 { f16x8 h; int4 i; };
  F8 m; m.h = *(const f16x8*)(G + (size_t)c * 128 + li * 8);  // self-loop
  F8 m2; m2.h = m.h;
  const int nc = min(ncnt[c], DENSW);
  const int* __restrict__ lst = dense + (size_t)c * DENSW;
  const int B = (nc + 3) >> 2;
  int b = 0;
  for (; b + 1 < B; b += 2) {
    int p0 = b * 4 + grp, p1 = p0 + 4;
    int i0 = lst[p0], i1 = lst[p1];   // in-bounds reads; value junk if p>=nc
    int r0 = (p0 < nc) ? i0 : c;
    int r1 = (p1 < nc) ? i1 : c;
    F8 v0; v0.h = *(const f16x8*)(G + (size_t)r0 * 128 + li * 8);
    F8 v1; v1.h = *(const f16x8*)(G + (size_t)r1 * 128 + li * 8);
    m.h  = max8(m.h,  v0.h);
    m2.h = max8(m2.h, v1.h);
  }
  if (b < B) {
    int p = b * 4 + grp;
    int idx = lst[p];
    int r = (p < nc) ? idx : c;
    F8 v; v.h = *(const f16x8*)(G + (size_t)r * 128 + li * 8);
    m.h = max8(m.h, v.h);
  }
  m.h = max8(m.h, m2.h);

  #pragma unroll
  for (int st = 16; st <= 32; st <<= 1) {
    F8 o;
    #pragma unroll
    for (int d = 0; d < 4; ++d) o.i[d] = __shfl_xor(m.i[d], st, 64);
    m.h = max8(m.h, o.h);
  }

  const float dc = dinv[c];
  float v[8];
  float s = 0.f, sq = 0.f;
  #pragma unroll
  for (int j = 0; j < 8; ++j) {
    v[j] = (float)m.h[j] * dc + bias[li * 8 + j];
    s += v[j]; sq += v[j] * v[j];
  }

  if constexpr (MODE == 2) {
    if (grp == 0) {
      f16x8 xv = *(const f16x8*)(xg + (size_t)c * 160 + li * 8);
      f16x8 uv = *(const f16x8*)(u  + (size_t)c * 128 + li * 8);
      float o[8];
      #pragma unroll
      for (int j = 0; j < 8; ++j) o[j] = (float)xv[j] + v[j] * (float)uv[j];
      float* op = (float*)out + (size_t)c * 128 + li * 8;
      *(float4*)op       = make_float4(o[0], o[1], o[2], o[3]);
      *(float4*)(op + 4) = make_float4(o[4], o[5], o[6], o[7]);
    }
  } else {
    #pragma unroll
    for (int st = 1; st <= 8; st <<= 1) {
      s  += __shfl_xor(s, st, 64);
      sq += __shfl_xor(sq, st, 64);
    }
    float mu  = s * (1.0f / 128.0f);
    float var = sq * (1.0f / 128.0f) - mu * mu;
    float rstd = rsqrtf(var + 1e-5f);
    if (grp == 0) {
      f16x8 ov;
      #pragma unroll
      for (int j = 0; j < 8; ++j) {
        float o = (v[j] - mu) * rstd * gamma[li * 8 + j] + beta[li * 8 + j];
        if constexpr (MODE == 0) o = fmaxf(o, 0.0f);
        ov[j] = (f16)o;
      }
      *(f16x8*)((f16*)out + (size_t)c * 128 + li * 8) = ov;
    }
  }
}

extern "C" void kernel_launch(void* const* d_in, const int* in_sizes, int n_in,
                              void* d_out, int out_size, void* d_ws, size_t ws_size,
                              hipStream_t stream) {
  (void)n_in; (void)out_size; (void)ws_size;
  const float* x       = (const float*)d_in[0];
  const int*   ei      = (const int*)d_in[1];
  const float* initial = (const float*)d_in[2];
  const float* Wf1 = (const float*)d_in[3];  const float* bf1 = (const float*)d_in[4];
  const float* Wf2 = (const float*)d_in[5];  const float* bf2 = (const float*)d_in[6];
  const float* Wu1 = (const float*)d_in[7];  const float* bu1 = (const float*)d_in[8];
  const float* Wu2 = (const float*)d_in[9];  const float* bu2 = (const float*)d_in[10];
  const float* Wc1 = (const float*)d_in[11]; const float* bc1 = (const float*)d_in[12];
  const float* Wc2 = (const float*)d_in[13]; const float* bc2 = (const float*)d_in[14];
  const float* Wc3 = (const float*)d_in[15]; const float* bc3 = (const float*)d_in[16];
  const float* Wc4 = (const float*)d_in[17]; const float* bc4 = (const float*)d_in[18];
  const float* Wco = (const float*)d_in[19]; const float* bco = (const float*)d_in[20];
  const float* g3  = (const float*)d_in[21]; const float* bn3 = (const float*)d_in[22];
  const float* g6  = (const float*)d_in[23]; const float* bn6 = (const float*)d_in[24];
  const float* g7  = (const float*)d_in[25]; const float* bn7 = (const float*)d_in[26];

  const int N  = in_sizes[0] / HC;   // 100000
  const int E  = in_sizes[1] / 2;    // 1600000
  const int NG = N - NIO;            // 99872
  const int NP = N + 128;            // padded rows for OOB-safe A-frag loads
  const int NB = (N + 127) / 128;    // 782 coarse buckets
  const int NSEG = 8 * SUBB;         // 64 append segments per bucket

  char* w = (char*)d_ws;
  auto carve = [&](size_t bytes) {
    char* p = w; w += (bytes + 255) & ~(size_t)255; return p;
  };
  int*      bcnt   = (int*)     carve((size_t)NB * NSEG * 4);
  unsigned* bucket = (unsigned*)carve((size_t)NB * NSEG * BCAP_S * 4);  // 32 MB
  int*      ncnt   = (int*)     carve((size_t)N * 4);
  int*      dense  = (int*)     carve((size_t)N * DENSW * 4);      // 25.6 MB
  float*    dinv   = (float*)   carve((size_t)N * 4);
  f16*      x16    = (f16*)     carve((size_t)NP * 160 * 2);
  f16*      S      = (f16*)     carve((size_t)NP * 128 * 2);
  f16*      xg     = (f16*)     carve((size_t)NP * 160 * 2);
  f16*      u      = (f16*)     carve((size_t)N  * 128 * 2);
  f16*      G      = (f16*)     carve((size_t)N  * 128 * 2);
  f16*      H      = (f16*)     carve((size_t)NP * 128 * 2);
  f16*      Wt_f1  = (f16*)     carve(160 * 128 * 2);
  f16*      Wt_f2  = (f16*)     carve(128 * 144 * 2);
  f16*      Wt_u1  = (f16*)     carve(160 * 128 * 2);
  f16*      Wt_u2  = (f16*)     carve(128 * 128 * 2);
  f16*      Wt_c1  = (f16*)     carve(160 * 128 * 2);
  f16*      Wt_c2  = (f16*)     carve(128 * 128 * 2);
  f16*      Wt_c3  = (f16*)     carve(128 * 128 * 2);
  f16*      Wt_c4  = (f16*)     carve(128 * 128 * 2);
  f16*      Wt_co  = (f16*)     carve(128 * 128 * 2);

  const int* erow = ei;
  const int* ecol = ei + E;

  const int gE = (E + 255) / 256;
  const int gM = (N + 127) / 128;
  const int gA = (N + 3) / 4;

  // weight/x prep
  WAll wa;
  wa.m[0] = {Wf1, Wt_f1, HC,  HID, 160, 128};
  wa.m[1] = {Wf2, Wt_f2, HID, HC,  128, 144};
  wa.m[2] = {Wu1, Wt_u1, HC,  HID, 160, 128};
  wa.m[3] = {Wu2, Wt_u2, HID, HID, 128, 128};
  wa.m[4] = {Wc1, Wt_c1, HC,  HID, 160, 128};
  wa.m[5] = {Wc2, Wt_c2, HID, HID, 128, 128};
  wa.m[6] = {Wc3, Wt_c3, HID, HID, 128, 128};
  wa.m[7] = {Wc4, Wt_c4, HID, HID, 128, 128};
  wa.m[8] = {Wco, Wt_co, HID, HID, 128, 128};
  wprep_kernel<<<dim3(10, 9), 256, 0, stream>>>(wa);
  xprep_kernel<<<(N * 160 + 255) / 256, 256, 0, stream>>>(x, x16, xg, N);

  // graph build (two-level binning)
  zero_int_kernel<<<(NB * NSEG + 255) / 256, 256, 0, stream>>>(bcnt, NB * NSEG);
  binscatter_kernel<<<gE, 256, 0, stream>>>(erow, ecol, bcnt, bucket, E, NB);
  build_kernel<<<NB, 256, 0, stream>>>(bcnt, bucket, ncnt, dense, dinv, N, NB);

  // forget gate
  mm_mfma<160, 160, 128, 128, 0><<<gM, 256, 0, stream>>>(x16, Wt_f1, bf1, S,  nullptr, nullptr, nullptr, N, NG);
  mm_mfma<128, 128, 144, 130, 1><<<gM, 256, 0, stream>>>(S,   Wt_f2, bf2, xg, nullptr, x16, initial, N, NG);
  // update gate
  mm_mfma<160, 160, 128, 128, 0><<<gM, 256, 0, stream>>>(xg,  Wt_u1, bu1, S,  nullptr, nullptr, nullptr, N, NG);
  mm_mfma<128, 128, 128, 128, 0><<<gM, 256, 0, stream>>>(S,   Wt_u2, bu2, u,  nullptr, nullptr, nullptr, N, NG);

  // gcn1: relu(LN(..., g3, bn3))
  mm_mfma<160, 160, 128, 128, 2><<<gM, 256, 0, stream>>>(xg, Wt_c1, nullptr, G, dinv, nullptr, nullptr, N, NG);
  agg_kernel<0><<<gA, 256, 0, stream>>>(G, ncnt, dense, dinv, bc1, g3, bn3, nullptr, nullptr, H, N);
  // gcn2: LN(..., g3, bn3)
  mm_mfma<128, 128, 128, 128, 2><<<gM, 256, 0, stream>>>(H, Wt_c2, nullptr, G, dinv, nullptr, nullptr, N, NG);
  agg_kernel<1><<<gA, 256, 0, stream>>>(G, ncnt, dense, dinv, bc2, g3, bn3, nullptr, nullptr, H, N);
  // gcn3: LN(..., g6, bn6)
  mm_mfma<128, 128, 128, 128, 2><<<gM, 256, 0, stream>>>(H, Wt_c3, nullptr, G, dinv, nullptr, nullptr, N, NG);
  agg_kernel<1><<<gA, 256, 0, stream>>>(G, ncnt, dense, dinv, bc3, g6, bn6, nullptr, nullptr, H, N);
  // gcn4: LN(..., g7, bn7)
  mm_mfma<128, 128, 128, 128, 2><<<gM, 256, 0, stream>>>(H, Wt_c4, nullptr, G, dinv, nullptr, nullptr, N, NG);
  agg_kernel<1><<<gA, 256, 0, stream>>>(G, ncnt, dense, dinv, bc4, g7, bn7, nullptr, nullptr, H, N);
  // gcn5 + final: out = xg[:, :128] + (agg + bco) * u
  mm_mfma<128, 128, 128, 128, 2><<<gM, 256, 0, stream>>>(H, Wt_co, nullptr, G, dinv, nullptr, nullptr, N, NG);
  agg_kernel<2><<<gA, 256, 0, stream>>>(G, ncnt, dense, dinv, bco, nullptr, nullptr, xg, u, d_out, N);
}

// Round 5
// 785.669 us; speedup vs baseline: 1.1489x; 1.0121x over previous
//
#include <hip/hip_runtime.h>
#include <cstdint>

#define HID 128
#define HC  130
#define NIO 128
#define DENSW 64     // dense ELL width (max in-degree ~45 for Poisson(16))
#define SUBB 8       // sub-cursors per (xcd,bucket): kills same-address atomic serialization
#define BCAP_S 160   // per-(xcd,sub,bucket) capacity; mean ~32, 5x margin

typedef _Float16 f16;
typedef _Float16 f16x2 __attribute__((ext_vector_type(2)));
typedef _Float16 f16x8 __attribute__((ext_vector_type(8)));
typedef float    f32x4 __attribute__((ext_vector_type(4)));

__device__ __forceinline__ float sigm(float z) {
  return 1.0f / (1.0f + __expf(-z));
}

__device__ __forceinline__ int xcc_id() {
  int x;
  asm volatile("s_getreg_b32 %0, hwreg(HW_REG_XCC_ID)" : "=s"(x));
  return x & 7;
}

// Packed f16 max: v_pk_max_f16 does 2 elements/op. The C ternary lowers to
// v_cmp+v_cndmask (2 ops/element) -> 4x the VALU. Inputs are finite
// (sigmoid/LN outputs), so fmax semantics are safe.
__device__ __forceinline__ f16x8 max8(f16x8 a, f16x8 b) {
  union P { f16x8 h; f16x2 p[4]; } A, B, O;
  A.h = a; B.h = b;
  #pragma unroll
  for (int i = 0; i < 4; ++i)
    asm("v_pk_max_f16 %0, %1, %2" : "=v"(O.p[i]) : "v"(A.p[i]), "v"(B.p[i]));
  return O.h;
}

// ---------------- graph build: two-level binning ----------------
__global__ void zero_int_kernel(int* __restrict__ p, int n) {
  int i = blockIdx.x * blockDim.x + threadIdx.x;
  if (i < n) p[i] = 0;
}

// Pass 1: bin edges into per-(XCD,sub, bucket=c>>7) append buffers.
// sub = (blockIdx.x>>3)&7 is DEcorrelated from xcc_id (dispatch is ~round-robin
// in blockIdx). 64 segments: ~32 colliding atomics per counter and a 200 KB
// counter window spread over all channels.
__global__ void binscatter_kernel(const int* __restrict__ row, const int* __restrict__ col,
    int* __restrict__ bcnt, unsigned* __restrict__ bucket, int e, int nb) {
  const int g0 = xcc_id() * SUBB + ((blockIdx.x >> 3) & (SUBB - 1));
  int i = blockIdx.x * blockDim.x + threadIdx.x;
  if (i >= e) return;
  int c = col[i], r = row[i];
  int b = c >> 7;
  int cur = atomicAdd(&bcnt[g0 * nb + b], 1);
  if (cur < BCAP_S)
    bucket[((size_t)g0 * nb + b) * BCAP_S + cur] = ((unsigned)r << 7) | (unsigned)(c & 127);
}

// Pass 2: one block per bucket. Each of the 4 waves independently drains 16 of
// the 64 segments (LDS atomics; no inter-segment barriers). Fuses ncnt + dinv.
__global__ __launch_bounds__(256) void build_kernel(const int* __restrict__ bcnt,
    const unsigned* __restrict__ bucket, int* __restrict__ ncnt,
    int* __restrict__ dense, float* __restrict__ dinv, int n, int nb) {
  __shared__ int lcnt[128];
  const int b = blockIdx.x;
  const int t = threadIdx.x;
  if (t < 128) lcnt[t] = 0;
  __syncthreads();
  const int wv = t >> 6, ln = t & 63;
  #pragma unroll 1
  for (int g = wv * 16; g < wv * 16 + 16; ++g) {
    const int cntg = min(bcnt[g * nb + b], BCAP_S);
    const unsigned* __restrict__ src = bucket + ((size_t)g * nb + b) * BCAP_S;
    for (int idx = ln; idx < cntg; idx += 64) {
      unsigned ev = src[idx];
      int cl = (int)(ev & 127u);
      int r  = (int)(ev >> 7);
      int s = atomicAdd(&lcnt[cl], 1);
      if (s < DENSW) dense[(size_t)((b << 7) + cl) * DENSW + s] = r;
    }
  }
  __syncthreads();
  if (t < 128) {
    int c = (b << 7) + t;
    if (c < n) {
      int cc = min(lcnt[t], DENSW);
      ncnt[c] = cc;
      dinv[c] = rsqrtf((float)(cc + 1));  // +1 self-loop
    }
  }
}

// ---------------- prep: weights -> frag-ordered fp16 ----------------
struct WDesc { const float* src; f16* dst; int K, NC, Kpad, NCpad; };
struct WAll { WDesc m[9]; };

__global__ __launch_bounds__(256) void wprep_kernel(WAll wa) {
  const WDesc d = wa.m[blockIdx.y];
  const int KST = d.Kpad >> 5;
  const int total = (d.NCpad >> 4) * KST * 64;
  int idx = blockIdx.x * 256 + threadIdx.x;
  if (idx >= total) return;
  int nt  = idx / (KST * 64);
  int rem = idx - nt * (KST * 64);
  int ks  = rem >> 6;
  int l   = rem & 63;
  int n   = nt * 16 + (l & 15);
  int k0  = ks * 32 + (l >> 4) * 8;
  f16x8 o;
  #pragma unroll
  for (int j = 0; j < 8; ++j) {
    int k = k0 + j;
    float v = (k < d.K && n < d.NC) ? d.src[(size_t)k * d.NC + n] : 0.0f;
    o[j] = (f16)v;
  }
  *((f16x8*)d.dst + idx) = o;
}

__global__ void xprep_kernel(const float* __restrict__ x, f16* __restrict__ x16,
                             f16* __restrict__ xg, int n) {
  int idx = blockIdx.x * blockDim.x + threadIdx.x;
  if (idx >= n * 160) return;
  int r = idx / 160, c = idx - r * 160;
  x16[idx] = (f16)((c < 130) ? x[(size_t)r * 130 + c] : 0.0f);
  if (c >= 130) xg[idx] = (f16)0.0f;
}

// ---------------- MFMA matmul ----------------
// Y[N,NC] = X[N,K] @ W[K,NC], fp16 in / fp32 acc / fp16 out, fused epilogue.
// MODE 0: Y = sigmoid(acc+bias); MODE 1: forget-gate mix (NC=130, Y stride 160);
// MODE 2: Y = acc * dinv[row].
// Epilogue via LDS transpose; PSTR % 16 == 4 -> conflict-free acc scatter.
// MODE 1 reads the mix input from the f16 x16 copy, prefetched into registers
// BEFORE the transpose barrier so its latency hides under the MFMA main loop.
template<int KPAD, int RS, int NCPAD, int NC, int MODE>
__global__ __launch_bounds__(256, 4) void mm_mfma(
    const f16* __restrict__ X, const f16* __restrict__ Wt,
    const float* __restrict__ bias, f16* __restrict__ Y,
    const float* __restrict__ dinv, const f16* __restrict__ xor16,
    const float* __restrict__ initial, int n, int ngrid)
{
  constexpr int KST = KPAD / 32;
  constexpr int NT  = NCPAD / 16;
  constexpr int YRS = (MODE == 1) ? 160 : 128;
  constexpr int PSTR = (NCPAD == 128) ? 132 : 148;  // %16 == 4
  constexpr int LDSH = (NCPAD * KPAD > 128 * PSTR) ? NCPAD * KPAD : 128 * PSTR;
  __shared__ f16 Bs[LDSH];

  const int t = threadIdx.x;
  constexpr int BSW = NCPAD * KPAD / 8;
  #pragma unroll
  for (int i = 0; i < (BSW + 255) / 256; ++i) {
    int idx = t + i * 256;
    if (BSW % 256 == 0 || idx < BSW)
      ((f16x8*)Bs)[idx] = ((const f16x8*)Wt)[idx];
  }

  // --- MODE 1: prefetch the x-mix row chunk into registers (16B aligned,
  // rows padded to NP so OOB rows are readable garbage; stores are guarded).
  f16x8 xo[8];
  f16x2 xo2;
  if constexpr (MODE == 1) {
    const int r_ep  = t >> 1;
    const int hf_ep = t & 1;
    const f16* xp = xor16 + (size_t)(blockIdx.x * 128 + r_ep) * 160;
    #pragma unroll
    for (int c8 = 0; c8 < 8; ++c8)
      xo[c8] = *(const f16x8*)(xp + hf_ep * 64 + c8 * 8);
    xo2 = *(const f16x2*)(xp + 128);
  }

  __syncthreads();

  const int wid  = t >> 6;
  const int l    = t & 63;
  const int m15  = l & 15;
  const int quad = l >> 4;
  const int rw   = blockIdx.x * 128 + wid * 32;

  f32x4 acc[2][NT];
  #pragma unroll
  for (int mt = 0; mt < 2; ++mt)
    #pragma unroll
    for (int nt = 0; nt < NT; ++nt)
      acc[mt][nt] = (f32x4){0.f, 0.f, 0.f, 0.f};

  const f16* Xr0 = X + (size_t)(rw + m15) * RS;
  const f16* Xr1 = X + (size_t)(rw + 16 + m15) * RS;

  #pragma unroll
  for (int ks = 0; ks < KST; ++ks) {
    const int off = ks * 32 + quad * 8;
    f16x8 a0 = *(const f16x8*)(Xr0 + off);
    f16x8 a1 = *(const f16x8*)(Xr1 + off);
    #pragma unroll
    for (int nt = 0; nt < NT; ++nt) {
      f16x8 b = *((const f16x8*)Bs + (nt * KST + ks) * 64 + l);
      acc[0][nt] = __builtin_amdgcn_mfma_f32_16x16x32_f16(a0, b, acc[0][nt], 0, 0, 0);
      acc[1][nt] = __builtin_amdgcn_mfma_f32_16x16x32_f16(a1, b, acc[1][nt], 0, 0, 0);
    }
  }

  __syncthreads();  // done reading Bs; reuse as transpose tile

  #pragma unroll
  for (int mt = 0; mt < 2; ++mt) {
    #pragma unroll
    for (int reg = 0; reg < 4; ++reg) {
      const int rl = wid * 32 + mt * 16 + quad * 4 + reg;
      #pragma unroll
      for (int nt = 0; nt < NT; ++nt)
        Bs[rl * PSTR + nt * 16 + m15] = (f16)acc[mt][nt][reg];
    }
  }
  __syncthreads();

  const int r  = t >> 1;
  const int hf = t & 1;
  const int gr = blockIdx.x * 128 + r;
  if (gr < n) {
    if constexpr (MODE == 0 || MODE == 2) {
      float dv = 0.0f;
      if constexpr (MODE == 2) dv = dinv[gr];
      #pragma unroll
      for (int c8 = 0; c8 < 8; ++c8) {
        const int c0 = hf * 64 + c8 * 8;
        f16x8 v = *(const f16x8*)&Bs[r * PSTR + c0];
        f16x8 o;
        #pragma unroll
        for (int j = 0; j < 8; ++j) {
          float a = (float)v[j];
          if constexpr (MODE == 0) o[j] = (f16)sigm(a + bias[c0 + j]);
          else                     o[j] = (f16)(a * dv);
        }
        *(f16x8*)&Y[(size_t)gr * YRS + c0] = o;
      }
    } else {  // MODE 1, NC=130
      const bool hasInit = (gr >= ngrid);
      #pragma unroll
      for (int c8 = 0; c8 < 8; ++c8) {
        const int c0 = hf * 64 + c8 * 8;
        f16x8 v = *(const f16x8*)&Bs[r * PSTR + c0];
        f16x8 o;
        #pragma unroll
        for (int j = 0; j < 8; ++j) {
          const int col = c0 + j;
          float fv = sigm((float)v[j] + bias[col]);
          float xov = (float)xo[c8][j];
          float ip = hasInit ? initial[(size_t)(gr - ngrid) * 128 + col] : 0.0f;
          o[j] = (f16)(xov * fv + (1.0f - fv) * ip);
        }
        *(f16x8*)&Y[(size_t)gr * YRS + c0] = o;
      }
      if (hf) {
        #pragma unroll
        for (int k = 0; k < 2; ++k) {
          const int col = 128 + k;
          float fv = sigm((float)Bs[r * PSTR + col] + bias[col]);
          Y[(size_t)gr * YRS + col] = (f16)((float)xo2[k] * fv);
        }
      }
    }
  }
}

// ---------------- aggregation (lane-group batched gather) ----------------
// One wave per dest; 16 lanes x 16 B per row -> 4 rows per vmem instr.
// All 64 ELL indices are loaded upfront with ONE coalesced per-lane load
// (defaulted to the self row for lane>=nc -- max-idempotent), so per-batch
// indices come from __shfl (LDS pipe) instead of chained global loads.
// 4-way interleaved accumulators -> up to 64 lines in flight per wave.
template<int MODE>
__global__ __launch_bounds__(256) void agg_kernel(
    const f16* __restrict__ G, const int* __restrict__ ncnt,
    const int* __restrict__ dense,
    const float* __restrict__ dinv, const float* __restrict__ bias,
    const float* __restrict__ gamma, const float* __restrict__ beta,
    const f16* __restrict__ xg, const f16* __restrict__ u,
    void* __restrict__ out, int n)
{
  const int wid = threadIdx.x >> 6, lane = threadIdx.x & 63;
  const int c = blockIdx.x * 4 + wid;
  if (c >= n) return;
  const int li = lane & 15, grp = lane >> 4;

  union F8 { f16x8 h; int4 i; };
  const int nc = min(ncnt[c], DENSW);
  const int raw = dense[(size_t)c * DENSW + lane];   // coalesced; junk if lane>=nc
  const int myidx = (lane < nc) ? raw : c;           // self row is max-idempotent

  F8 m; m.h = *(const f16x8*)(G + (size_t)c * 128 + li * 8);  // self-loop
  F8 m2; m2.h = m.h;
  F8 m3; m3.h = m.h;
  F8 m4; m4.h = m.h;
  const int B = (nc + 3) >> 2;
  int b = 0;
  for (; b + 3 < B; b += 4) {
    int r0 = __shfl(myidx, (b + 0) * 4 + grp, 64);
    int r1 = __shfl(myidx, (b + 1) * 4 + grp, 64);
    int r2 = __shfl(myidx, (b + 2) * 4 + grp, 64);
    int r3 = __shfl(myidx, (b + 3) * 4 + grp, 64);
    F8 v0; v0.h = *(const f16x8*)(G + (size_t)r0 * 128 + li * 8);
    F8 v1; v1.h = *(const f16x8*)(G + (size_t)r1 * 128 + li * 8);
    F8 v2; v2.h = *(const f16x8*)(G + (size_t)r2 * 128 + li * 8);
    F8 v3; v3.h = *(const f16x8*)(G + (size_t)r3 * 128 + li * 8);
    m.h  = max8(m.h,  v0.h);
    m2.h = max8(m2.h, v1.h);
    m3.h = max8(m3.h, v2.h);
    m4.h = max8(m4.h, v3.h);
  }
  for (; b < B; ++b) {
    int r0 = __shfl(myidx, b * 4 + grp, 64);
    F8 v; v.h = *(const f16x8*)(G + (size_t)r0 * 128 + li * 8);
    m.h = max8(m.h, v.h);
  }
  m.h = max8(max8(m.h, m2.h), max8(m3.h, m4.h));

  #pragma unroll
  for (int st = 16; st <= 32; st <<= 1) {
    F8 o;
    #pragma unroll
    for (int d = 0; d < 4; ++d) o.i[d] = __shfl_xor(m.i[d], st, 64);
    m.h = max8(m.h, o.h);
  }

  const float dc = dinv[c];
  float v[8];
  float s = 0.f, sq = 0.f;
  #pragma unroll
  for (int j = 0; j < 8; ++j) {
    v[j] = (float)m.h[j] * dc + bias[li * 8 + j];
    s += v[j]; sq += v[j] * v[j];
  }

  if constexpr (MODE == 2) {
    if (grp == 0) {
      f16x8 xv = *(const f16x8*)(xg + (size_t)c * 160 + li * 8);
      f16x8 uv = *(const f16x8*)(u  + (size_t)c * 128 + li * 8);
      float o[8];
      #pragma unroll
      for (int j = 0; j < 8; ++j) o[j] = (float)xv[j] + v[j] * (float)uv[j];
      float* op = (float*)out + (size_t)c * 128 + li * 8;
      *(float4*)op       = make_float4(o[0], o[1], o[2], o[3]);
      *(float4*)(op + 4) = make_float4(o[4], o[5], o[6], o[7]);
    }
  } else {
    #pragma unroll
    for (int st = 1; st <= 8; st <<= 1) {
      s  += __shfl_xor(s, st, 64);
      sq += __shfl_xor(sq, st, 64);
    }
    float mu  = s * (1.0f / 128.0f);
    float var = sq * (1.0f / 128.0f) - mu * mu;
    float rstd = rsqrtf(var + 1e-5f);
    if (grp == 0) {
      f16x8 ov;
      #pragma unroll
      for (int j = 0; j < 8; ++j) {
        float o = (v[j] - mu) * rstd * gamma[li * 8 + j] + beta[li * 8 + j];
        if constexpr (MODE == 0) o = fmaxf(o, 0.0f);
        ov[j] = (f16)o;
      }
      *(f16x8*)((f16*)out + (size_t)c * 128 + li * 8) = ov;
    }
  }
}

extern "C" void kernel_launch(void* const* d_in, const int* in_sizes, int n_in,
                              void* d_out, int out_size, void* d_ws, size_t ws_size,
                              hipStream_t stream) {
  (void)n_in; (void)out_size; (void)ws_size;
  const float* x       = (const float*)d_in[0];
  const int*   ei      = (const int*)d_in[1];
  const float* initial = (const float*)d_in[2];
  const float* Wf1 = (const float*)d_in[3];  const float* bf1 = (const float*)d_in[4];
  const float* Wf2 = (const float*)d_in[5];  const float* bf2 = (const float*)d_in[6];
  const float* Wu1 = (const float*)d_in[7];  const float* bu1 = (const float*)d_in[8];
  const float* Wu2 = (const float*)d_in[9];  const float* bu2 = (const float*)d_in[10];
  const float* Wc1 = (const float*)d_in[11]; const float* bc1 = (const float*)d_in[12];
  const float* Wc2 = (const float*)d_in[13]; const float* bc2 = (const float*)d_in[14];
  const float* Wc3 = (const float*)d_in[15]; const float* bc3 = (const float*)d_in[16];
  const float* Wc4 = (const float*)d_in[17]; const float* bc4 = (const float*)d_in[18];
  const float* Wco = (const float*)d_in[19]; const float* bco = (const float*)d_in[20];
  const float* g3  = (const float*)d_in[21]; const float* bn3 = (const float*)d_in[22];
  const float* g6  = (const float*)d_in[23]; const float* bn6 = (const float*)d_in[24];
  const float* g7  = (const float*)d_in[25]; const float* bn7 = (const float*)d_in[26];

  const int N  = in_sizes[0] / HC;   // 100000
  const int E  = in_sizes[1] / 2;    // 1600000
  const int NG = N - NIO;            // 99872
  const int NP = N + 128;            // padded rows for OOB-safe A-frag loads
  const int NB = (N + 127) / 128;    // 782 coarse buckets
  const int NSEG = 8 * SUBB;         // 64 append segments per bucket

  char* w = (char*)d_ws;
  auto carve = [&](size_t bytes) {
    char* p = w; w += (bytes + 255) & ~(size_t)255; return p;
  };
  int*      bcnt   = (int*)     carve((size_t)NB * NSEG * 4);
  unsigned* bucket = (unsigned*)carve((size_t)NB * NSEG * BCAP_S * 4);  // 32 MB
  int*      ncnt   = (int*)     carve((size_t)N * 4);
  int*      dense  = (int*)     carve((size_t)N * DENSW * 4);      // 25.6 MB
  float*    dinv   = (float*)   carve((size_t)N * 4);
  f16*      x16    = (f16*)     carve((size_t)NP * 160 * 2);
  f16*      S      = (f16*)     carve((size_t)NP * 128 * 2);
  f16*      xg     = (f16*)     carve((size_t)NP * 160 * 2);
  f16*      u      = (f16*)     carve((size_t)N  * 128 * 2);
  f16*      G      = (f16*)     carve((size_t)N  * 128 * 2);
  f16*      H      = (f16*)     carve((size_t)NP * 128 * 2);
  f16*      Wt_f1  = (f16*)     carve(160 * 128 * 2);
  f16*      Wt_f2  = (f16*)     carve(128 * 144 * 2);
  f16*      Wt_u1  = (f16*)     carve(160 * 128 * 2);
  f16*      Wt_u2  = (f16*)     carve(128 * 128 * 2);
  f16*      Wt_c1  = (f16*)     carve(160 * 128 * 2);
  f16*      Wt_c2  = (f16*)     carve(128 * 128 * 2);
  f16*      Wt_c3  = (f16*)     carve(128 * 128 * 2);
  f16*      Wt_c4  = (f16*)     carve(128 * 128 * 2);
  f16*      Wt_co  = (f16*)     carve(128 * 128 * 2);

  const int* erow = ei;
  const int* ecol = ei + E;

  const int gE = (E + 255) / 256;
  const int gM = (N + 127) / 128;
  const int gA = (N + 3) / 4;

  // weight/x prep
  WAll wa;
  wa.m[0] = {Wf1, Wt_f1, HC,  HID, 160, 128};
  wa.m[1] = {Wf2, Wt_f2, HID, HC,  128, 144};
  wa.m[2] = {Wu1, Wt_u1, HC,  HID, 160, 128};
  wa.m[3] = {Wu2, Wt_u2, HID, HID, 128, 128};
  wa.m[4] = {Wc1, Wt_c1, HC,  HID, 160, 128};
  wa.m[5] = {Wc2, Wt_c2, HID, HID, 128, 128};
  wa.m[6] = {Wc3, Wt_c3, HID, HID, 128, 128};
  wa.m[7] = {Wc4, Wt_c4, HID, HID, 128, 128};
  wa.m[8] = {Wco, Wt_co, HID, HID, 128, 128};
  wprep_kernel<<<dim3(10, 9), 256, 0, stream>>>(wa);
  xprep_kernel<<<(N * 160 + 255) / 256, 256, 0, stream>>>(x, x16, xg, N);

  // graph build (two-level binning)
  zero_int_kernel<<<(NB * NSEG + 255) / 256, 256, 0, stream>>>(bcnt, NB * NSEG);
  binscatter_kernel<<<gE, 256, 0, stream>>>(erow, ecol, bcnt, bucket, E, NB);
  build_kernel<<<NB, 256, 0, stream>>>(bcnt, bucket, ncnt, dense, dinv, N, NB);

  // forget gate
  mm_mfma<160, 160, 128, 128, 0><<<gM, 256, 0, stream>>>(x16, Wt_f1, bf1, S,  nullptr, nullptr, nullptr, N, NG);
  mm_mfma<128, 128, 144, 130, 1><<<gM, 256, 0, stream>>>(S,   Wt_f2, bf2, xg, nullptr, x16, initial, N, NG);
  // update gate
  mm_mfma<160, 160, 128, 128, 0><<<gM, 256, 0, stream>>>(xg,  Wt_u1, bu1, S,  nullptr, nullptr, nullptr, N, NG);
  mm_mfma<128, 128, 128, 128, 0><<<gM, 256, 0, stream>>>(S,   Wt_u2, bu2, u,  nullptr, nullptr, nullptr, N, NG);

  // gcn1: relu(LN(..., g3, bn3))
  mm_mfma<160, 160, 128, 128, 2><<<gM, 256, 0, stream>>>(xg, Wt_c1, nullptr, G, dinv, nullptr, nullptr, N, NG);
  agg_kernel<0><<<gA, 256, 0, stream>>>(G, ncnt, dense, dinv, bc1, g3, bn3, nullptr, nullptr, H, N);
  // gcn2: LN(..., g3, bn3)
  mm_mfma<128, 128, 128, 128, 2><<<gM, 256, 0, stream>>>(H, Wt_c2, nullptr, G, dinv, nullptr, nullptr, N, NG);
  agg_kernel<1><<<gA, 256, 0, stream>>>(G, ncnt, dense, dinv, bc2, g3, bn3, nullptr, nullptr, H, N);
  // gcn3: LN(..., g6, bn6)
  mm_mfma<128, 128, 128, 128, 2><<<gM, 256, 0, stream>>>(H, Wt_c3, nullptr, G, dinv, nullptr, nullptr, N, NG);
  agg_kernel<1><<<gA, 256, 0, stream>>>(G, ncnt, dense, dinv, bc3, g6, bn6, nullptr, nullptr, H, N);
  // gcn4: LN(..., g7, bn7)
  mm_mfma<128, 128, 128, 128, 2><<<gM, 256, 0, stream>>>(H, Wt_c4, nullptr, G, dinv, nullptr, nullptr, N, NG);
  agg_kernel<1><<<gA, 256, 0, stream>>>(G, ncnt, dense, dinv, bc4, g7, bn7, nullptr, nullptr, H, N);
  // gcn5 + final: out = xg[:, :128] + (agg + bco) * u
  mm_mfma<128, 128, 128, 128, 2><<<gM, 256, 0, stream>>>(H, Wt_co, nullptr, G, dinv, nullptr, nullptr, N, NG);
  agg_kernel<2><<<gA, 256, 0, stream>>>(G, ncnt, dense, dinv, bco, nullptr, nullptr, xg, u, d_out, N);
}

// Round 6
// 751.714 us; speedup vs baseline: 1.2008x; 1.0452x over previous
//
#include <hip/hip_runtime.h>
#include <cstdint>

#define HID 128
#define HC  130
#define NIO 128
#define DENSW 64     // dense ELL width (max in-degree ~45 for Poisson(16))
#define SUBB 8       // sub-cursors per (xcd,bucket): kills same-address atomic serialization
#define BCAP_S 160   // per-(xcd,sub,bucket) capacity; mean ~32, 5x margin

typedef _Float16 f16;
typedef _Float16 f16x2 __attribute__((ext_vector_type(2)));
typedef _Float16 f16x4 __attribute__((ext_vector_type(4)));
typedef _Float16 f16x8 __attribute__((ext_vector_type(8)));
typedef float    f32x4 __attribute__((ext_vector_type(4)));

__device__ __forceinline__ float sigm(float z) {
  return 1.0f / (1.0f + __expf(-z));
}

__device__ __forceinline__ int xcc_id() {
  int x;
  asm volatile("s_getreg_b32 %0, hwreg(HW_REG_XCC_ID)" : "=s"(x));
  return x & 7;
}

// Packed f16 max: v_pk_max_f16 does 2 elements/op (ternary lowers to
// v_cmp+v_cndmask = 4x the VALU). Inputs finite (sigmoid/LN outputs).
__device__ __forceinline__ f16x8 max8(f16x8 a, f16x8 b) {
  union P { f16x8 h; f16x2 p[4]; } A, B, O;
  A.h = a; B.h = b;
  #pragma unroll
  for (int i = 0; i < 4; ++i)
    asm("v_pk_max_f16 %0, %1, %2" : "=v"(O.p[i]) : "v"(A.p[i]), "v"(B.p[i]));
  return O.h;
}

// ---------------- graph build: two-level binning ----------------
__global__ void zero_int_kernel(int* __restrict__ p, int n) {
  int i = blockIdx.x * blockDim.x + threadIdx.x;
  if (i < n) p[i] = 0;
}

__global__ void binscatter_kernel(const int* __restrict__ row, const int* __restrict__ col,
    int* __restrict__ bcnt, unsigned* __restrict__ bucket, int e, int nb) {
  const int g0 = xcc_id() * SUBB + ((blockIdx.x >> 3) & (SUBB - 1));
  int i = blockIdx.x * blockDim.x + threadIdx.x;
  if (i >= e) return;
  int c = col[i], r = row[i];
  int b = c >> 7;
  int cur = atomicAdd(&bcnt[g0 * nb + b], 1);
  if (cur < BCAP_S)
    bucket[((size_t)g0 * nb + b) * BCAP_S + cur] = ((unsigned)r << 7) | (unsigned)(c & 127);
}

__global__ __launch_bounds__(256) void build_kernel(const int* __restrict__ bcnt,
    const unsigned* __restrict__ bucket, int* __restrict__ ncnt,
    int* __restrict__ dense, float* __restrict__ dinv, int n, int nb) {
  __shared__ int lcnt[128];
  const int b = blockIdx.x;
  const int t = threadIdx.x;
  if (t < 128) lcnt[t] = 0;
  __syncthreads();
  const int wv = t >> 6, ln = t & 63;
  #pragma unroll 1
  for (int g = wv * 16; g < wv * 16 + 16; ++g) {
    const int cntg = min(bcnt[g * nb + b], BCAP_S);
    const unsigned* __restrict__ src = bucket + ((size_t)g * nb + b) * BCAP_S;
    for (int idx = ln; idx < cntg; idx += 64) {
      unsigned ev = src[idx];
      int cl = (int)(ev & 127u);
      int r  = (int)(ev >> 7);
      int s = atomicAdd(&lcnt[cl], 1);
      if (s < DENSW) dense[(size_t)((b << 7) + cl) * DENSW + s] = r;
    }
  }
  __syncthreads();
  if (t < 128) {
    int c = (b << 7) + t;
    if (c < n) {
      int cc = min(lcnt[t], DENSW);
      ncnt[c] = cc;
      dinv[c] = rsqrtf((float)(cc + 1));  // +1 self-loop
    }
  }
}

// ---------------- prep: weights -> frag-ordered fp16 ----------------
struct WDesc { const float* src; f16* dst; int K, NC, Kpad, NCpad; };
struct WAll { WDesc m[9]; };

__global__ __launch_bounds__(256) void wprep_kernel(WAll wa) {
  const WDesc d = wa.m[blockIdx.y];
  const int KST = d.Kpad >> 5;
  const int total = (d.NCpad >> 4) * KST * 64;
  int idx = blockIdx.x * 256 + threadIdx.x;
  if (idx >= total) return;
  int nt  = idx / (KST * 64);
  int rem = idx - nt * (KST * 64);
  int ks  = rem >> 6;
  int l   = rem & 63;
  int n   = nt * 16 + (l & 15);
  int k0  = ks * 32 + (l >> 4) * 8;
  f16x8 o;
  #pragma unroll
  for (int j = 0; j < 8; ++j) {
    int k = k0 + j;
    float v = (k < d.K && n < d.NC) ? d.src[(size_t)k * d.NC + n] : 0.0f;
    o[j] = (f16)v;
  }
  *((f16x8*)d.dst + idx) = o;
}

__global__ void xprep_kernel(const float* __restrict__ x, f16* __restrict__ x16,
                             f16* __restrict__ xg, int n) {
  int idx = blockIdx.x * blockDim.x + threadIdx.x;
  if (idx >= n * 160) return;
  int r = idx / 160, c = idx - r * 160;
  x16[idx] = (f16)((c < 130) ? x[(size_t)r * 130 + c] : 0.0f);
  if (c >= 130) xg[idx] = (f16)0.0f;
}

// ---------------- MFMA matmul (single, MODE 2 only now) ----------------
// Y[N,NC] = X[N,K] @ W[K,NC]; MODE 2: Y = acc * dinv[row].
template<int KPAD, int RS, int NCPAD, int NC, int MODE>
__global__ __launch_bounds__(256, 4) void mm_mfma(
    const f16* __restrict__ X, const f16* __restrict__ Wt,
    const float* __restrict__ bias, f16* __restrict__ Y,
    const float* __restrict__ dinv, const f16* __restrict__ xor16,
    const float* __restrict__ initial, int n, int ngrid)
{
  constexpr int KST = KPAD / 32;
  constexpr int NT  = NCPAD / 16;
  constexpr int YRS = (MODE == 1) ? 160 : 128;
  constexpr int PSTR = (NCPAD == 128) ? 132 : 148;  // %16 == 4
  constexpr int LDSH = (NCPAD * KPAD > 128 * PSTR) ? NCPAD * KPAD : 128 * PSTR;
  __shared__ __align__(16) f16 Bs[LDSH];

  const int t = threadIdx.x;
  constexpr int BSW = NCPAD * KPAD / 8;
  #pragma unroll
  for (int i = 0; i < (BSW + 255) / 256; ++i) {
    int idx = t + i * 256;
    if (BSW % 256 == 0 || idx < BSW)
      ((f16x8*)Bs)[idx] = ((const f16x8*)Wt)[idx];
  }

  f16x8 xo[8];
  f16x2 xo2;
  if constexpr (MODE == 1) {
    const f16* xp = xor16 + (size_t)(blockIdx.x * 128 + (t >> 1)) * 160;
    #pragma unroll
    for (int c8 = 0; c8 < 8; ++c8)
      xo[c8] = *(const f16x8*)(xp + (t & 1) * 64 + c8 * 8);
    xo2 = *(const f16x2*)(xp + 128);
  }

  __syncthreads();

  const int wid  = t >> 6;
  const int l    = t & 63;
  const int m15  = l & 15;
  const int quad = l >> 4;
  const int rw   = blockIdx.x * 128 + wid * 32;

  f32x4 acc[2][NT];
  #pragma unroll
  for (int mt = 0; mt < 2; ++mt)
    #pragma unroll
    for (int nt = 0; nt < NT; ++nt)
      acc[mt][nt] = (f32x4){0.f, 0.f, 0.f, 0.f};

  const f16* Xr0 = X + (size_t)(rw + m15) * RS;
  const f16* Xr1 = X + (size_t)(rw + 16 + m15) * RS;

  #pragma unroll
  for (int ks = 0; ks < KST; ++ks) {
    const int off = ks * 32 + quad * 8;
    f16x8 a0 = *(const f16x8*)(Xr0 + off);
    f16x8 a1 = *(const f16x8*)(Xr1 + off);
    #pragma unroll
    for (int nt = 0; nt < NT; ++nt) {
      f16x8 b = *((const f16x8*)Bs + (nt * KST + ks) * 64 + l);
      acc[0][nt] = __builtin_amdgcn_mfma_f32_16x16x32_f16(a0, b, acc[0][nt], 0, 0, 0);
      acc[1][nt] = __builtin_amdgcn_mfma_f32_16x16x32_f16(a1, b, acc[1][nt], 0, 0, 0);
    }
  }

  __syncthreads();  // done reading Bs; reuse as transpose tile

  #pragma unroll
  for (int mt = 0; mt < 2; ++mt) {
    #pragma unroll
    for (int reg = 0; reg < 4; ++reg) {
      const int rl = wid * 32 + mt * 16 + quad * 4 + reg;
      #pragma unroll
      for (int nt = 0; nt < NT; ++nt)
        Bs[rl * PSTR + nt * 16 + m15] = (f16)acc[mt][nt][reg];
    }
  }
  __syncthreads();

  const int r  = t >> 1;
  const int hf = t & 1;
  const int gr = blockIdx.x * 128 + r;
  if (gr < n) {
    if constexpr (MODE == 0 || MODE == 2) {
      float dv = 0.0f;
      if constexpr (MODE == 2) dv = dinv[gr];
      #pragma unroll
      for (int c8 = 0; c8 < 8; ++c8) {
        const int c0 = hf * 64 + c8 * 8;
        f16x8 v = *(const f16x8*)&Bs[r * PSTR + c0];
        f16x8 o;
        #pragma unroll
        for (int j = 0; j < 8; ++j) {
          float a = (float)v[j];
          if constexpr (MODE == 0) o[j] = (f16)sigm(a + bias[c0 + j]);
          else                     o[j] = (f16)(a * dv);
        }
        *(f16x8*)&Y[(size_t)gr * YRS + c0] = o;
      }
    } else {  // MODE 1, NC=130
      const bool hasInit = (gr >= ngrid);
      #pragma unroll
      for (int c8 = 0; c8 < 8; ++c8) {
        const int c0 = hf * 64 + c8 * 8;
        f16x8 v = *(const f16x8*)&Bs[r * PSTR + c0];
        f16x8 o;
        #pragma unroll
        for (int j = 0; j < 8; ++j) {
          const int col = c0 + j;
          float fv = sigm((float)v[j] + bias[col]);
          float xov = (float)xo[c8][j];
          float ip = hasInit ? initial[(size_t)(gr - ngrid) * 128 + col] : 0.0f;
          o[j] = (f16)(xov * fv + (1.0f - fv) * ip);
        }
        *(f16x8*)&Y[(size_t)gr * YRS + c0] = o;
      }
      if (hf) {
        #pragma unroll
        for (int k = 0; k < 2; ++k) {
          const int col = 128 + k;
          float fv = sigm((float)Bs[r * PSTR + col] + bias[col]);
          Y[(size_t)gr * YRS + col] = (f16)((float)xo2[k] * fv);
        }
      }
    }
  }
}

// ---------------- fused two-layer MLP ----------------
// Y = epilogue2( sigm(X@W1 + b1) @ W2 + b2 ).
// Stage 1 writes S (post-sigmoid) into the LDS transpose buffer; stage 2 reads
// A-fragments of S back from LDS (no HBM round trip for the 25.6 MB
// intermediate, one launch instead of two).
// MODE2 == 0: Y = sigm(acc2 + b2) [update gate, NC2=128, Y stride 128]
// MODE2 == 1: forget-gate mix     [NC2=130, Y stride 160]
template<int K1PAD, int RS1, int NC2PAD, int NC2, int MODE2>
__global__ __launch_bounds__(256, 2) void mm_fused(
    const f16* __restrict__ X, const f16* __restrict__ W1t, const f16* __restrict__ W2t,
    const float* __restrict__ b1, const float* __restrict__ b2, f16* __restrict__ Y,
    const f16* __restrict__ xor16, const float* __restrict__ initial, int n, int ngrid)
{
  constexpr int KST1 = K1PAD / 32;   // 5
  constexpr int NT1  = 8;            // mid = 128 cols
  constexpr int KST2 = 4;            // K2 = 128
  constexpr int NT2  = NC2PAD / 16;  // 8 or 9
  constexpr int PSTR1 = 132;         // %16==4: conflict-light scatter
  constexpr int PSTR2 = (NC2PAD == 128) ? 132 : 148;
  constexpr int YRS  = (MODE2 == 1) ? 160 : 128;
  constexpr int W2U  = NC2PAD * 128;                 // f16 units
  constexpr int SC_A = K1PAD * 128;                  // W1 frag area
  constexpr int SC_B = 128 * PSTR2;                  // tr2 area (>= tr1: PSTR2>=PSTR1)
  constexpr int SCU  = (SC_A > SC_B) ? SC_A : SC_B;
  __shared__ __align__(16) f16 L[W2U + SCU];
  f16* Bs2 = L;
  f16* SC  = L + W2U;

  const int t = threadIdx.x;
  constexpr int W1W = K1PAD * 128 / 8;
  constexpr int W2W = NC2PAD * 128 / 8;
  for (int i = t; i < W1W; i += 256) ((f16x8*)SC)[i]  = ((const f16x8*)W1t)[i];
  for (int i = t; i < W2W; i += 256) ((f16x8*)Bs2)[i] = ((const f16x8*)W2t)[i];

  // MODE2==1: prefetch x-mix rows early (latency hides under both MFMA stages)
  f16x8 xo[8];
  f16x2 xo2;
  if constexpr (MODE2 == 1) {
    const f16* xp = xor16 + (size_t)(blockIdx.x * 128 + (t >> 1)) * 160;
    #pragma unroll
    for (int c8 = 0; c8 < 8; ++c8)
      xo[c8] = *(const f16x8*)(xp + (t & 1) * 64 + c8 * 8);
    xo2 = *(const f16x2*)(xp + 128);
  }

  const int wid  = t >> 6;
  const int l    = t & 63;
  const int m15  = l & 15;
  const int quad = l >> 4;
  const int rw   = blockIdx.x * 128 + wid * 32;

  // stage-1 bias, one scalar per output col this lane owns
  float b1r[NT1];
  #pragma unroll
  for (int nt = 0; nt < NT1; ++nt) b1r[nt] = b1[nt * 16 + m15];

  __syncthreads();

  // ---- stage 1: acc1 = X @ W1 ----
  f32x4 acc1[2][NT1];
  #pragma unroll
  for (int mt = 0; mt < 2; ++mt)
    #pragma unroll
    for (int nt = 0; nt < NT1; ++nt)
      acc1[mt][nt] = (f32x4){0.f, 0.f, 0.f, 0.f};

  const f16* Xr0 = X + (size_t)(rw + m15) * RS1;
  const f16* Xr1 = X + (size_t)(rw + 16 + m15) * RS1;
  #pragma unroll
  for (int ks = 0; ks < KST1; ++ks) {
    const int off = ks * 32 + quad * 8;
    f16x8 a0 = *(const f16x8*)(Xr0 + off);
    f16x8 a1 = *(const f16x8*)(Xr1 + off);
    #pragma unroll
    for (int nt = 0; nt < NT1; ++nt) {
      f16x8 b = *((const f16x8*)SC + (nt * KST1 + ks) * 64 + l);
      acc1[0][nt] = __builtin_amdgcn_mfma_f32_16x16x32_f16(a0, b, acc1[0][nt], 0, 0, 0);
      acc1[1][nt] = __builtin_amdgcn_mfma_f32_16x16x32_f16(a1, b, acc1[1][nt], 0, 0, 0);
    }
  }

  __syncthreads();  // all waves done reading W1 -> SC reusable

  // ---- scatter S = sigm(acc1 + b1) into SC (row-major, stride PSTR1) ----
  #pragma unroll
  for (int mt = 0; mt < 2; ++mt) {
    #pragma unroll
    for (int reg = 0; reg < 4; ++reg) {
      const int rl = wid * 32 + mt * 16 + quad * 4 + reg;
      #pragma unroll
      for (int nt = 0; nt < NT1; ++nt)
        SC[rl * PSTR1 + nt * 16 + m15] = (f16)sigm(acc1[mt][nt][reg] + b1r[nt]);
    }
  }
  __syncthreads();

  // ---- stage 2: acc2 = S @ W2 (A-frags of S from SC) ----
  f32x4 acc2[2][NT2];
  #pragma unroll
  for (int mt = 0; mt < 2; ++mt)
    #pragma unroll
    for (int nt = 0; nt < NT2; ++nt)
      acc2[mt][nt] = (f32x4){0.f, 0.f, 0.f, 0.f};

  const int rA0 = wid * 32 + m15;
  const int rA1 = rA0 + 16;
  union A8 { f16x8 v; f16x4 q[2]; };
  #pragma unroll
  for (int ks = 0; ks < KST2; ++ks) {
    const int k0 = ks * 32 + quad * 8;
    A8 a0, a1;
    a0.q[0] = *(const f16x4*)&SC[rA0 * PSTR1 + k0];
    a0.q[1] = *(const f16x4*)&SC[rA0 * PSTR1 + k0 + 4];
    a1.q[0] = *(const f16x4*)&SC[rA1 * PSTR1 + k0];
    a1.q[1] = *(const f16x4*)&SC[rA1 * PSTR1 + k0 + 4];
    #pragma unroll
    for (int nt = 0; nt < NT2; ++nt) {
      f16x8 b = *((const f16x8*)Bs2 + (nt * KST2 + ks) * 64 + l);
      acc2[0][nt] = __builtin_amdgcn_mfma_f32_16x16x32_f16(a0.v, b, acc2[0][nt], 0, 0, 0);
      acc2[1][nt] = __builtin_amdgcn_mfma_f32_16x16x32_f16(a1.v, b, acc2[1][nt], 0, 0, 0);
    }
  }
  __syncthreads();  // done reading S -> SC reusable for tr2

  // ---- scatter acc2 raw -> SC (stride PSTR2) ----
  #pragma unroll
  for (int mt = 0; mt < 2; ++mt) {
    #pragma unroll
    for (int reg = 0; reg < 4; ++reg) {
      const int rl = wid * 32 + mt * 16 + quad * 4 + reg;
      #pragma unroll
      for (int nt = 0; nt < NT2; ++nt)
        SC[rl * PSTR2 + nt * 16 + m15] = (f16)acc2[mt][nt][reg];
    }
  }
  __syncthreads();

  // ---- epilogue (identical semantics to the old second kernel) ----
  const int r  = t >> 1;
  const int hf = t & 1;
  const int gr = blockIdx.x * 128 + r;
  if (gr < n) {
    if constexpr (MODE2 == 0) {
      #pragma unroll
      for (int c8 = 0; c8 < 8; ++c8) {
        const int c0 = hf * 64 + c8 * 8;
        f16x8 v = *(const f16x8*)&SC[r * PSTR2 + c0];
        f16x8 o;
        #pragma unroll
        for (int j = 0; j < 8; ++j)
          o[j] = (f16)sigm((float)v[j] + b2[c0 + j]);
        *(f16x8*)&Y[(size_t)gr * YRS + c0] = o;
      }
    } else {  // MODE2 == 1, NC2 = 130
      const bool hasInit = (gr >= ngrid);
      #pragma unroll
      for (int c8 = 0; c8 < 8; ++c8) {
        const int c0 = hf * 64 + c8 * 8;
        f16x8 v = *(const f16x8*)&SC[r * PSTR2 + c0];
        f16x8 o;
        #pragma unroll
        for (int j = 0; j < 8; ++j) {
          const int col = c0 + j;
          float fv = sigm((float)v[j] + b2[col]);
          float xov = (float)xo[c8][j];
          float ip = hasInit ? initial[(size_t)(gr - ngrid) * 128 + col] : 0.0f;
          o[j] = (f16)(xov * fv + (1.0f - fv) * ip);
        }
        *(f16x8*)&Y[(size_t)gr * YRS + c0] = o;
      }
      if (hf) {
        #pragma unroll
        for (int k = 0; k < 2; ++k) {
          const int col = 128 + k;
          float fv = sigm((float)SC[r * PSTR2 + col] + b2[col]);
          Y[(size_t)gr * YRS + col] = (f16)((float)xo2[k] * fv);
        }
      }
    }
  }
}

// ---------------- aggregation (lane-group batched gather) ----------------
template<int MODE>
__global__ __launch_bounds__(256) void agg_kernel(
    const f16* __restrict__ G, const int* __restrict__ ncnt,
    const int* __restrict__ dense,
    const float* __restrict__ dinv, const float* __restrict__ bias,
    const float* __restrict__ gamma, const float* __restrict__ beta,
    const f16* __restrict__ xg, const f16* __restrict__ u,
    void* __restrict__ out, int n)
{
  const int wid = threadIdx.x >> 6, lane = threadIdx.x & 63;
  const int c = blockIdx.x * 4 + wid;
  if (c >= n) return;
  const int li = lane & 15, grp = lane >> 4;

  union F8 { f16x8 h; int4 i; };
  const int nc = min(ncnt[c], DENSW);
  const int raw = dense[(size_t)c * DENSW + lane];   // coalesced; junk if lane>=nc
  const int myidx = (lane < nc) ? raw : c;           // self row is max-idempotent

  F8 m; m.h = *(const f16x8*)(G + (size_t)c * 128 + li * 8);  // self-loop
  F8 m2; m2.h = m.h;
  F8 m3; m3.h = m.h;
  F8 m4; m4.h = m.h;
  const int B = (nc + 3) >> 2;
  int b = 0;
  for (; b + 3 < B; b += 4) {
    int r0 = __shfl(myidx, (b + 0) * 4 + grp, 64);
    int r1 = __shfl(myidx, (b + 1) * 4 + grp, 64);
    int r2 = __shfl(myidx, (b + 2) * 4 + grp, 64);
    int r3 = __shfl(myidx, (b + 3) * 4 + grp, 64);
    F8 v0; v0.h = *(const f16x8*)(G + (size_t)r0 * 128 + li * 8);
    F8 v1; v1.h = *(const f16x8*)(G + (size_t)r1 * 128 + li * 8);
    F8 v2; v2.h = *(const f16x8*)(G + (size_t)r2 * 128 + li * 8);
    F8 v3; v3.h = *(const f16x8*)(G + (size_t)r3 * 128 + li * 8);
    m.h  = max8(m.h,  v0.h);
    m2.h = max8(m2.h, v1.h);
    m3.h = max8(m3.h, v2.h);
    m4.h = max8(m4.h, v3.h);
  }
  for (; b < B; ++b) {
    int r0 = __shfl(myidx, b * 4 + grp, 64);
    F8 v; v.h = *(const f16x8*)(G + (size_t)r0 * 128 + li * 8);
    m.h = max8(m.h, v.h);
  }
  m.h = max8(max8(m.h, m2.h), max8(m3.h, m4.h));

  #pragma unroll
  for (int st = 16; st <= 32; st <<= 1) {
    F8 o;
    #pragma unroll
    for (int d = 0; d < 4; ++d) o.i[d] = __shfl_xor(m.i[d], st, 64);
    m.h = max8(m.h, o.h);
  }

  const float dc = dinv[c];
  float v[8];
  float s = 0.f, sq = 0.f;
  #pragma unroll
  for (int j = 0; j < 8; ++j) {
    v[j] = (float)m.h[j] * dc + bias[li * 8 + j];
    s += v[j]; sq += v[j] * v[j];
  }

  if constexpr (MODE == 2) {
    if (grp == 0) {
      f16x8 xv = *(const f16x8*)(xg + (size_t)c * 160 + li * 8);
      f16x8 uv = *(const f16x8*)(u  + (size_t)c * 128 + li * 8);
      float o[8];
      #pragma unroll
      for (int j = 0; j < 8; ++j) o[j] = (float)xv[j] + v[j] * (float)uv[j];
      float* op = (float*)out + (size_t)c * 128 + li * 8;
      *(float4*)op       = make_float4(o[0], o[1], o[2], o[3]);
      *(float4*)(op + 4) = make_float4(o[4], o[5], o[6], o[7]);
    }
  } else {
    #pragma unroll
    for (int st = 1; st <= 8; st <<= 1) {
      s  += __shfl_xor(s, st, 64);
      sq += __shfl_xor(sq, st, 64);
    }
    float mu  = s * (1.0f / 128.0f);
    float var = sq * (1.0f / 128.0f) - mu * mu;
    float rstd = rsqrtf(var + 1e-5f);
    if (grp == 0) {
      f16x8 ov;
      #pragma unroll
      for (int j = 0; j < 8; ++j) {
        float o = (v[j] - mu) * rstd * gamma[li * 8 + j] + beta[li * 8 + j];
        if constexpr (MODE == 0) o = fmaxf(o, 0.0f);
        ov[j] = (f16)o;
      }
      *(f16x8*)((f16*)out + (size_t)c * 128 + li * 8) = ov;
    }
  }
}

extern "C" void kernel_launch(void* const* d_in, const int* in_sizes, int n_in,
                              void* d_out, int out_size, void* d_ws, size_t ws_size,
                              hipStream_t stream) {
  (void)n_in; (void)out_size; (void)ws_size;
  const float* x       = (const float*)d_in[0];
  const int*   ei      = (const int*)d_in[1];
  const float* initial = (const float*)d_in[2];
  const float* Wf1 = (const float*)d_in[3];  const float* bf1 = (const float*)d_in[4];
  const float* Wf2 = (const float*)d_in[5];  const float* bf2 = (const float*)d_in[6];
  const float* Wu1 = (const float*)d_in[7];  const float* bu1 = (const float*)d_in[8];
  const float* Wu2 = (const float*)d_in[9];  const float* bu2 = (const float*)d_in[10];
  const float* Wc1 = (const float*)d_in[11]; const float* bc1 = (const float*)d_in[12];
  const float* Wc2 = (const float*)d_in[13]; const float* bc2 = (const float*)d_in[14];
  const float* Wc3 = (const float*)d_in[15]; const float* bc3 = (const float*)d_in[16];
  const float* Wc4 = (const float*)d_in[17]; const float* bc4 = (const float*)d_in[18];
  const float* Wco = (const float*)d_in[19]; const float* bco = (const float*)d_in[20];
  const float* g3  = (const float*)d_in[21]; const float* bn3 = (const float*)d_in[22];
  const float* g6  = (const float*)d_in[23]; const float* bn6 = (const float*)d_in[24];
  const float* g7  = (const float*)d_in[25]; const float* bn7 = (const float*)d_in[26];

  const int N  = in_sizes[0] / HC;   // 100000
  const int E  = in_sizes[1] / 2;    // 1600000
  const int NG = N - NIO;            // 99872
  const int NP = N + 128;            // padded rows for OOB-safe A-frag loads
  const int NB = (N + 127) / 128;    // 782 coarse buckets
  const int NSEG = 8 * SUBB;         // 64 append segments per bucket

  char* w = (char*)d_ws;
  auto carve = [&](size_t bytes) {
    char* p = w; w += (bytes + 255) & ~(size_t)255; return p;
  };
  int*      bcnt   = (int*)     carve((size_t)NB * NSEG * 4);
  unsigned* bucket = (unsigned*)carve((size_t)NB * NSEG * BCAP_S * 4);  // 32 MB
  int*      ncnt   = (int*)     carve((size_t)N * 4);
  int*      dense  = (int*)     carve((size_t)N * DENSW * 4);      // 25.6 MB
  float*    dinv   = (float*)   carve((size_t)N * 4);
  f16*      x16    = (f16*)     carve((size_t)NP * 160 * 2);
  f16*      S      = (f16*)     carve((size_t)NP * 128 * 2);
  f16*      xg     = (f16*)     carve((size_t)NP * 160 * 2);
  f16*      u      = (f16*)     carve((size_t)N  * 128 * 2);
  f16*      G      = (f16*)     carve((size_t)N  * 128 * 2);
  f16*      H      = (f16*)     carve((size_t)NP * 128 * 2);
  f16*      Wt_f1  = (f16*)     carve(160 * 128 * 2);
  f16*      Wt_f2  = (f16*)     carve(128 * 144 * 2);
  f16*      Wt_u1  = (f16*)     carve(160 * 128 * 2);
  f16*      Wt_u2  = (f16*)     carve(128 * 128 * 2);
  f16*      Wt_c1  = (f16*)     carve(160 * 128 * 2);
  f16*      Wt_c2  = (f16*)     carve(128 * 128 * 2);
  f16*      Wt_c3  = (f16*)     carve(128 * 128 * 2);
  f16*      Wt_c4  = (f16*)     carve(128 * 128 * 2);
  f16*      Wt_co  = (f16*)     carve(128 * 128 * 2);
  (void)S;

  const int* erow = ei;
  const int* ecol = ei + E;

  const int gE = (E + 255) / 256;
  const int gM = (N + 127) / 128;
  const int gA = (N + 3) / 4;

  // weight/x prep
  WAll wa;
  wa.m[0] = {Wf1, Wt_f1, HC,  HID, 160, 128};
  wa.m[1] = {Wf2, Wt_f2, HID, HC,  128, 144};
  wa.m[2] = {Wu1, Wt_u1, HC,  HID, 160, 128};
  wa.m[3] = {Wu2, Wt_u2, HID, HID, 128, 128};
  wa.m[4] = {Wc1, Wt_c1, HC,  HID, 160, 128};
  wa.m[5] = {Wc2, Wt_c2, HID, HID, 128, 128};
  wa.m[6] = {Wc3, Wt_c3, HID, HID, 128, 128};
  wa.m[7] = {Wc4, Wt_c4, HID, HID, 128, 128};
  wa.m[8] = {Wco, Wt_co, HID, HID, 128, 128};
  wprep_kernel<<<dim3(10, 9), 256, 0, stream>>>(wa);
  xprep_kernel<<<(N * 160 + 255) / 256, 256, 0, stream>>>(x, x16, xg, N);

  // graph build (two-level binning)
  zero_int_kernel<<<(NB * NSEG + 255) / 256, 256, 0, stream>>>(bcnt, NB * NSEG);
  binscatter_kernel<<<gE, 256, 0, stream>>>(erow, ecol, bcnt, bucket, E, NB);
  build_kernel<<<NB, 256, 0, stream>>>(bcnt, bucket, ncnt, dense, dinv, N, NB);

  // forget gate (f1+f2 fused): xg = mix(sigm(sigm(x@Wf1+bf1)@Wf2+bf2))
  mm_fused<160, 160, 144, 130, 1><<<gM, 256, 0, stream>>>(
      x16, Wt_f1, Wt_f2, bf1, bf2, xg, x16, initial, N, NG);
  // update gate (u1+u2 fused): u = sigm(sigm(xg@Wu1+bu1)@Wu2+bu2)
  mm_fused<160, 160, 128, 128, 0><<<gM, 256, 0, stream>>>(
      xg, Wt_u1, Wt_u2, bu1, bu2, u, nullptr, nullptr, N, NG);

  // gcn1: relu(LN(..., g3, bn3))
  mm_mfma<160, 160, 128, 128, 2><<<gM, 256, 0, stream>>>(xg, Wt_c1, nullptr, G, dinv, nullptr, nullptr, N, NG);
  agg_kernel<0><<<gA, 256, 0, stream>>>(G, ncnt, dense, dinv, bc1, g3, bn3, nullptr, nullptr, H, N);
  // gcn2: LN(..., g3, bn3)
  mm_mfma<128, 128, 128, 128, 2><<<gM, 256, 0, stream>>>(H, Wt_c2, nullptr, G, dinv, nullptr, nullptr, N, NG);
  agg_kernel<1><<<gA, 256, 0, stream>>>(G, ncnt, dense, dinv, bc2, g3, bn3, nullptr, nullptr, H, N);
  // gcn3: LN(..., g6, bn6)
  mm_mfma<128, 128, 128, 128, 2><<<gM, 256, 0, stream>>>(H, Wt_c3, nullptr, G, dinv, nullptr, nullptr, N, NG);
  agg_kernel<1><<<gA, 256, 0, stream>>>(G, ncnt, dense, dinv, bc3, g6, bn6, nullptr, nullptr, H, N);
  // gcn4: LN(..., g7, bn7)
  mm_mfma<128, 128, 128, 128, 2><<<gM, 256, 0, stream>>>(H, Wt_c4, nullptr, G, dinv, nullptr, nullptr, N, NG);
  agg_kernel<1><<<gA, 256, 0, stream>>>(G, ncnt, dense, dinv, bc4, g7, bn7, nullptr, nullptr, H, N);
  // gcn5 + final: out = xg[:, :128] + (agg + bco) * u
  mm_mfma<128, 128, 128, 128, 2><<<gM, 256, 0, stream>>>(H, Wt_co, nullptr, G, dinv, nullptr, nullptr, N, NG);
  agg_kernel<2><<<gA, 256, 0, stream>>>(G, ncnt, dense, dinv, bco, nullptr, nullptr, xg, u, d_out, N);
}

// Round 7
// 745.682 us; speedup vs baseline: 1.2105x; 1.0081x over previous
//
#include <hip/hip_runtime.h>
#include <cstdint>

#define HID 128
#define HC  130
#define NIO 128
#define DENSW 64     // dense ELL width (max in-degree ~45 for Poisson(16))
#define SUBB 8       // sub-cursors per (xcd,bucket): kills same-address atomic serialization
#define BCAP_S 160   // per-(xcd,sub,bucket) capacity; mean ~32, 5x margin

typedef _Float16 f16;
typedef _Float16 f16x2 __attribute__((ext_vector_type(2)));
typedef _Float16 f16x4 __attribute__((ext_vector_type(4)));
typedef _Float16 f16x8 __attribute__((ext_vector_type(8)));
typedef float    f32x4 __attribute__((ext_vector_type(4)));

__device__ __forceinline__ float sigm(float z) {
  return 1.0f / (1.0f + __expf(-z));
}

__device__ __forceinline__ int xcc_id() {
  int x;
  asm volatile("s_getreg_b32 %0, hwreg(HW_REG_XCC_ID)" : "=s"(x));
  return x & 7;
}

// Packed f16 max: v_pk_max_f16 does 2 elements/op (ternary lowers to
// v_cmp+v_cndmask = 4x the VALU). Inputs finite (sigmoid/LN outputs).
__device__ __forceinline__ f16x8 max8(f16x8 a, f16x8 b) {
  union P { f16x8 h; f16x2 p[4]; } A, B, O;
  A.h = a; B.h = b;
  #pragma unroll
  for (int i = 0; i < 4; ++i)
    asm("v_pk_max_f16 %0, %1, %2" : "=v"(O.p[i]) : "v"(A.p[i]), "v"(B.p[i]));
  return O.h;
}

// ---------------- graph build: two-level binning ----------------
__global__ void zero_int_kernel(int* __restrict__ p, int n) {
  int i = blockIdx.x * blockDim.x + threadIdx.x;
  if (i < n) p[i] = 0;
}

__global__ void binscatter_kernel(const int* __restrict__ row, const int* __restrict__ col,
    int* __restrict__ bcnt, unsigned* __restrict__ bucket, int e, int nb) {
  const int g0 = xcc_id() * SUBB + ((blockIdx.x >> 3) & (SUBB - 1));
  int i = blockIdx.x * blockDim.x + threadIdx.x;
  if (i >= e) return;
  int c = col[i], r = row[i];
  int b = c >> 7;
  int cur = atomicAdd(&bcnt[g0 * nb + b], 1);
  if (cur < BCAP_S)
    bucket[((size_t)g0 * nb + b) * BCAP_S + cur] = ((unsigned)r << 7) | (unsigned)(c & 127);
}

__global__ __launch_bounds__(256) void build_kernel(const int* __restrict__ bcnt,
    const unsigned* __restrict__ bucket, int* __restrict__ ncnt,
    int* __restrict__ dense, float* __restrict__ dinv, int n, int nb) {
  __shared__ int lcnt[128];
  const int b = blockIdx.x;
  const int t = threadIdx.x;
  if (t < 128) lcnt[t] = 0;
  __syncthreads();
  const int wv = t >> 6, ln = t & 63;
  #pragma unroll 1
  for (int g = wv * 16; g < wv * 16 + 16; ++g) {
    const int cntg = min(bcnt[g * nb + b], BCAP_S);
    const unsigned* __restrict__ src = bucket + ((size_t)g * nb + b) * BCAP_S;
    for (int idx = ln; idx < cntg; idx += 64) {
      unsigned ev = src[idx];
      int cl = (int)(ev & 127u);
      int r  = (int)(ev >> 7);
      int s = atomicAdd(&lcnt[cl], 1);
      if (s < DENSW) dense[(size_t)((b << 7) + cl) * DENSW + s] = r;
    }
  }
  __syncthreads();
  if (t < 128) {
    int c = (b << 7) + t;
    if (c < n) {
      int cc = min(lcnt[t], DENSW);
      ncnt[c] = cc;
      dinv[c] = rsqrtf((float)(cc + 1));  // +1 self-loop
    }
  }
}

// ---------------- prep: weights -> frag-ordered fp16 ----------------
struct WDesc { const float* src; f16* dst; int K, NC, Kpad, NCpad; };
struct WAll { WDesc m[9]; };

__global__ __launch_bounds__(256) void wprep_kernel(WAll wa) {
  const WDesc d = wa.m[blockIdx.y];
  const int KST = d.Kpad >> 5;
  const int total = (d.NCpad >> 4) * KST * 64;
  int idx = blockIdx.x * 256 + threadIdx.x;
  if (idx >= total) return;
  int nt  = idx / (KST * 64);
  int rem = idx - nt * (KST * 64);
  int ks  = rem >> 6;
  int l   = rem & 63;
  int n   = nt * 16 + (l & 15);
  int k0  = ks * 32 + (l >> 4) * 8;
  f16x8 o;
  #pragma unroll
  for (int j = 0; j < 8; ++j) {
    int k = k0 + j;
    float v = (k < d.K && n < d.NC) ? d.src[(size_t)k * d.NC + n] : 0.0f;
    o[j] = (f16)v;
  }
  *((f16x8*)d.dst + idx) = o;
}

__global__ void xprep_kernel(const float* __restrict__ x, f16* __restrict__ x16,
                             f16* __restrict__ xg, int n) {
  int idx = blockIdx.x * blockDim.x + threadIdx.x;
  if (idx >= n * 160) return;
  int r = idx / 160, c = idx - r * 160;
  x16[idx] = (f16)((c < 130) ? x[(size_t)r * 130 + c] : 0.0f);
  if (c >= 130) xg[idx] = (f16)0.0f;
}

// ---------------- MFMA matmul ----------------
// Y[N,NC] = X[N,K] @ W[K,NC]; MODE 0: sigm(acc+bias); MODE 2: acc*dinv[row].
// A-fragments (and dinv) are loaded into REGISTERS BEFORE the W-staging
// barrier: their HBM latency overlaps the LDS staging instead of serializing
// behind it (syncthreads' fence blocks compiler hoisting; do it in source).
template<int KPAD, int RS, int NCPAD, int NC, int MODE>
__global__ __launch_bounds__(256, 4) void mm_mfma(
    const f16* __restrict__ X, const f16* __restrict__ Wt,
    const float* __restrict__ bias, f16* __restrict__ Y,
    const float* __restrict__ dinv, const f16* __restrict__ xor16,
    const float* __restrict__ initial, int n, int ngrid)
{
  constexpr int KST = KPAD / 32;
  constexpr int NT  = NCPAD / 16;
  constexpr int YRS = (MODE == 1) ? 160 : 128;
  constexpr int PSTR = (NCPAD == 128) ? 132 : 148;  // %16 == 4
  constexpr int LDSH = (NCPAD * KPAD > 128 * PSTR) ? NCPAD * KPAD : 128 * PSTR;
  __shared__ __align__(16) f16 Bs[LDSH];

  const int t = threadIdx.x;
  const int wid  = t >> 6;
  const int l    = t & 63;
  const int m15  = l & 15;
  const int quad = l >> 4;
  const int rw   = blockIdx.x * 128 + wid * 32;

  // issue W staging first (loads queue ahead)...
  constexpr int BSW = NCPAD * KPAD / 8;
  #pragma unroll
  for (int i = 0; i < (BSW + 255) / 256; ++i) {
    int idx = t + i * 256;
    if (BSW % 256 == 0 || idx < BSW)
      ((f16x8*)Bs)[idx] = ((const f16x8*)Wt)[idx];
  }

  // ...then A-fragment prefetch into registers (latency hides under staging)
  const f16* Xr0 = X + (size_t)(rw + m15) * RS;
  const f16* Xr1 = X + (size_t)(rw + 16 + m15) * RS;
  f16x8 a0r[KST], a1r[KST];
  #pragma unroll
  for (int ks = 0; ks < KST; ++ks) {
    const int off = ks * 32 + quad * 8;
    a0r[ks] = *(const f16x8*)(Xr0 + off);
    a1r[ks] = *(const f16x8*)(Xr1 + off);
  }

  // epilogue scalars, also pre-barrier
  const int r  = t >> 1;
  const int hf = t & 1;
  const int gr = blockIdx.x * 128 + r;
  float dv = 0.0f;
  if constexpr (MODE == 2) dv = (gr < n) ? dinv[gr] : 0.0f;

  f16x8 xo[8];
  f16x2 xo2;
  if constexpr (MODE == 1) {
    const f16* xp = xor16 + (size_t)(blockIdx.x * 128 + r) * 160;
    #pragma unroll
    for (int c8 = 0; c8 < 8; ++c8)
      xo[c8] = *(const f16x8*)(xp + hf * 64 + c8 * 8);
    xo2 = *(const f16x2*)(xp + 128);
  }

  __syncthreads();

  f32x4 acc[2][NT];
  #pragma unroll
  for (int mt = 0; mt < 2; ++mt)
    #pragma unroll
    for (int nt = 0; nt < NT; ++nt)
      acc[mt][nt] = (f32x4){0.f, 0.f, 0.f, 0.f};

  #pragma unroll
  for (int ks = 0; ks < KST; ++ks) {
    #pragma unroll
    for (int nt = 0; nt < NT; ++nt) {
      f16x8 b = *((const f16x8*)Bs + (nt * KST + ks) * 64 + l);
      acc[0][nt] = __builtin_amdgcn_mfma_f32_16x16x32_f16(a0r[ks], b, acc[0][nt], 0, 0, 0);
      acc[1][nt] = __builtin_amdgcn_mfma_f32_16x16x32_f16(a1r[ks], b, acc[1][nt], 0, 0, 0);
    }
  }

  __syncthreads();  // done reading Bs; reuse as transpose tile

  #pragma unroll
  for (int mt = 0; mt < 2; ++mt) {
    #pragma unroll
    for (int reg = 0; reg < 4; ++reg) {
      const int rl = wid * 32 + mt * 16 + quad * 4 + reg;
      #pragma unroll
      for (int nt = 0; nt < NT; ++nt)
        Bs[rl * PSTR + nt * 16 + m15] = (f16)acc[mt][nt][reg];
    }
  }
  __syncthreads();

  if (gr < n) {
    if constexpr (MODE == 0 || MODE == 2) {
      #pragma unroll
      for (int c8 = 0; c8 < 8; ++c8) {
        const int c0 = hf * 64 + c8 * 8;
        f16x8 v = *(const f16x8*)&Bs[r * PSTR + c0];
        f16x8 o;
        #pragma unroll
        for (int j = 0; j < 8; ++j) {
          float a = (float)v[j];
          if constexpr (MODE == 0) o[j] = (f16)sigm(a + bias[c0 + j]);
          else                     o[j] = (f16)(a * dv);
        }
        *(f16x8*)&Y[(size_t)gr * YRS + c0] = o;
      }
    } else {  // MODE 1, NC=130
      const bool hasInit = (gr >= ngrid);
      #pragma unroll
      for (int c8 = 0; c8 < 8; ++c8) {
        const int c0 = hf * 64 + c8 * 8;
        f16x8 v = *(const f16x8*)&Bs[r * PSTR + c0];
        f16x8 o;
        #pragma unroll
        for (int j = 0; j < 8; ++j) {
          const int col = c0 + j;
          float fv = sigm((float)v[j] + bias[col]);
          float xov = (float)xo[c8][j];
          float ip = hasInit ? initial[(size_t)(gr - ngrid) * 128 + col] : 0.0f;
          o[j] = (f16)(xov * fv + (1.0f - fv) * ip);
        }
        *(f16x8*)&Y[(size_t)gr * YRS + c0] = o;
      }
      if (hf) {
        #pragma unroll
        for (int k = 0; k < 2; ++k) {
          const int col = 128 + k;
          float fv = sigm((float)Bs[r * PSTR + col] + bias[col]);
          Y[(size_t)gr * YRS + col] = (f16)((float)xo2[k] * fv);
        }
      }
    }
  }
}

// ---------------- fused two-layer MLP ----------------
// Y = epilogue2( sigm(X@W1 + b1) @ W2 + b2 ). Stage-1 A-fragments prefetched
// into registers before the weight-staging barrier (same async-split as
// mm_mfma); S lives only in LDS.
template<int K1PAD, int RS1, int NC2PAD, int NC2, int MODE2>
__global__ __launch_bounds__(256, 2) void mm_fused(
    const f16* __restrict__ X, const f16* __restrict__ W1t, const f16* __restrict__ W2t,
    const float* __restrict__ b1, const float* __restrict__ b2, f16* __restrict__ Y,
    const f16* __restrict__ xor16, const float* __restrict__ initial, int n, int ngrid)
{
  constexpr int KST1 = K1PAD / 32;   // 5
  constexpr int NT1  = 8;            // mid = 128 cols
  constexpr int KST2 = 4;            // K2 = 128
  constexpr int NT2  = NC2PAD / 16;  // 8 or 9
  constexpr int PSTR1 = 132;         // %16==4: conflict-light scatter
  constexpr int PSTR2 = (NC2PAD == 128) ? 132 : 148;
  constexpr int YRS  = (MODE2 == 1) ? 160 : 128;
  constexpr int W2U  = NC2PAD * 128;                 // f16 units
  constexpr int SC_A = K1PAD * 128;                  // W1 frag area
  constexpr int SC_B = 128 * PSTR2;                  // tr2 area (>= tr1)
  constexpr int SCU  = (SC_A > SC_B) ? SC_A : SC_B;
  __shared__ __align__(16) f16 L[W2U + SCU];
  f16* Bs2 = L;
  f16* SC  = L + W2U;

  const int t = threadIdx.x;
  const int wid  = t >> 6;
  const int l    = t & 63;
  const int m15  = l & 15;
  const int quad = l >> 4;
  const int rw   = blockIdx.x * 128 + wid * 32;

  constexpr int W1W = K1PAD * 128 / 8;
  constexpr int W2W = NC2PAD * 128 / 8;
  for (int i = t; i < W1W; i += 256) ((f16x8*)SC)[i]  = ((const f16x8*)W1t)[i];
  for (int i = t; i < W2W; i += 256) ((f16x8*)Bs2)[i] = ((const f16x8*)W2t)[i];

  // stage-1 A prefetch (overlaps W staging)
  const f16* Xr0 = X + (size_t)(rw + m15) * RS1;
  const f16* Xr1 = X + (size_t)(rw + 16 + m15) * RS1;
  f16x8 a0r[KST1], a1r[KST1];
  #pragma unroll
  for (int ks = 0; ks < KST1; ++ks) {
    const int off = ks * 32 + quad * 8;
    a0r[ks] = *(const f16x8*)(Xr0 + off);
    a1r[ks] = *(const f16x8*)(Xr1 + off);
  }

  // MODE2==1: prefetch x-mix rows early (latency hides under both MFMA stages)
  f16x8 xo[8];
  f16x2 xo2;
  if constexpr (MODE2 == 1) {
    const f16* xp = xor16 + (size_t)(blockIdx.x * 128 + (t >> 1)) * 160;
    #pragma unroll
    for (int c8 = 0; c8 < 8; ++c8)
      xo[c8] = *(const f16x8*)(xp + (t & 1) * 64 + c8 * 8);
    xo2 = *(const f16x2*)(xp + 128);
  }

  // stage-1 bias, one scalar per output col this lane owns
  float b1r[NT1];
  #pragma unroll
  for (int nt = 0; nt < NT1; ++nt) b1r[nt] = b1[nt * 16 + m15];

  __syncthreads();

  // ---- stage 1: acc1 = X @ W1 ----
  f32x4 acc1[2][NT1];
  #pragma unroll
  for (int mt = 0; mt < 2; ++mt)
    #pragma unroll
    for (int nt = 0; nt < NT1; ++nt)
      acc1[mt][nt] = (f32x4){0.f, 0.f, 0.f, 0.f};

  #pragma unroll
  for (int ks = 0; ks < KST1; ++ks) {
    #pragma unroll
    for (int nt = 0; nt < NT1; ++nt) {
      f16x8 b = *((const f16x8*)SC + (nt * KST1 + ks) * 64 + l);
      acc1[0][nt] = __builtin_amdgcn_mfma_f32_16x16x32_f16(a0r[ks], b, acc1[0][nt], 0, 0, 0);
      acc1[1][nt] = __builtin_amdgcn_mfma_f32_16x16x32_f16(a1r[ks], b, acc1[1][nt], 0, 0, 0);
    }
  }

  __syncthreads();  // all waves done reading W1 -> SC reusable

  // ---- scatter S = sigm(acc1 + b1) into SC (row-major, stride PSTR1) ----
  #pragma unroll
  for (int mt = 0; mt < 2; ++mt) {
    #pragma unroll
    for (int reg = 0; reg < 4; ++reg) {
      const int rl = wid * 32 + mt * 16 + quad * 4 + reg;
      #pragma unroll
      for (int nt = 0; nt < NT1; ++nt)
        SC[rl * PSTR1 + nt * 16 + m15] = (f16)sigm(acc1[mt][nt][reg] + b1r[nt]);
    }
  }
  __syncthreads();

  // ---- stage 2: acc2 = S @ W2 (A-frags of S from SC) ----
  f32x4 acc2[2][NT2];
  #pragma unroll
  for (int mt = 0; mt < 2; ++mt)
    #pragma unroll
    for (int nt = 0; nt < NT2; ++nt)
      acc2[mt][nt] = (f32x4){0.f, 0.f, 0.f, 0.f};

  const int rA0 = wid * 32 + m15;
  const int rA1 = rA0 + 16;
  union A8 { f16x8 v; f16x4 q[2]; };
  #pragma unroll
  for (int ks = 0; ks < KST2; ++ks) {
    const int k0 = ks * 32 + quad * 8;
    A8 a0, a1;
    a0.q[0] = *(const f16x4*)&SC[rA0 * PSTR1 + k0];
    a0.q[1] = *(const f16x4*)&SC[rA0 * PSTR1 + k0 + 4];
    a1.q[0] = *(const f16x4*)&SC[rA1 * PSTR1 + k0];
    a1.q[1] = *(const f16x4*)&SC[rA1 * PSTR1 + k0 + 4];
    #pragma unroll
    for (int nt = 0; nt < NT2; ++nt) {
      f16x8 b = *((const f16x8*)Bs2 + (nt * KST2 + ks) * 64 + l);
      acc2[0][nt] = __builtin_amdgcn_mfma_f32_16x16x32_f16(a0.v, b, acc2[0][nt], 0, 0, 0);
      acc2[1][nt] = __builtin_amdgcn_mfma_f32_16x16x32_f16(a1.v, b, acc2[1][nt], 0, 0, 0);
    }
  }
  __syncthreads();  // done reading S -> SC reusable for tr2

  // ---- scatter acc2 raw -> SC (stride PSTR2) ----
  #pragma unroll
  for (int mt = 0; mt < 2; ++mt) {
    #pragma unroll
    for (int reg = 0; reg < 4; ++reg) {
      const int rl = wid * 32 + mt * 16 + quad * 4 + reg;
      #pragma unroll
      for (int nt = 0; nt < NT2; ++nt)
        SC[rl * PSTR2 + nt * 16 + m15] = (f16)acc2[mt][nt][reg];
    }
  }
  __syncthreads();

  // ---- epilogue (identical semantics to the old second kernel) ----
  const int r  = t >> 1;
  const int hf = t & 1;
  const int gr = blockIdx.x * 128 + r;
  if (gr < n) {
    if constexpr (MODE2 == 0) {
      #pragma unroll
      for (int c8 = 0; c8 < 8; ++c8) {
        const int c0 = hf * 64 + c8 * 8;
        f16x8 v = *(const f16x8*)&SC[r * PSTR2 + c0];
        f16x8 o;
        #pragma unroll
        for (int j = 0; j < 8; ++j)
          o[j] = (f16)sigm((float)v[j] + b2[c0 + j]);
        *(f16x8*)&Y[(size_t)gr * YRS + c0] = o;
      }
    } else {  // MODE2 == 1, NC2 = 130
      const bool hasInit = (gr >= ngrid);
      #pragma unroll
      for (int c8 = 0; c8 < 8; ++c8) {
        const int c0 = hf * 64 + c8 * 8;
        f16x8 v = *(const f16x8*)&SC[r * PSTR2 + c0];
        f16x8 o;
        #pragma unroll
        for (int j = 0; j < 8; ++j) {
          const int col = c0 + j;
          float fv = sigm((float)v[j] + b2[col]);
          float xov = (float)xo[c8][j];
          float ip = hasInit ? initial[(size_t)(gr - ngrid) * 128 + col] : 0.0f;
          o[j] = (f16)(xov * fv + (1.0f - fv) * ip);
        }
        *(f16x8*)&Y[(size_t)gr * YRS + c0] = o;
      }
      if (hf) {
        #pragma unroll
        for (int k = 0; k < 2; ++k) {
          const int col = 128 + k;
          float fv = sigm((float)SC[r * PSTR2 + col] + b2[col]);
          Y[(size_t)gr * YRS + col] = (f16)((float)xo2[k] * fv);
        }
      }
    }
  }
}

// ---------------- aggregation (lane-group batched gather) ----------------
template<int MODE>
__global__ __launch_bounds__(256) void agg_kernel(
    const f16* __restrict__ G, const int* __restrict__ ncnt,
    const int* __restrict__ dense,
    const float* __restrict__ dinv, const float* __restrict__ bias,
    const float* __restrict__ gamma, const float* __restrict__ beta,
    const f16* __restrict__ xg, const f16* __restrict__ u,
    void* __restrict__ out, int n)
{
  const int wid = threadIdx.x >> 6, lane = threadIdx.x & 63;
  const int c = blockIdx.x * 4 + wid;
  if (c >= n) return;
  const int li = lane & 15, grp = lane >> 4;

  union F8 { f16x8 h; int4 i; };
  const int nc = min(ncnt[c], DENSW);
  const int raw = dense[(size_t)c * DENSW + lane];   // coalesced; junk if lane>=nc
  const int myidx = (lane < nc) ? raw : c;           // self row is max-idempotent

  F8 m; m.h = *(const f16x8*)(G + (size_t)c * 128 + li * 8);  // self-loop
  F8 m2; m2.h = m.h;
  F8 m3; m3.h = m.h;
  F8 m4; m4.h = m.h;
  const int B = (nc + 3) >> 2;
  int b = 0;
  for (; b + 3 < B; b += 4) {
    int r0 = __shfl(myidx, (b + 0) * 4 + grp, 64);
    int r1 = __shfl(myidx, (b + 1) * 4 + grp, 64);
    int r2 = __shfl(myidx, (b + 2) * 4 + grp, 64);
    int r3 = __shfl(myidx, (b + 3) * 4 + grp, 64);
    F8 v0; v0.h = *(const f16x8*)(G + (size_t)r0 * 128 + li * 8);
    F8 v1; v1.h = *(const f16x8*)(G + (size_t)r1 * 128 + li * 8);
    F8 v2; v2.h = *(const f16x8*)(G + (size_t)r2 * 128 + li * 8);
    F8 v3; v3.h = *(const f16x8*)(G + (size_t)r3 * 128 + li * 8);
    m.h  = max8(m.h,  v0.h);
    m2.h = max8(m2.h, v1.h);
    m3.h = max8(m3.h, v2.h);
    m4.h = max8(m4.h, v3.h);
  }
  for (; b < B; ++b) {
    int r0 = __shfl(myidx, b * 4 + grp, 64);
    F8 v; v.h = *(const f16x8*)(G + (size_t)r0 * 128 + li * 8);
    m.h = max8(m.h, v.h);
  }
  m.h = max8(max8(m.h, m2.h), max8(m3.h, m4.h));

  #pragma unroll
  for (int st = 16; st <= 32; st <<= 1) {
    F8 o;
    #pragma unroll
    for (int d = 0; d < 4; ++d) o.i[d] = __shfl_xor(m.i[d], st, 64);
    m.h = max8(m.h, o.h);
  }

  const float dc = dinv[c];
  float v[8];
  float s = 0.f, sq = 0.f;
  #pragma unroll
  for (int j = 0; j < 8; ++j) {
    v[j] = (float)m.h[j] * dc + bias[li * 8 + j];
    s += v[j]; sq += v[j] * v[j];
  }

  if constexpr (MODE == 2) {
    if (grp == 0) {
      f16x8 xv = *(const f16x8*)(xg + (size_t)c * 160 + li * 8);
      f16x8 uv = *(const f16x8*)(u  + (size_t)c * 128 + li * 8);
      float o[8];
      #pragma unroll
      for (int j = 0; j < 8; ++j) o[j] = (float)xv[j] + v[j] * (float)uv[j];
      float* op = (float*)out + (size_t)c * 128 + li * 8;
      *(float4*)op       = make_float4(o[0], o[1], o[2], o[3]);
      *(float4*)(op + 4) = make_float4(o[4], o[5], o[6], o[7]);
    }
  } else {
    #pragma unroll
    for (int st = 1; st <= 8; st <<= 1) {
      s  += __shfl_xor(s, st, 64);
      sq += __shfl_xor(sq, st, 64);
    }
    float mu  = s * (1.0f / 128.0f);
    float var = sq * (1.0f / 128.0f) - mu * mu;
    float rstd = rsqrtf(var + 1e-5f);
    if (grp == 0) {
      f16x8 ov;
      #pragma unroll
      for (int j = 0; j < 8; ++j) {
        float o = (v[j] - mu) * rstd * gamma[li * 8 + j] + beta[li * 8 + j];
        if constexpr (MODE == 0) o = fmaxf(o, 0.0f);
        ov[j] = (f16)o;
      }
      *(f16x8*)((f16*)out + (size_t)c * 128 + li * 8) = ov;
    }
  }
}

extern "C" void kernel_launch(void* const* d_in, const int* in_sizes, int n_in,
                              void* d_out, int out_size, void* d_ws, size_t ws_size,
                              hipStream_t stream) {
  (void)n_in; (void)out_size; (void)ws_size;
  const float* x       = (const float*)d_in[0];
  const int*   ei      = (const int*)d_in[1];
  const float* initial = (const float*)d_in[2];
  const float* Wf1 = (const float*)d_in[3];  const float* bf1 = (const float*)d_in[4];
  const float* Wf2 = (const float*)d_in[5];  const float* bf2 = (const float*)d_in[6];
  const float* Wu1 = (const float*)d_in[7];  const float* bu1 = (const float*)d_in[8];
  const float* Wu2 = (const float*)d_in[9];  const float* bu2 = (const float*)d_in[10];
  const float* Wc1 = (const float*)d_in[11]; const float* bc1 = (const float*)d_in[12];
  const float* Wc2 = (const float*)d_in[13]; const float* bc2 = (const float*)d_in[14];
  const float* Wc3 = (const float*)d_in[15]; const float* bc3 = (const float*)d_in[16];
  const float* Wc4 = (const float*)d_in[17]; const float* bc4 = (const float*)d_in[18];
  const float* Wco = (const float*)d_in[19]; const float* bco = (const float*)d_in[20];
  const float* g3  = (const float*)d_in[21]; const float* bn3 = (const float*)d_in[22];
  const float* g6  = (const float*)d_in[23]; const float* bn6 = (const float*)d_in[24];
  const float* g7  = (const float*)d_in[25]; const float* bn7 = (const float*)d_in[26];

  const int N  = in_sizes[0] / HC;   // 100000
  const int E  = in_sizes[1] / 2;    // 1600000
  const int NG = N - NIO;            // 99872
  const int NP = N + 128;            // padded rows for OOB-safe A-frag loads
  const int NB = (N + 127) / 128;    // 782 coarse buckets
  const int NSEG = 8 * SUBB;         // 64 append segments per bucket

  char* w = (char*)d_ws;
  auto carve = [&](size_t bytes) {
    char* p = w; w += (bytes + 255) & ~(size_t)255; return p;
  };
  int*      bcnt   = (int*)     carve((size_t)NB * NSEG * 4);
  unsigned* bucket = (unsigned*)carve((size_t)NB * NSEG * BCAP_S * 4);  // 32 MB
  int*      ncnt   = (int*)     carve((size_t)N * 4);
  int*      dense  = (int*)     carve((size_t)N * DENSW * 4);      // 25.6 MB
  float*    dinv   = (float*)   carve((size_t)N * 4);
  f16*      x16    = (f16*)     carve((size_t)NP * 160 * 2);
  f16*      S      = (f16*)     carve((size_t)NP * 128 * 2);
  f16*      xg     = (f16*)     carve((size_t)NP * 160 * 2);
  f16*      u      = (f16*)     carve((size_t)N  * 128 * 2);
  f16*      G      = (f16*)     carve((size_t)N  * 128 * 2);
  f16*      H      = (f16*)     carve((size_t)NP * 128 * 2);
  f16*      Wt_f1  = (f16*)     carve(160 * 128 * 2);
  f16*      Wt_f2  = (f16*)     carve(128 * 144 * 2);
  f16*      Wt_u1  = (f16*)     carve(160 * 128 * 2);
  f16*      Wt_u2  = (f16*)     carve(128 * 128 * 2);
  f16*      Wt_c1  = (f16*)     carve(160 * 128 * 2);
  f16*      Wt_c2  = (f16*)     carve(128 * 128 * 2);
  f16*      Wt_c3  = (f16*)     carve(128 * 128 * 2);
  f16*      Wt_c4  = (f16*)     carve(128 * 128 * 2);
  f16*      Wt_co  = (f16*)     carve(128 * 128 * 2);
  (void)S;

  const int* erow = ei;
  const int* ecol = ei + E;

  const int gE = (E + 255) / 256;
  const int gM = (N + 127) / 128;
  const int gA = (N + 3) / 4;

  // weight/x prep
  WAll wa;
  wa.m[0] = {Wf1, Wt_f1, HC,  HID, 160, 128};
  wa.m[1] = {Wf2, Wt_f2, HID, HC,  128, 144};
  wa.m[2] = {Wu1, Wt_u1, HC,  HID, 160, 128};
  wa.m[3] = {Wu2, Wt_u2, HID, HID, 128, 128};
  wa.m[4] = {Wc1, Wt_c1, HC,  HID, 160, 128};
  wa.m[5] = {Wc2, Wt_c2, HID, HID, 128, 128};
  wa.m[6] = {Wc3, Wt_c3, HID, HID, 128, 128};
  wa.m[7] = {Wc4, Wt_c4, HID, HID, 128, 128};
  wa.m[8] = {Wco, Wt_co, HID, HID, 128, 128};
  wprep_kernel<<<dim3(10, 9), 256, 0, stream>>>(wa);
  xprep_kernel<<<(N * 160 + 255) / 256, 256, 0, stream>>>(x, x16, xg, N);

  // graph build (two-level binning)
  zero_int_kernel<<<(NB * NSEG + 255) / 256, 256, 0, stream>>>(bcnt, NB * NSEG);
  binscatter_kernel<<<gE, 256, 0, stream>>>(erow, ecol, bcnt, bucket, E, NB);
  build_kernel<<<NB, 256, 0, stream>>>(bcnt, bucket, ncnt, dense, dinv, N, NB);

  // forget gate (f1+f2 fused): xg = mix(sigm(sigm(x@Wf1+bf1)@Wf2+bf2))
  mm_fused<160, 160, 144, 130, 1><<<gM, 256, 0, stream>>>(
      x16, Wt_f1, Wt_f2, bf1, bf2, xg, x16, initial, N, NG);
  // update gate (u1+u2 fused): u = sigm(sigm(xg@Wu1+bu1)@Wu2+bu2)
  mm_fused<160, 160, 128, 128, 0><<<gM, 256, 0, stream>>>(
      xg, Wt_u1, Wt_u2, bu1, bu2, u, nullptr, nullptr, N, NG);

  // gcn1: relu(LN(..., g3, bn3))
  mm_mfma<160, 160, 128, 128, 2><<<gM, 256, 0, stream>>>(xg, Wt_c1, nullptr, G, dinv, nullptr, nullptr, N, NG);
  agg_kernel<0><<<gA, 256, 0, stream>>>(G, ncnt, dense, dinv, bc1, g3, bn3, nullptr, nullptr, H, N);
  // gcn2: LN(..., g3, bn3)
  mm_mfma<128, 128, 128, 128, 2><<<gM, 256, 0, stream>>>(H, Wt_c2, nullptr, G, dinv, nullptr, nullptr, N, NG);
  agg_kernel<1><<<gA, 256, 0, stream>>>(G, ncnt, dense, dinv, bc2, g3, bn3, nullptr, nullptr, H, N);
  // gcn3: LN(..., g6, bn6)
  mm_mfma<128, 128, 128, 128, 2><<<gM, 256, 0, stream>>>(H, Wt_c3, nullptr, G, dinv, nullptr, nullptr, N, NG);
  agg_kernel<1><<<gA, 256, 0, stream>>>(G, ncnt, dense, dinv, bc3, g6, bn6, nullptr, nullptr, H, N);
  // gcn4: LN(..., g7, bn7)
  mm_mfma<128, 128, 128, 128, 2><<<gM, 256, 0, stream>>>(H, Wt_c4, nullptr, G, dinv, nullptr, nullptr, N, NG);
  agg_kernel<1><<<gA, 256, 0, stream>>>(G, ncnt, dense, dinv, bc4, g7, bn7, nullptr, nullptr, H, N);
  // gcn5 + final: out = xg[:, :128] + (agg + bco) * u
  mm_mfma<128, 128, 128, 128, 2><<<gM, 256, 0, stream>>>(H, Wt_co, nullptr, G, dinv, nullptr, nullptr, N, NG);
  agg_kernel<2><<<gA, 256, 0, stream>>>(G, ncnt, dense, dinv, bco, nullptr, nullptr, xg, u, d_out, N);
}

// Round 8
// 738.679 us; speedup vs baseline: 1.2220x; 1.0095x over previous
//
#include <hip/hip_runtime.h>
#include <cstdint>

#define HID 128
#define HC  130
#define NIO 128
#define DENSW 64     // dense ELL width (max in-degree ~45 for Poisson(16))
#define SUBB 8       // sub-cursors per (xcd,bucket): kills same-address atomic serialization
#define BCAP_S 128   // per-(xcd,sub,bucket) capacity; mean ~32 (+17 sigma), 25.6MB total

typedef _Float16 f16;
typedef _Float16 f16x2 __attribute__((ext_vector_type(2)));
typedef _Float16 f16x4 __attribute__((ext_vector_type(4)));
typedef _Float16 f16x8 __attribute__((ext_vector_type(8)));
typedef float    f32x4 __attribute__((ext_vector_type(4)));

__device__ __forceinline__ float sigm(float z) {
  return 1.0f / (1.0f + __expf(-z));
}

__device__ __forceinline__ int xcc_id() {
  int x;
  asm volatile("s_getreg_b32 %0, hwreg(HW_REG_XCC_ID)" : "=s"(x));
  return x & 7;
}

// Packed f16 max: v_pk_max_f16 does 2 elements/op (ternary lowers to
// v_cmp+v_cndmask = 4x the VALU). Inputs finite (sigmoid/LN outputs).
__device__ __forceinline__ f16x8 max8(f16x8 a, f16x8 b) {
  union P { f16x8 h; f16x2 p[4]; } A, B, O;
  A.h = a; B.h = b;
  #pragma unroll
  for (int i = 0; i < 4; ++i)
    asm("v_pk_max_f16 %0, %1, %2" : "=v"(O.p[i]) : "v"(A.p[i]), "v"(B.p[i]));
  return O.h;
}

// ---------------- prep mega-kernel ----------------
// One launch covering three independent jobs (were 3 serialized launches):
//   blocks [0, gX)            : x -> x16 (f16, stride 160) + xg col-pad zeroing
//   blocks [gX, gX+90)        : weight reorder into MFMA frag order
//   blocks [gX+90, ...)       : zero bcnt
struct WDesc { const float* src; f16* dst; int K, NC, Kpad, NCpad; };
struct WAll { WDesc m[9]; };

__global__ __launch_bounds__(256) void prep_kernel(
    const float* __restrict__ x, f16* __restrict__ x16, f16* __restrict__ xg,
    int n, WAll wa, int* __restrict__ bcnt, int nzero, int gX) {
  const int bb = blockIdx.x;
  const int t = threadIdx.x;
  if (bb < gX) {
    // xprep, 8-col granule: vector f16x8 stores (16B), scalar f32 reads
    int idx = bb * 256 + t;
    if (idx >= n * 20) return;
    int r = idx / 20, g = idx - r * 20;
    int c0 = g * 8;
    f16x8 o;
    #pragma unroll
    for (int j = 0; j < 8; ++j) {
      int c = c0 + j;
      o[j] = (f16)((c < HC) ? x[(size_t)r * HC + c] : 0.0f);
    }
    *(f16x8*)&x16[(size_t)r * 160 + c0] = o;
    if (c0 >= 136) {
      f16x8 z = (f16x8){0,0,0,0,0,0,0,0};
      *(f16x8*)&xg[(size_t)r * 160 + c0] = z;
    } else if (c0 == 128) {
      #pragma unroll
      for (int c = 130; c < 136; ++c) xg[(size_t)r * 160 + c] = (f16)0.0f;
    }
  } else if (bb < gX + 90) {
    const int wb = bb - gX;
    const WDesc d = wa.m[wb / 10];
    const int KST = d.Kpad >> 5;
    const int total = (d.NCpad >> 4) * KST * 64;
    int idx = (wb % 10) * 256 + t;
    if (idx >= total) return;
    int nt  = idx / (KST * 64);
    int rem = idx - nt * (KST * 64);
    int ks  = rem >> 6;
    int l   = rem & 63;
    int nn  = nt * 16 + (l & 15);
    int k0  = ks * 32 + (l >> 4) * 8;
    f16x8 o;
    #pragma unroll
    for (int j = 0; j < 8; ++j) {
      int k = k0 + j;
      float v = (k < d.K && nn < d.NC) ? d.src[(size_t)k * d.NC + nn] : 0.0f;
      o[j] = (f16)v;
    }
    *((f16x8*)d.dst + idx) = o;
  } else {
    int i = (bb - gX - 90) * 256 + t;
    if (i < nzero) bcnt[i] = 0;
  }
}

// ---------------- graph build: two-level binning ----------------
__global__ void binscatter_kernel(const int* __restrict__ row, const int* __restrict__ col,
    int* __restrict__ bcnt, unsigned* __restrict__ bucket, int e, int nb) {
  const int g0 = xcc_id() * SUBB + ((blockIdx.x >> 3) & (SUBB - 1));
  int i = blockIdx.x * blockDim.x + threadIdx.x;
  if (i >= e) return;
  int c = col[i], r = row[i];
  int b = c >> 7;
  int cur = atomicAdd(&bcnt[g0 * nb + b], 1);
  if (cur < BCAP_S)
    bucket[((size_t)g0 * nb + b) * BCAP_S + cur] = ((unsigned)r << 7) | (unsigned)(c & 127);
}

__global__ __launch_bounds__(256) void build_kernel(const int* __restrict__ bcnt,
    const unsigned* __restrict__ bucket, int* __restrict__ ncnt,
    int* __restrict__ dense, float* __restrict__ dinv, int n, int nb) {
  __shared__ int lcnt[128];
  const int b = blockIdx.x;
  const int t = threadIdx.x;
  if (t < 128) lcnt[t] = 0;
  __syncthreads();
  const int wv = t >> 6, ln = t & 63;
  #pragma unroll 1
  for (int g = wv * 16; g < wv * 16 + 16; ++g) {
    const int cntg = min(bcnt[g * nb + b], BCAP_S);
    const unsigned* __restrict__ src = bucket + ((size_t)g * nb + b) * BCAP_S;
    for (int idx = ln; idx < cntg; idx += 64) {
      unsigned ev = src[idx];
      int cl = (int)(ev & 127u);
      int r  = (int)(ev >> 7);
      int s = atomicAdd(&lcnt[cl], 1);
      if (s < DENSW) dense[(size_t)((b << 7) + cl) * DENSW + s] = r;
    }
  }
  __syncthreads();
  if (t < 128) {
    int c = (b << 7) + t;
    if (c < n) {
      int cc = min(lcnt[t], DENSW);
      ncnt[c] = cc;
      dinv[c] = rsqrtf((float)(cc + 1));  // +1 self-loop
    }
  }
}

// ---------------- MFMA matmul ----------------
// Y[N,NC] = X[N,K] @ W[K,NC]; MODE 0: sigm(acc+bias); MODE 2: acc*dinv[row].
// A-fragments/dinv prefetched into registers before the W-staging barrier.
template<int KPAD, int RS, int NCPAD, int NC, int MODE>
__global__ __launch_bounds__(256, 4) void mm_mfma(
    const f16* __restrict__ X, const f16* __restrict__ Wt,
    const float* __restrict__ bias, f16* __restrict__ Y,
    const float* __restrict__ dinv, const f16* __restrict__ xor16,
    const float* __restrict__ initial, int n, int ngrid)
{
  constexpr int KST = KPAD / 32;
  constexpr int NT  = NCPAD / 16;
  constexpr int YRS = (MODE == 1) ? 160 : 128;
  constexpr int PSTR = (NCPAD == 128) ? 132 : 148;  // %16 == 4
  constexpr int LDSH = (NCPAD * KPAD > 128 * PSTR) ? NCPAD * KPAD : 128 * PSTR;
  __shared__ __align__(16) f16 Bs[LDSH];

  const int t = threadIdx.x;
  const int wid  = t >> 6;
  const int l    = t & 63;
  const int m15  = l & 15;
  const int quad = l >> 4;
  const int rw   = blockIdx.x * 128 + wid * 32;

  constexpr int BSW = NCPAD * KPAD / 8;
  #pragma unroll
  for (int i = 0; i < (BSW + 255) / 256; ++i) {
    int idx = t + i * 256;
    if (BSW % 256 == 0 || idx < BSW)
      ((f16x8*)Bs)[idx] = ((const f16x8*)Wt)[idx];
  }

  const f16* Xr0 = X + (size_t)(rw + m15) * RS;
  const f16* Xr1 = X + (size_t)(rw + 16 + m15) * RS;
  f16x8 a0r[KST], a1r[KST];
  #pragma unroll
  for (int ks = 0; ks < KST; ++ks) {
    const int off = ks * 32 + quad * 8;
    a0r[ks] = *(const f16x8*)(Xr0 + off);
    a1r[ks] = *(const f16x8*)(Xr1 + off);
  }

  const int r  = t >> 1;
  const int hf = t & 1;
  const int gr = blockIdx.x * 128 + r;
  float dv = 0.0f;
  if constexpr (MODE == 2) dv = (gr < n) ? dinv[gr] : 0.0f;

  f16x8 xo[8];
  f16x2 xo2;
  if constexpr (MODE == 1) {
    const f16* xp = xor16 + (size_t)(blockIdx.x * 128 + r) * 160;
    #pragma unroll
    for (int c8 = 0; c8 < 8; ++c8)
      xo[c8] = *(const f16x8*)(xp + hf * 64 + c8 * 8);
    xo2 = *(const f16x2*)(xp + 128);
  }

  __syncthreads();

  f32x4 acc[2][NT];
  #pragma unroll
  for (int mt = 0; mt < 2; ++mt)
    #pragma unroll
    for (int nt = 0; nt < NT; ++nt)
      acc[mt][nt] = (f32x4){0.f, 0.f, 0.f, 0.f};

  #pragma unroll
  for (int ks = 0; ks < KST; ++ks) {
    #pragma unroll
    for (int nt = 0; nt < NT; ++nt) {
      f16x8 b = *((const f16x8*)Bs + (nt * KST + ks) * 64 + l);
      acc[0][nt] = __builtin_amdgcn_mfma_f32_16x16x32_f16(a0r[ks], b, acc[0][nt], 0, 0, 0);
      acc[1][nt] = __builtin_amdgcn_mfma_f32_16x16x32_f16(a1r[ks], b, acc[1][nt], 0, 0, 0);
    }
  }

  __syncthreads();  // done reading Bs; reuse as transpose tile

  #pragma unroll
  for (int mt = 0; mt < 2; ++mt) {
    #pragma unroll
    for (int reg = 0; reg < 4; ++reg) {
      const int rl = wid * 32 + mt * 16 + quad * 4 + reg;
      #pragma unroll
      for (int nt = 0; nt < NT; ++nt)
        Bs[rl * PSTR + nt * 16 + m15] = (f16)acc[mt][nt][reg];
    }
  }
  __syncthreads();

  if (gr < n) {
    if constexpr (MODE == 0 || MODE == 2) {
      #pragma unroll
      for (int c8 = 0; c8 < 8; ++c8) {
        const int c0 = hf * 64 + c8 * 8;
        f16x8 v = *(const f16x8*)&Bs[r * PSTR + c0];
        f16x8 o;
        #pragma unroll
        for (int j = 0; j < 8; ++j) {
          float a = (float)v[j];
          if constexpr (MODE == 0) o[j] = (f16)sigm(a + bias[c0 + j]);
          else                     o[j] = (f16)(a * dv);
        }
        *(f16x8*)&Y[(size_t)gr * YRS + c0] = o;
      }
    } else {  // MODE 1, NC=130
      const bool hasInit = (gr >= ngrid);
      #pragma unroll
      for (int c8 = 0; c8 < 8; ++c8) {
        const int c0 = hf * 64 + c8 * 8;
        f16x8 v = *(const f16x8*)&Bs[r * PSTR + c0];
        f16x8 o;
        #pragma unroll
        for (int j = 0; j < 8; ++j) {
          const int col = c0 + j;
          float fv = sigm((float)v[j] + bias[col]);
          float xov = (float)xo[c8][j];
          float ip = hasInit ? initial[(size_t)(gr - ngrid) * 128 + col] : 0.0f;
          o[j] = (f16)(xov * fv + (1.0f - fv) * ip);
        }
        *(f16x8*)&Y[(size_t)gr * YRS + c0] = o;
      }
      if (hf) {
        #pragma unroll
        for (int k = 0; k < 2; ++k) {
          const int col = 128 + k;
          float fv = sigm((float)Bs[r * PSTR + col] + bias[col]);
          Y[(size_t)gr * YRS + col] = (f16)((float)xo2[k] * fv);
        }
      }
    }
  }
}

// ---------------- fused two-layer MLP ----------------
// Y = epilogue2( sigm(X@W1 + b1) @ W2 + b2 ); S lives only in LDS.
template<int K1PAD, int RS1, int NC2PAD, int NC2, int MODE2>
__global__ __launch_bounds__(256, 2) void mm_fused(
    const f16* __restrict__ X, const f16* __restrict__ W1t, const f16* __restrict__ W2t,
    const float* __restrict__ b1, const float* __restrict__ b2, f16* __restrict__ Y,
    const f16* __restrict__ xor16, const float* __restrict__ initial, int n, int ngrid)
{
  constexpr int KST1 = K1PAD / 32;   // 5
  constexpr int NT1  = 8;            // mid = 128 cols
  constexpr int KST2 = 4;            // K2 = 128
  constexpr int NT2  = NC2PAD / 16;  // 8 or 9
  constexpr int PSTR1 = 132;         // %16==4: conflict-light scatter
  constexpr int PSTR2 = (NC2PAD == 128) ? 132 : 148;
  constexpr int YRS  = (MODE2 == 1) ? 160 : 128;
  constexpr int W2U  = NC2PAD * 128;                 // f16 units
  constexpr int SC_A = K1PAD * 128;                  // W1 frag area
  constexpr int SC_B = 128 * PSTR2;                  // tr2 area (>= tr1)
  constexpr int SCU  = (SC_A > SC_B) ? SC_A : SC_B;
  __shared__ __align__(16) f16 L[W2U + SCU];
  f16* Bs2 = L;
  f16* SC  = L + W2U;

  const int t = threadIdx.x;
  const int wid  = t >> 6;
  const int l    = t & 63;
  const int m15  = l & 15;
  const int quad = l >> 4;
  const int rw   = blockIdx.x * 128 + wid * 32;

  constexpr int W1W = K1PAD * 128 / 8;
  constexpr int W2W = NC2PAD * 128 / 8;
  for (int i = t; i < W1W; i += 256) ((f16x8*)SC)[i]  = ((const f16x8*)W1t)[i];
  for (int i = t; i < W2W; i += 256) ((f16x8*)Bs2)[i] = ((const f16x8*)W2t)[i];

  const f16* Xr0 = X + (size_t)(rw + m15) * RS1;
  const f16* Xr1 = X + (size_t)(rw + 16 + m15) * RS1;
  f16x8 a0r[KST1], a1r[KST1];
  #pragma unroll
  for (int ks = 0; ks < KST1; ++ks) {
    const int off = ks * 32 + quad * 8;
    a0r[ks] = *(const f16x8*)(Xr0 + off);
    a1r[ks] = *(const f16x8*)(Xr1 + off);
  }

  f16x8 xo[8];
  f16x2 xo2;
  if constexpr (MODE2 == 1) {
    const f16* xp = xor16 + (size_t)(blockIdx.x * 128 + (t >> 1)) * 160;
    #pragma unroll
    for (int c8 = 0; c8 < 8; ++c8)
      xo[c8] = *(const f16x8*)(xp + (t & 1) * 64 + c8 * 8);
    xo2 = *(const f16x2*)(xp + 128);
  }

  float b1r[NT1];
  #pragma unroll
  for (int nt = 0; nt < NT1; ++nt) b1r[nt] = b1[nt * 16 + m15];

  __syncthreads();

  // ---- stage 1: acc1 = X @ W1 ----
  f32x4 acc1[2][NT1];
  #pragma unroll
  for (int mt = 0; mt < 2; ++mt)
    #pragma unroll
    for (int nt = 0; nt < NT1; ++nt)
      acc1[mt][nt] = (f32x4){0.f, 0.f, 0.f, 0.f};

  #pragma unroll
  for (int ks = 0; ks < KST1; ++ks) {
    #pragma unroll
    for (int nt = 0; nt < NT1; ++nt) {
      f16x8 b = *((const f16x8*)SC + (nt * KST1 + ks) * 64 + l);
      acc1[0][nt] = __builtin_amdgcn_mfma_f32_16x16x32_f16(a0r[ks], b, acc1[0][nt], 0, 0, 0);
      acc1[1][nt] = __builtin_amdgcn_mfma_f32_16x16x32_f16(a1r[ks], b, acc1[1][nt], 0, 0, 0);
    }
  }

  __syncthreads();  // all waves done reading W1 -> SC reusable

  // ---- scatter S = sigm(acc1 + b1) into SC (row-major, stride PSTR1) ----
  #pragma unroll
  for (int mt = 0; mt < 2; ++mt) {
    #pragma unroll
    for (int reg = 0; reg < 4; ++reg) {
      const int rl = wid * 32 + mt * 16 + quad * 4 + reg;
      #pragma unroll
      for (int nt = 0; nt < NT1; ++nt)
        SC[rl * PSTR1 + nt * 16 + m15] = (f16)sigm(acc1[mt][nt][reg] + b1r[nt]);
    }
  }
  __syncthreads();

  // ---- stage 2: acc2 = S @ W2 ----
  f32x4 acc2[2][NT2];
  #pragma unroll
  for (int mt = 0; mt < 2; ++mt)
    #pragma unroll
    for (int nt = 0; nt < NT2; ++nt)
      acc2[mt][nt] = (f32x4){0.f, 0.f, 0.f, 0.f};

  const int rA0 = wid * 32 + m15;
  const int rA1 = rA0 + 16;
  union A8 { f16x8 v; f16x4 q[2]; };
  #pragma unroll
  for (int ks = 0; ks < KST2; ++ks) {
    const int k0 = ks * 32 + quad * 8;
    A8 a0, a1;
    a0.q[0] = *(const f16x4*)&SC[rA0 * PSTR1 + k0];
    a0.q[1] = *(const f16x4*)&SC[rA0 * PSTR1 + k0 + 4];
    a1.q[0] = *(const f16x4*)&SC[rA1 * PSTR1 + k0];
    a1.q[1] = *(const f16x4*)&SC[rA1 * PSTR1 + k0 + 4];
    #pragma unroll
    for (int nt = 0; nt < NT2; ++nt) {
      f16x8 b = *((const f16x8*)Bs2 + (nt * KST2 + ks) * 64 + l);
      acc2[0][nt] = __builtin_amdgcn_mfma_f32_16x16x32_f16(a0.v, b, acc2[0][nt], 0, 0, 0);
      acc2[1][nt] = __builtin_amdgcn_mfma_f32_16x16x32_f16(a1.v, b, acc2[1][nt], 0, 0, 0);
    }
  }
  __syncthreads();  // done reading S -> SC reusable for tr2

  #pragma unroll
  for (int mt = 0; mt < 2; ++mt) {
    #pragma unroll
    for (int reg = 0; reg < 4; ++reg) {
      const int rl = wid * 32 + mt * 16 + quad * 4 + reg;
      #pragma unroll
      for (int nt = 0; nt < NT2; ++nt)
        SC[rl * PSTR2 + nt * 16 + m15] = (f16)acc2[mt][nt][reg];
    }
  }
  __syncthreads();

  const int r  = t >> 1;
  const int hf = t & 1;
  const int gr = blockIdx.x * 128 + r;
  if (gr < n) {
    if constexpr (MODE2 == 0) {
      #pragma unroll
      for (int c8 = 0; c8 < 8; ++c8) {
        const int c0 = hf * 64 + c8 * 8;
        f16x8 v = *(const f16x8*)&SC[r * PSTR2 + c0];
        f16x8 o;
        #pragma unroll
        for (int j = 0; j < 8; ++j)
          o[j] = (f16)sigm((float)v[j] + b2[c0 + j]);
        *(f16x8*)&Y[(size_t)gr * YRS + c0] = o;
      }
    } else {  // MODE2 == 1, NC2 = 130
      const bool hasInit = (gr >= ngrid);
      #pragma unroll
      for (int c8 = 0; c8 < 8; ++c8) {
        const int c0 = hf * 64 + c8 * 8;
        f16x8 v = *(const f16x8*)&SC[r * PSTR2 + c0];
        f16x8 o;
        #pragma unroll
        for (int j = 0; j < 8; ++j) {
          const int col = c0 + j;
          float fv = sigm((float)v[j] + b2[col]);
          float xov = (float)xo[c8][j];
          float ip = hasInit ? initial[(size_t)(gr - ngrid) * 128 + col] : 0.0f;
          o[j] = (f16)(xov * fv + (1.0f - fv) * ip);
        }
        *(f16x8*)&Y[(size_t)gr * YRS + c0] = o;
      }
      if (hf) {
        #pragma unroll
        for (int k = 0; k < 2; ++k) {
          const int col = 128 + k;
          float fv = sigm((float)SC[r * PSTR2 + col] + b2[col]);
          Y[(size_t)gr * YRS + col] = (f16)((float)xo2[k] * fv);
        }
      }
    }
  }
}

// ---------------- aggregation (lane-group batched gather) ----------------
// Index load trimmed to lanes<32 (128 B/dest vs 256 B): mean in-degree ~17,
// P(nc>32) ~ 1e-4 -> wave-uniform rare branch fetches the tail.
template<int MODE>
__global__ __launch_bounds__(256) void agg_kernel(
    const f16* __restrict__ G, const int* __restrict__ ncnt,
    const int* __restrict__ dense,
    const float* __restrict__ dinv, const float* __restrict__ bias,
    const float* __restrict__ gamma, const float* __restrict__ beta,
    const f16* __restrict__ xg, const f16* __restrict__ u,
    void* __restrict__ out, int n)
{
  const int wid = threadIdx.x >> 6, lane = threadIdx.x & 63;
  const int c = blockIdx.x * 4 + wid;
  if (c >= n) return;
  const int li = lane & 15, grp = lane >> 4;

  union F8 { f16x8 h; int4 i; };
  const int nc = min(ncnt[c], DENSW);
  int raw = 0;
  if (lane < 32) raw = dense[(size_t)c * DENSW + lane];  // coalesced 128B
  if (nc > 32) {                                         // rare, wave-uniform
    if (lane >= 32) raw = dense[(size_t)c * DENSW + lane];
  }
  const int myidx = (lane < nc) ? raw : c;               // self row is max-idempotent

  F8 m; m.h = *(const f16x8*)(G + (size_t)c * 128 + li * 8);  // self-loop
  F8 m2; m2.h = m.h;
  F8 m3; m3.h = m.h;
  F8 m4; m4.h = m.h;
  const int B = (nc + 3) >> 2;
  int b = 0;
  for (; b + 3 < B; b += 4) {
    int r0 = __shfl(myidx, (b + 0) * 4 + grp, 64);
    int r1 = __shfl(myidx, (b + 1) * 4 + grp, 64);
    int r2 = __shfl(myidx, (b + 2) * 4 + grp, 64);
    int r3 = __shfl(myidx, (b + 3) * 4 + grp, 64);
    F8 v0; v0.h = *(const f16x8*)(G + (size_t)r0 * 128 + li * 8);
    F8 v1; v1.h = *(const f16x8*)(G + (size_t)r1 * 128 + li * 8);
    F8 v2; v2.h = *(const f16x8*)(G + (size_t)r2 * 128 + li * 8);
    F8 v3; v3.h = *(const f16x8*)(G + (size_t)r3 * 128 + li * 8);
    m.h  = max8(m.h,  v0.h);
    m2.h = max8(m2.h, v1.h);
    m3.h = max8(m3.h, v2.h);
    m4.h = max8(m4.h, v3.h);
  }
  for (; b < B; ++b) {
    int r0 = __shfl(myidx, b * 4 + grp, 64);
    F8 v; v.h = *(const f16x8*)(G + (size_t)r0 * 128 + li * 8);
    m.h = max8(m.h, v.h);
  }
  m.h = max8(max8(m.h, m2.h), max8(m3.h, m4.h));

  #pragma unroll
  for (int st = 16; st <= 32; st <<= 1) {
    F8 o;
    #pragma unroll
    for (int d = 0; d < 4; ++d) o.i[d] = __shfl_xor(m.i[d], st, 64);
    m.h = max8(m.h, o.h);
  }

  const float dc = dinv[c];
  float v[8];
  float s = 0.f, sq = 0.f;
  #pragma unroll
  for (int j = 0; j < 8; ++j) {
    v[j] = (float)m.h[j] * dc + bias[li * 8 + j];
    s += v[j]; sq += v[j] * v[j];
  }

  if constexpr (MODE == 2) {
    if (grp == 0) {
      f16x8 xv = *(const f16x8*)(xg + (size_t)c * 160 + li * 8);
      f16x8 uv = *(const f16x8*)(u  + (size_t)c * 128 + li * 8);
      float o[8];
      #pragma unroll
      for (int j = 0; j < 8; ++j) o[j] = (float)xv[j] + v[j] * (float)uv[j];
      float* op = (float*)out + (size_t)c * 128 + li * 8;
      *(float4*)op       = make_float4(o[0], o[1], o[2], o[3]);
      *(float4*)(op + 4) = make_float4(o[4], o[5], o[6], o[7]);
    }
  } else {
    #pragma unroll
    for (int st = 1; st <= 8; st <<= 1) {
      s  += __shfl_xor(s, st, 64);
      sq += __shfl_xor(sq, st, 64);
    }
    float mu  = s * (1.0f / 128.0f);
    float var = sq * (1.0f / 128.0f) - mu * mu;
    float rstd = rsqrtf(var + 1e-5f);
    if (grp == 0) {
      f16x8 ov;
      #pragma unroll
      for (int j = 0; j < 8; ++j) {
        float o = (v[j] - mu) * rstd * gamma[li * 8 + j] + beta[li * 8 + j];
        if constexpr (MODE == 0) o = fmaxf(o, 0.0f);
        ov[j] = (f16)o;
      }
      *(f16x8*)((f16*)out + (size_t)c * 128 + li * 8) = ov;
    }
  }
}

extern "C" void kernel_launch(void* const* d_in, const int* in_sizes, int n_in,
                              void* d_out, int out_size, void* d_ws, size_t ws_size,
                              hipStream_t stream) {
  (void)n_in; (void)out_size; (void)ws_size;
  const float* x       = (const float*)d_in[0];
  const int*   ei      = (const int*)d_in[1];
  const float* initial = (const float*)d_in[2];
  const float* Wf1 = (const float*)d_in[3];  const float* bf1 = (const float*)d_in[4];
  const float* Wf2 = (const float*)d_in[5];  const float* bf2 = (const float*)d_in[6];
  const float* Wu1 = (const float*)d_in[7];  const float* bu1 = (const float*)d_in[8];
  const float* Wu2 = (const float*)d_in[9];  const float* bu2 = (const float*)d_in[10];
  const float* Wc1 = (const float*)d_in[11]; const float* bc1 = (const float*)d_in[12];
  const float* Wc2 = (const float*)d_in[13]; const float* bc2 = (const float*)d_in[14];
  const float* Wc3 = (const float*)d_in[15]; const float* bc3 = (const float*)d_in[16];
  const float* Wc4 = (const float*)d_in[17]; const float* bc4 = (const float*)d_in[18];
  const float* Wco = (const float*)d_in[19]; const float* bco = (const float*)d_in[20];
  const float* g3  = (const float*)d_in[21]; const float* bn3 = (const float*)d_in[22];
  const float* g6  = (const float*)d_in[23]; const float* bn6 = (const float*)d_in[24];
  const float* g7  = (const float*)d_in[25]; const float* bn7 = (const float*)d_in[26];

  const int N  = in_sizes[0] / HC;   // 100000
  const int E  = in_sizes[1] / 2;    // 1600000
  const int NG = N - NIO;            // 99872
  const int NP = N + 128;            // padded rows for OOB-safe A-frag loads
  const int NB = (N + 127) / 128;    // 782 coarse buckets
  const int NSEG = 8 * SUBB;         // 64 append segments per bucket

  char* w = (char*)d_ws;
  auto carve = [&](size_t bytes) {
    char* p = w; w += (bytes + 255) & ~(size_t)255; return p;
  };
  int*      bcnt   = (int*)     carve((size_t)NB * NSEG * 4);
  unsigned* bucket = (unsigned*)carve((size_t)NB * NSEG * BCAP_S * 4);  // 25.6 MB
  int*      ncnt   = (int*)     carve((size_t)N * 4);
  int*      dense  = (int*)     carve((size_t)N * DENSW * 4);      // 25.6 MB
  float*    dinv   = (float*)   carve((size_t)N * 4);
  f16*      x16    = (f16*)     carve((size_t)NP * 160 * 2);
  f16*      xg     = (f16*)     carve((size_t)NP * 160 * 2);
  f16*      u      = (f16*)     carve((size_t)N  * 128 * 2);
  f16*      G      = (f16*)     carve((size_t)N  * 128 * 2);
  f16*      H      = (f16*)     carve((size_t)NP * 128 * 2);
  f16*      Wt_f1  = (f16*)     carve(160 * 128 * 2);
  f16*      Wt_f2  = (f16*)     carve(128 * 144 * 2);
  f16*      Wt_u1  = (f16*)     carve(160 * 128 * 2);
  f16*      Wt_u2  = (f16*)     carve(128 * 128 * 2);
  f16*      Wt_c1  = (f16*)     carve(160 * 128 * 2);
  f16*      Wt_c2  = (f16*)     carve(128 * 128 * 2);
  f16*      Wt_c3  = (f16*)     carve(128 * 128 * 2);
  f16*      Wt_c4  = (f16*)     carve(128 * 128 * 2);
  f16*      Wt_co  = (f16*)     carve(128 * 128 * 2);

  const int* erow = ei;
  const int* ecol = ei + E;

  const int gE = (E + 255) / 256;
  const int gM = (N + 127) / 128;
  const int gA = (N + 3) / 4;

  // fused prep: xprep (vectorized) + wprep + bcnt zero in ONE launch
  WAll wa;
  wa.m[0] = {Wf1, Wt_f1, HC,  HID, 160, 128};
  wa.m[1] = {Wf2, Wt_f2, HID, HC,  128, 144};
  wa.m[2] = {Wu1, Wt_u1, HC,  HID, 160, 128};
  wa.m[3] = {Wu2, Wt_u2, HID, HID, 128, 128};
  wa.m[4] = {Wc1, Wt_c1, HC,  HID, 160, 128};
  wa.m[5] = {Wc2, Wt_c2, HID, HID, 128, 128};
  wa.m[6] = {Wc3, Wt_c3, HID, HID, 128, 128};
  wa.m[7] = {Wc4, Wt_c4, HID, HID, 128, 128};
  wa.m[8] = {Wco, Wt_co, HID, HID, 128, 128};
  const int gX = (N * 20 + 255) / 256;
  const int gZ = (NB * NSEG + 255) / 256;
  prep_kernel<<<gX + 90 + gZ, 256, 0, stream>>>(x, x16, xg, N, wa, bcnt, NB * NSEG, gX);

  // graph build (two-level binning)
  binscatter_kernel<<<gE, 256, 0, stream>>>(erow, ecol, bcnt, bucket, E, NB);
  build_kernel<<<NB, 256, 0, stream>>>(bcnt, bucket, ncnt, dense, dinv, N, NB);

  // forget gate (f1+f2 fused): xg = mix(sigm(sigm(x@Wf1+bf1)@Wf2+bf2))
  mm_fused<160, 160, 144, 130, 1><<<gM, 256, 0, stream>>>(
      x16, Wt_f1, Wt_f2, bf1, bf2, xg, x16, initial, N, NG);
  // update gate (u1+u2 fused): u = sigm(sigm(xg@Wu1+bu1)@Wu2+bu2)
  mm_fused<160, 160, 128, 128, 0><<<gM, 256, 0, stream>>>(
      xg, Wt_u1, Wt_u2, bu1, bu2, u, nullptr, nullptr, N, NG);

  // gcn1: relu(LN(..., g3, bn3))
  mm_mfma<160, 160, 128, 128, 2><<<gM, 256, 0, stream>>>(xg, Wt_c1, nullptr, G, dinv, nullptr, nullptr, N, NG);
  agg_kernel<0><<<gA, 256, 0, stream>>>(G, ncnt, dense, dinv, bc1, g3, bn3, nullptr, nullptr, H, N);
  // gcn2: LN(..., g3, bn3)
  mm_mfma<128, 128, 128, 128, 2><<<gM, 256, 0, stream>>>(H, Wt_c2, nullptr, G, dinv, nullptr, nullptr, N, NG);
  agg_kernel<1><<<gA, 256, 0, stream>>>(G, ncnt, dense, dinv, bc2, g3, bn3, nullptr, nullptr, H, N);
  // gcn3: LN(..., g6, bn6)
  mm_mfma<128, 128, 128, 128, 2><<<gM, 256, 0, stream>>>(H, Wt_c3, nullptr, G, dinv, nullptr, nullptr, N, NG);
  agg_kernel<1><<<gA, 256, 0, stream>>>(G, ncnt, dense, dinv, bc3, g6, bn6, nullptr, nullptr, H, N);
  // gcn4: LN(..., g7, bn7)
  mm_mfma<128, 128, 128, 128, 2><<<gM, 256, 0, stream>>>(H, Wt_c4, nullptr, G, dinv, nullptr, nullptr, N, NG);
  agg_kernel<1><<<gA, 256, 0, stream>>>(G, ncnt, dense, dinv, bc4, g7, bn7, nullptr, nullptr, H, N);
  // gcn5 + final: out = xg[:, :128] + (agg + bco) * u
  mm_mfma<128, 128, 128, 128, 2><<<gM, 256, 0, stream>>>(H, Wt_co, nullptr, G, dinv, nullptr, nullptr, N, NG);
  agg_kernel<2><<<gA, 256, 0, stream>>>(G, ncnt, dense, dinv, bco, nullptr, nullptr, xg, u, d_out, N);
}

// Round 9
// 726.173 us; speedup vs baseline: 1.2431x; 1.0172x over previous
//
#include <hip/hip_runtime.h>
#include <cstdint>

#define HID 128
#define HC  130
#define NIO 128
#define DENSW 64     // dense ELL width (max in-degree ~45 for Poisson(16))
#define SUBB 8       // sub-cursors per (xcd,bucket): kills same-address atomic serialization
#define BCAP_S 128   // per-(xcd,sub,bucket) capacity; mean ~32 (+17 sigma), 25.6MB total

typedef _Float16 f16;
typedef _Float16 f16x2 __attribute__((ext_vector_type(2)));
typedef _Float16 f16x4 __attribute__((ext_vector_type(4)));
typedef _Float16 f16x8 __attribute__((ext_vector_type(8)));
typedef float    f32x4 __attribute__((ext_vector_type(4)));

__device__ __forceinline__ float sigm(float z) {
  return 1.0f / (1.0f + __expf(-z));
}

__device__ __forceinline__ int xcc_id() {
  int x;
  asm volatile("s_getreg_b32 %0, hwreg(HW_REG_XCC_ID)" : "=s"(x));
  return x & 7;
}

// Packed f16 max: v_pk_max_f16 does 2 elements/op (ternary lowers to
// v_cmp+v_cndmask = 4x the VALU). Inputs finite (sigmoid/LN outputs).
__device__ __forceinline__ f16x8 max8(f16x8 a, f16x8 b) {
  union P { f16x8 h; f16x2 p[4]; } A, B, O;
  A.h = a; B.h = b;
  #pragma unroll
  for (int i = 0; i < 4; ++i)
    asm("v_pk_max_f16 %0, %1, %2" : "=v"(O.p[i]) : "v"(A.p[i]), "v"(B.p[i]));
  return O.h;
}

// ---------------- prep mega-kernel ----------------
struct WDesc { const float* src; f16* dst; int K, NC, Kpad, NCpad; };
struct WAll { WDesc m[9]; };

__global__ __launch_bounds__(256) void prep_kernel(
    const float* __restrict__ x, f16* __restrict__ x16, f16* __restrict__ xg,
    int n, WAll wa, int* __restrict__ bcnt, int nzero, int gX) {
  const int bb = blockIdx.x;
  const int t = threadIdx.x;
  if (bb < gX) {
    int idx = bb * 256 + t;
    if (idx >= n * 20) return;
    int r = idx / 20, g = idx - r * 20;
    int c0 = g * 8;
    f16x8 o;
    #pragma unroll
    for (int j = 0; j < 8; ++j) {
      int c = c0 + j;
      o[j] = (f16)((c < HC) ? x[(size_t)r * HC + c] : 0.0f);
    }
    *(f16x8*)&x16[(size_t)r * 160 + c0] = o;
    if (c0 >= 136) {
      f16x8 z = (f16x8){0,0,0,0,0,0,0,0};
      *(f16x8*)&xg[(size_t)r * 160 + c0] = z;
    } else if (c0 == 128) {
      #pragma unroll
      for (int c = 130; c < 136; ++c) xg[(size_t)r * 160 + c] = (f16)0.0f;
    }
  } else if (bb < gX + 90) {
    const int wb = bb - gX;
    const WDesc d = wa.m[wb / 10];
    const int KST = d.Kpad >> 5;
    const int total = (d.NCpad >> 4) * KST * 64;
    int idx = (wb % 10) * 256 + t;
    if (idx >= total) return;
    int nt  = idx / (KST * 64);
    int rem = idx - nt * (KST * 64);
    int ks  = rem >> 6;
    int l   = rem & 63;
    int nn  = nt * 16 + (l & 15);
    int k0  = ks * 32 + (l >> 4) * 8;
    f16x8 o;
    #pragma unroll
    for (int j = 0; j < 8; ++j) {
      int k = k0 + j;
      float v = (k < d.K && nn < d.NC) ? d.src[(size_t)k * d.NC + nn] : 0.0f;
      o[j] = (f16)v;
    }
    *((f16x8*)d.dst + idx) = o;
  } else {
    int i = (bb - gX - 90) * 256 + t;
    if (i < nzero) bcnt[i] = 0;
  }
}

// ---------------- graph build: two-level binning ----------------
__global__ void binscatter_kernel(const int* __restrict__ row, const int* __restrict__ col,
    int* __restrict__ bcnt, unsigned* __restrict__ bucket, int e, int nb) {
  const int g0 = xcc_id() * SUBB + ((blockIdx.x >> 3) & (SUBB - 1));
  int i = blockIdx.x * blockDim.x + threadIdx.x;
  if (i >= e) return;
  int c = col[i], r = row[i];
  int b = c >> 7;
  int cur = atomicAdd(&bcnt[g0 * nb + b], 1);
  if (cur < BCAP_S)
    bucket[((size_t)g0 * nb + b) * BCAP_S + cur] = ((unsigned)r << 7) | (unsigned)(c & 127);
}

__global__ __launch_bounds__(256) void build_kernel(const int* __restrict__ bcnt,
    const unsigned* __restrict__ bucket, int* __restrict__ ncnt,
    int* __restrict__ dense, float* __restrict__ dinv, int n, int nb) {
  __shared__ int lcnt[128];
  const int b = blockIdx.x;
  const int t = threadIdx.x;
  if (t < 128) lcnt[t] = 0;
  __syncthreads();
  const int wv = t >> 6, ln = t & 63;
  #pragma unroll 1
  for (int g = wv * 16; g < wv * 16 + 16; ++g) {
    const int cntg = min(bcnt[g * nb + b], BCAP_S);
    const unsigned* __restrict__ src = bucket + ((size_t)g * nb + b) * BCAP_S;
    for (int idx = ln; idx < cntg; idx += 64) {
      unsigned ev = src[idx];
      int cl = (int)(ev & 127u);
      int r  = (int)(ev >> 7);
      int s = atomicAdd(&lcnt[cl], 1);
      if (s < DENSW) dense[(size_t)((b << 7) + cl) * DENSW + s] = r;
    }
  }
  __syncthreads();
  if (t < 128) {
    int c = (b << 7) + t;
    if (c < n) {
      int cc = min(lcnt[t], DENSW);
      ncnt[c] = cc;
      dinv[c] = rsqrtf((float)(cc + 1));  // +1 self-loop
    }
  }
}

// ---------------- MFMA matmul ----------------
// Y[N,NC] = X[N,K] @ W[K,NC]; MODE 0: sigm(acc+bias); MODE 2: acc*dinv[row].
// MROWS = rows per block (128 or 64). 64-row tiles double the grid (1563 vs
// 782 blocks, ~6/CU demand vs 3) so resident blocks sit at DIFFERENT phases
// and each other's memory phases get hidden (m114-style wave-level overlap;
// R7 showed intra-block ILP hoisting alone is null).
template<int KPAD, int RS, int NCPAD, int NC, int MODE, int MROWS>
__global__ __launch_bounds__(256, 4) void mm_mfma(
    const f16* __restrict__ X, const f16* __restrict__ Wt,
    const float* __restrict__ bias, f16* __restrict__ Y,
    const float* __restrict__ dinv, const f16* __restrict__ xor16,
    const float* __restrict__ initial, int n, int ngrid)
{
  static_assert(MODE != 1 || MROWS == 128, "MODE1 only at 128 rows");
  constexpr int KST = KPAD / 32;
  constexpr int NT  = NCPAD / 16;
  constexpr int MT  = MROWS / 64;          // m-tiles per wave: 2 or 1
  constexpr int RPW = MROWS / 4;           // rows per wave: 32 or 16
  constexpr int YRS = (MODE == 1) ? 160 : 128;
  constexpr int PSTR = (NCPAD == 128) ? 132 : 148;  // %16 == 4
  constexpr int LDSH = (NCPAD * KPAD > MROWS * PSTR) ? NCPAD * KPAD : MROWS * PSTR;
  __shared__ __align__(16) f16 Bs[LDSH];

  const int t = threadIdx.x;
  const int wid  = t >> 6;
  const int l    = t & 63;
  const int m15  = l & 15;
  const int quad = l >> 4;
  const int rw   = blockIdx.x * MROWS + wid * RPW;

  constexpr int BSW = NCPAD * KPAD / 8;
  #pragma unroll
  for (int i = 0; i < (BSW + 255) / 256; ++i) {
    int idx = t + i * 256;
    if (BSW % 256 == 0 || idx < BSW)
      ((f16x8*)Bs)[idx] = ((const f16x8*)Wt)[idx];
  }

  const f16* Xr0 = X + (size_t)(rw + m15) * RS;
  const f16* Xr1 = X + (size_t)(rw + 16 + m15) * RS;  // used only if MT==2
  f16x8 a0r[KST], a1r[KST];
  #pragma unroll
  for (int ks = 0; ks < KST; ++ks) {
    const int off = ks * 32 + quad * 8;
    a0r[ks] = *(const f16x8*)(Xr0 + off);
    if constexpr (MT == 2) a1r[ks] = *(const f16x8*)(Xr1 + off);
  }

  // epilogue geometry: TPR threads per row, CSP cols per thread
  constexpr int TPR = 256 / MROWS;   // 2 or 4
  constexpr int CSP = 128 / TPR;     // 64 or 32
  const int r  = t / TPR;
  const int cp = t % TPR;
  const int gr = blockIdx.x * MROWS + r;
  float dv = 0.0f;
  if constexpr (MODE == 2) dv = (gr < n) ? dinv[gr] : 0.0f;

  f16x8 xo[CSP / 8];
  f16x2 xo2;
  if constexpr (MODE == 1) {
    const f16* xp = xor16 + (size_t)gr * 160;
    #pragma unroll
    for (int c8 = 0; c8 < CSP / 8; ++c8)
      xo[c8] = *(const f16x8*)(xp + cp * CSP + c8 * 8);
    xo2 = *(const f16x2*)(xp + 128);
  }

  __syncthreads();

  f32x4 acc[MT][NT];
  #pragma unroll
  for (int mt = 0; mt < MT; ++mt)
    #pragma unroll
    for (int nt = 0; nt < NT; ++nt)
      acc[mt][nt] = (f32x4){0.f, 0.f, 0.f, 0.f};

  #pragma unroll
  for (int ks = 0; ks < KST; ++ks) {
    #pragma unroll
    for (int nt = 0; nt < NT; ++nt) {
      f16x8 b = *((const f16x8*)Bs + (nt * KST + ks) * 64 + l);
      acc[0][nt] = __builtin_amdgcn_mfma_f32_16x16x32_f16(a0r[ks], b, acc[0][nt], 0, 0, 0);
      if constexpr (MT == 2)
        acc[1][nt] = __builtin_amdgcn_mfma_f32_16x16x32_f16(a1r[ks], b, acc[1][nt], 0, 0, 0);
    }
  }

  __syncthreads();  // done reading Bs; reuse as transpose tile

  #pragma unroll
  for (int mt = 0; mt < MT; ++mt) {
    #pragma unroll
    for (int reg = 0; reg < 4; ++reg) {
      const int rl = wid * RPW + mt * 16 + quad * 4 + reg;
      #pragma unroll
      for (int nt = 0; nt < NT; ++nt)
        Bs[rl * PSTR + nt * 16 + m15] = (f16)acc[mt][nt][reg];
    }
  }
  __syncthreads();

  if (gr < n) {
    if constexpr (MODE == 0 || MODE == 2) {
      #pragma unroll
      for (int c8 = 0; c8 < CSP / 8; ++c8) {
        const int c0 = cp * CSP + c8 * 8;
        f16x8 v = *(const f16x8*)&Bs[r * PSTR + c0];
        f16x8 o;
        #pragma unroll
        for (int j = 0; j < 8; ++j) {
          float a = (float)v[j];
          if constexpr (MODE == 0) o[j] = (f16)sigm(a + bias[c0 + j]);
          else                     o[j] = (f16)(a * dv);
        }
        *(f16x8*)&Y[(size_t)gr * YRS + c0] = o;
      }
    } else {  // MODE 1, NC=130 (MROWS==128, TPR==2)
      const bool hasInit = (gr >= ngrid);
      #pragma unroll
      for (int c8 = 0; c8 < CSP / 8; ++c8) {
        const int c0 = cp * CSP + c8 * 8;
        f16x8 v = *(const f16x8*)&Bs[r * PSTR + c0];
        f16x8 o;
        #pragma unroll
        for (int j = 0; j < 8; ++j) {
          const int col = c0 + j;
          float fv = sigm((float)v[j] + bias[col]);
          float xov = (float)xo[c8][j];
          float ip = hasInit ? initial[(size_t)(gr - ngrid) * 128 + col] : 0.0f;
          o[j] = (f16)(xov * fv + (1.0f - fv) * ip);
        }
        *(f16x8*)&Y[(size_t)gr * YRS + c0] = o;
      }
      if (cp == 1) {
        #pragma unroll
        for (int k = 0; k < 2; ++k) {
          const int col = 128 + k;
          float fv = sigm((float)Bs[r * PSTR + col] + bias[col]);
          Y[(size_t)gr * YRS + col] = (f16)((float)xo2[k] * fv);
        }
      }
    }
  }
}

// ---------------- fused two-layer MLP ----------------
// Y = epilogue2( sigm(X@W1 + b1) @ W2 + b2 ); S lives only in LDS.
template<int K1PAD, int RS1, int NC2PAD, int NC2, int MODE2>
__global__ __launch_bounds__(256, 2) void mm_fused(
    const f16* __restrict__ X, const f16* __restrict__ W1t, const f16* __restrict__ W2t,
    const float* __restrict__ b1, const float* __restrict__ b2, f16* __restrict__ Y,
    const f16* __restrict__ xor16, const float* __restrict__ initial, int n, int ngrid)
{
  constexpr int KST1 = K1PAD / 32;   // 5
  constexpr int NT1  = 8;            // mid = 128 cols
  constexpr int KST2 = 4;            // K2 = 128
  constexpr int NT2  = NC2PAD / 16;  // 8 or 9
  constexpr int PSTR1 = 132;         // %16==4: conflict-light scatter
  constexpr int PSTR2 = (NC2PAD == 128) ? 132 : 148;
  constexpr int YRS  = (MODE2 == 1) ? 160 : 128;
  constexpr int W2U  = NC2PAD * 128;                 // f16 units
  constexpr int SC_A = K1PAD * 128;                  // W1 frag area
  constexpr int SC_B = 128 * PSTR2;                  // tr2 area (>= tr1)
  constexpr int SCU  = (SC_A > SC_B) ? SC_A : SC_B;
  __shared__ __align__(16) f16 L[W2U + SCU];
  f16* Bs2 = L;
  f16* SC  = L + W2U;

  const int t = threadIdx.x;
  const int wid  = t >> 6;
  const int l    = t & 63;
  const int m15  = l & 15;
  const int quad = l >> 4;
  const int rw   = blockIdx.x * 128 + wid * 32;

  constexpr int W1W = K1PAD * 128 / 8;
  constexpr int W2W = NC2PAD * 128 / 8;
  for (int i = t; i < W1W; i += 256) ((f16x8*)SC)[i]  = ((const f16x8*)W1t)[i];
  for (int i = t; i < W2W; i += 256) ((f16x8*)Bs2)[i] = ((const f16x8*)W2t)[i];

  const f16* Xr0 = X + (size_t)(rw + m15) * RS1;
  const f16* Xr1 = X + (size_t)(rw + 16 + m15) * RS1;
  f16x8 a0r[KST1], a1r[KST1];
  #pragma unroll
  for (int ks = 0; ks < KST1; ++ks) {
    const int off = ks * 32 + quad * 8;
    a0r[ks] = *(const f16x8*)(Xr0 + off);
    a1r[ks] = *(const f16x8*)(Xr1 + off);
  }

  f16x8 xo[8];
  f16x2 xo2;
  if constexpr (MODE2 == 1) {
    const f16* xp = xor16 + (size_t)(blockIdx.x * 128 + (t >> 1)) * 160;
    #pragma unroll
    for (int c8 = 0; c8 < 8; ++c8)
      xo[c8] = *(const f16x8*)(xp + (t & 1) * 64 + c8 * 8);
    xo2 = *(const f16x2*)(xp + 128);
  }

  float b1r[NT1];
  #pragma unroll
  for (int nt = 0; nt < NT1; ++nt) b1r[nt] = b1[nt * 16 + m15];

  __syncthreads();

  // ---- stage 1: acc1 = X @ W1 ----
  f32x4 acc1[2][NT1];
  #pragma unroll
  for (int mt = 0; mt < 2; ++mt)
    #pragma unroll
    for (int nt = 0; nt < NT1; ++nt)
      acc1[mt][nt] = (f32x4){0.f, 0.f, 0.f, 0.f};

  #pragma unroll
  for (int ks = 0; ks < KST1; ++ks) {
    #pragma unroll
    for (int nt = 0; nt < NT1; ++nt) {
      f16x8 b = *((const f16x8*)SC + (nt * KST1 + ks) * 64 + l);
      acc1[0][nt] = __builtin_amdgcn_mfma_f32_16x16x32_f16(a0r[ks], b, acc1[0][nt], 0, 0, 0);
      acc1[1][nt] = __builtin_amdgcn_mfma_f32_16x16x32_f16(a1r[ks], b, acc1[1][nt], 0, 0, 0);
    }
  }

  __syncthreads();  // all waves done reading W1 -> SC reusable

  // ---- scatter S = sigm(acc1 + b1) into SC (row-major, stride PSTR1) ----
  #pragma unroll
  for (int mt = 0; mt < 2; ++mt) {
    #pragma unroll
    for (int reg = 0; reg < 4; ++reg) {
      const int rl = wid * 32 + mt * 16 + quad * 4 + reg;
      #pragma unroll
      for (int nt = 0; nt < NT1; ++nt)
        SC[rl * PSTR1 + nt * 16 + m15] = (f16)sigm(acc1[mt][nt][reg] + b1r[nt]);
    }
  }
  __syncthreads();

  // ---- stage 2: acc2 = S @ W2 ----
  f32x4 acc2[2][NT2];
  #pragma unroll
  for (int mt = 0; mt < 2; ++mt)
    #pragma unroll
    for (int nt = 0; nt < NT2; ++nt)
      acc2[mt][nt] = (f32x4){0.f, 0.f, 0.f, 0.f};

  const int rA0 = wid * 32 + m15;
  const int rA1 = rA0 + 16;
  union A8 { f16x8 v; f16x4 q[2]; };
  #pragma unroll
  for (int ks = 0; ks < KST2; ++ks) {
    const int k0 = ks * 32 + quad * 8;
    A8 a0, a1;
    a0.q[0] = *(const f16x4*)&SC[rA0 * PSTR1 + k0];
    a0.q[1] = *(const f16x4*)&SC[rA0 * PSTR1 + k0 + 4];
    a1.q[0] = *(const f16x4*)&SC[rA1 * PSTR1 + k0];
    a1.q[1] = *(const f16x4*)&SC[rA1 * PSTR1 + k0 + 4];
    #pragma unroll
    for (int nt = 0; nt < NT2; ++nt) {
      f16x8 b = *((const f16x8*)Bs2 + (nt * KST2 + ks) * 64 + l);
      acc2[0][nt] = __builtin_amdgcn_mfma_f32_16x16x32_f16(a0.v, b, acc2[0][nt], 0, 0, 0);
      acc2[1][nt] = __builtin_amdgcn_mfma_f32_16x16x32_f16(a1.v, b, acc2[1][nt], 0, 0, 0);
    }
  }
  __syncthreads();  // done reading S -> SC reusable for tr2

  #pragma unroll
  for (int mt = 0; mt < 2; ++mt) {
    #pragma unroll
    for (int reg = 0; reg < 4; ++reg) {
      const int rl = wid * 32 + mt * 16 + quad * 4 + reg;
      #pragma unroll
      for (int nt = 0; nt < NT2; ++nt)
        SC[rl * PSTR2 + nt * 16 + m15] = (f16)acc2[mt][nt][reg];
    }
  }
  __syncthreads();

  const int r  = t >> 1;
  const int hf = t & 1;
  const int gr = blockIdx.x * 128 + r;
  if (gr < n) {
    if constexpr (MODE2 == 0) {
      #pragma unroll
      for (int c8 = 0; c8 < 8; ++c8) {
        const int c0 = hf * 64 + c8 * 8;
        f16x8 v = *(const f16x8*)&SC[r * PSTR2 + c0];
        f16x8 o;
        #pragma unroll
        for (int j = 0; j < 8; ++j)
          o[j] = (f16)sigm((float)v[j] + b2[c0 + j]);
        *(f16x8*)&Y[(size_t)gr * YRS + c0] = o;
      }
    } else {  // MODE2 == 1, NC2 = 130
      const bool hasInit = (gr >= ngrid);
      #pragma unroll
      for (int c8 = 0; c8 < 8; ++c8) {
        const int c0 = hf * 64 + c8 * 8;
        f16x8 v = *(const f16x8*)&SC[r * PSTR2 + c0];
        f16x8 o;
        #pragma unroll
        for (int j = 0; j < 8; ++j) {
          const int col = c0 + j;
          float fv = sigm((float)v[j] + b2[col]);
          float xov = (float)xo[c8][j];
          float ip = hasInit ? initial[(size_t)(gr - ngrid) * 128 + col] : 0.0f;
          o[j] = (f16)(xov * fv + (1.0f - fv) * ip);
        }
        *(f16x8*)&Y[(size_t)gr * YRS + c0] = o;
      }
      if (hf) {
        #pragma unroll
        for (int k = 0; k < 2; ++k) {
          const int col = 128 + k;
          float fv = sigm((float)SC[r * PSTR2 + col] + b2[col]);
          Y[(size_t)gr * YRS + col] = (f16)((float)xo2[k] * fv);
        }
      }
    }
  }
}

// ---------------- aggregation (lane-group batched gather) ----------------
template<int MODE>
__global__ __launch_bounds__(256) void agg_kernel(
    const f16* __restrict__ G, const int* __restrict__ ncnt,
    const int* __restrict__ dense,
    const float* __restrict__ dinv, const float* __restrict__ bias,
    const float* __restrict__ gamma, const float* __restrict__ beta,
    const f16* __restrict__ xg, const f16* __restrict__ u,
    void* __restrict__ out, int n)
{
  const int wid = threadIdx.x >> 6, lane = threadIdx.x & 63;
  const int c = blockIdx.x * 4 + wid;
  if (c >= n) return;
  const int li = lane & 15, grp = lane >> 4;

  union F8 { f16x8 h; int4 i; };
  const int nc = min(ncnt[c], DENSW);
  int raw = 0;
  if (lane < 32) raw = dense[(size_t)c * DENSW + lane];  // coalesced 128B
  if (nc > 32) {                                         // rare, wave-uniform
    if (lane >= 32) raw = dense[(size_t)c * DENSW + lane];
  }
  const int myidx = (lane < nc) ? raw : c;               // self row is max-idempotent

  F8 m; m.h = *(const f16x8*)(G + (size_t)c * 128 + li * 8);  // self-loop
  F8 m2; m2.h = m.h;
  F8 m3; m3.h = m.h;
  F8 m4; m4.h = m.h;
  const int B = (nc + 3) >> 2;
  int b = 0;
  for (; b + 3 < B; b += 4) {
    int r0 = __shfl(myidx, (b + 0) * 4 + grp, 64);
    int r1 = __shfl(myidx, (b + 1) * 4 + grp, 64);
    int r2 = __shfl(myidx, (b + 2) * 4 + grp, 64);
    int r3 = __shfl(myidx, (b + 3) * 4 + grp, 64);
    F8 v0; v0.h = *(const f16x8*)(G + (size_t)r0 * 128 + li * 8);
    F8 v1; v1.h = *(const f16x8*)(G + (size_t)r1 * 128 + li * 8);
    F8 v2; v2.h = *(const f16x8*)(G + (size_t)r2 * 128 + li * 8);
    F8 v3; v3.h = *(const f16x8*)(G + (size_t)r3 * 128 + li * 8);
    m.h  = max8(m.h,  v0.h);
    m2.h = max8(m2.h, v1.h);
    m3.h = max8(m3.h, v2.h);
    m4.h = max8(m4.h, v3.h);
  }
  for (; b < B; ++b) {
    int r0 = __shfl(myidx, b * 4 + grp, 64);
    F8 v; v.h = *(const f16x8*)(G + (size_t)r0 * 128 + li * 8);
    m.h = max8(m.h, v.h);
  }
  m.h = max8(max8(m.h, m2.h), max8(m3.h, m4.h));

  #pragma unroll
  for (int st = 16; st <= 32; st <<= 1) {
    F8 o;
    #pragma unroll
    for (int d = 0; d < 4; ++d) o.i[d] = __shfl_xor(m.i[d], st, 64);
    m.h = max8(m.h, o.h);
  }

  const float dc = dinv[c];
  float v[8];
  float s = 0.f, sq = 0.f;
  #pragma unroll
  for (int j = 0; j < 8; ++j) {
    v[j] = (float)m.h[j] * dc + bias[li * 8 + j];
    s += v[j]; sq += v[j] * v[j];
  }

  if constexpr (MODE == 2) {
    if (grp == 0) {
      f16x8 xv = *(const f16x8*)(xg + (size_t)c * 160 + li * 8);
      f16x8 uv = *(const f16x8*)(u  + (size_t)c * 128 + li * 8);
      float o[8];
      #pragma unroll
      for (int j = 0; j < 8; ++j) o[j] = (float)xv[j] + v[j] * (float)uv[j];
      float* op = (float*)out + (size_t)c * 128 + li * 8;
      *(float4*)op       = make_float4(o[0], o[1], o[2], o[3]);
      *(float4*)(op + 4) = make_float4(o[4], o[5], o[6], o[7]);
    }
  } else {
    #pragma unroll
    for (int st = 1; st <= 8; st <<= 1) {
      s  += __shfl_xor(s, st, 64);
      sq += __shfl_xor(sq, st, 64);
    }
    float mu  = s * (1.0f / 128.0f);
    float var = sq * (1.0f / 128.0f) - mu * mu;
    float rstd = rsqrtf(var + 1e-5f);
    if (grp == 0) {
      f16x8 ov;
      #pragma unroll
      for (int j = 0; j < 8; ++j) {
        float o = (v[j] - mu) * rstd * gamma[li * 8 + j] + beta[li * 8 + j];
        if constexpr (MODE == 0) o = fmaxf(o, 0.0f);
        ov[j] = (f16)o;
      }
      *(f16x8*)((f16*)out + (size_t)c * 128 + li * 8) = ov;
    }
  }
}

extern "C" void kernel_launch(void* const* d_in, const int* in_sizes, int n_in,
                              void* d_out, int out_size, void* d_ws, size_t ws_size,
                              hipStream_t stream) {
  (void)n_in; (void)out_size; (void)ws_size;
  const float* x       = (const float*)d_in[0];
  const int*   ei      = (const int*)d_in[1];
  const float* initial = (const float*)d_in[2];
  const float* Wf1 = (const float*)d_in[3];  const float* bf1 = (const float*)d_in[4];
  const float* Wf2 = (const float*)d_in[5];  const float* bf2 = (const float*)d_in[6];
  const float* Wu1 = (const float*)d_in[7];  const float* bu1 = (const float*)d_in[8];
  const float* Wu2 = (const float*)d_in[9];  const float* bu2 = (const float*)d_in[10];
  const float* Wc1 = (const float*)d_in[11]; const float* bc1 = (const float*)d_in[12];
  const float* Wc2 = (const float*)d_in[13]; const float* bc2 = (const float*)d_in[14];
  const float* Wc3 = (const float*)d_in[15]; const float* bc3 = (const float*)d_in[16];
  const float* Wc4 = (const float*)d_in[17]; const float* bc4 = (const float*)d_in[18];
  const float* Wco = (const float*)d_in[19]; const float* bco = (const float*)d_in[20];
  const float* g3  = (const float*)d_in[21]; const float* bn3 = (const float*)d_in[22];
  const float* g6  = (const float*)d_in[23]; const float* bn6 = (const float*)d_in[24];
  const float* g7  = (const float*)d_in[25]; const float* bn7 = (const float*)d_in[26];

  const int N  = in_sizes[0] / HC;   // 100000
  const int E  = in_sizes[1] / 2;    // 1600000
  const int NG = N - NIO;            // 99872
  const int NP = N + 128;            // padded rows for OOB-safe A-frag loads
  const int NB = (N + 127) / 128;    // 782 coarse buckets
  const int NSEG = 8 * SUBB;         // 64 append segments per bucket

  char* w = (char*)d_ws;
  auto carve = [&](size_t bytes) {
    char* p = w; w += (bytes + 255) & ~(size_t)255; return p;
  };
  int*      bcnt   = (int*)     carve((size_t)NB * NSEG * 4);
  unsigned* bucket = (unsigned*)carve((size_t)NB * NSEG * BCAP_S * 4);  // 25.6 MB
  int*      ncnt   = (int*)     carve((size_t)N * 4);
  int*      dense  = (int*)     carve((size_t)N * DENSW * 4);      // 25.6 MB
  float*    dinv   = (float*)   carve((size_t)N * 4);
  f16*      x16    = (f16*)     carve((size_t)NP * 160 * 2);
  f16*      xg     = (f16*)     carve((size_t)NP * 160 * 2);
  f16*      u      = (f16*)     carve((size_t)N  * 128 * 2);
  f16*      G      = (f16*)     carve((size_t)N  * 128 * 2);
  f16*      H      = (f16*)     carve((size_t)NP * 128 * 2);
  f16*      Wt_f1  = (f16*)     carve(160 * 128 * 2);
  f16*      Wt_f2  = (f16*)     carve(128 * 144 * 2);
  f16*      Wt_u1  = (f16*)     carve(160 * 128 * 2);
  f16*      Wt_u2  = (f16*)     carve(128 * 128 * 2);
  f16*      Wt_c1  = (f16*)     carve(160 * 128 * 2);
  f16*      Wt_c2  = (f16*)     carve(128 * 128 * 2);
  f16*      Wt_c3  = (f16*)     carve(128 * 128 * 2);
  f16*      Wt_c4  = (f16*)     carve(128 * 128 * 2);
  f16*      Wt_co  = (f16*)     carve(128 * 128 * 2);

  const int* erow = ei;
  const int* ecol = ei + E;

  const int gE  = (E + 255) / 256;
  const int gM  = (N + 127) / 128;
  const int gM64 = (N + 63) / 64;
  const int gA  = (N + 3) / 4;

  // fused prep: xprep (vectorized) + wprep + bcnt zero in ONE launch
  WAll wa;
  wa.m[0] = {Wf1, Wt_f1, HC,  HID, 160, 128};
  wa.m[1] = {Wf2, Wt_f2, HID, HC,  128, 144};
  wa.m[2] = {Wu1, Wt_u1, HC,  HID, 160, 128};
  wa.m[3] = {Wu2, Wt_u2, HID, HID, 128, 128};
  wa.m[4] = {Wc1, Wt_c1, HC,  HID, 160, 128};
  wa.m[5] = {Wc2, Wt_c2, HID, HID, 128, 128};
  wa.m[6] = {Wc3, Wt_c3, HID, HID, 128, 128};
  wa.m[7] = {Wc4, Wt_c4, HID, HID, 128, 128};
  wa.m[8] = {Wco, Wt_co, HID, HID, 128, 128};
  const int gX = (N * 20 + 255) / 256;
  const int gZ = (NB * NSEG + 255) / 256;
  prep_kernel<<<gX + 90 + gZ, 256, 0, stream>>>(x, x16, xg, N, wa, bcnt, NB * NSEG, gX);

  // graph build (two-level binning)
  binscatter_kernel<<<gE, 256, 0, stream>>>(erow, ecol, bcnt, bucket, E, NB);
  build_kernel<<<NB, 256, 0, stream>>>(bcnt, bucket, ncnt, dense, dinv, N, NB);

  // forget gate (f1+f2 fused): xg = mix(sigm(sigm(x@Wf1+bf1)@Wf2+bf2))
  mm_fused<160, 160, 144, 130, 1><<<gM, 256, 0, stream>>>(
      x16, Wt_f1, Wt_f2, bf1, bf2, xg, x16, initial, N, NG);
  // update gate (u1+u2 fused): u = sigm(sigm(xg@Wu1+bu1)@Wu2+bu2)
  mm_fused<160, 160, 128, 128, 0><<<gM, 256, 0, stream>>>(
      xg, Wt_u1, Wt_u2, bu1, bu2, u, nullptr, nullptr, N, NG);

  // gcn1: relu(LN(..., g3, bn3))   -- 64-row tiles for TLP
  mm_mfma<160, 160, 128, 128, 2, 64><<<gM64, 256, 0, stream>>>(xg, Wt_c1, nullptr, G, dinv, nullptr, nullptr, N, NG);
  agg_kernel<0><<<gA, 256, 0, stream>>>(G, ncnt, dense, dinv, bc1, g3, bn3, nullptr, nullptr, H, N);
  // gcn2: LN(..., g3, bn3)
  mm_mfma<128, 128, 128, 128, 2, 64><<<gM64, 256, 0, stream>>>(H, Wt_c2, nullptr, G, dinv, nullptr, nullptr, N, NG);
  agg_kernel<1><<<gA, 256, 0, stream>>>(G, ncnt, dense, dinv, bc2, g3, bn3, nullptr, nullptr, H, N);
  // gcn3: LN(..., g6, bn6)
  mm_mfma<128, 128, 128, 128, 2, 64><<<gM64, 256, 0, stream>>>(H, Wt_c3, nullptr, G, dinv, nullptr, nullptr, N, NG);
  agg_kernel<1><<<gA, 256, 0, stream>>>(G, ncnt, dense, dinv, bc3, g6, bn6, nullptr, nullptr, H, N);
  // gcn4: LN(..., g7, bn7)
  mm_mfma<128, 128, 128, 128, 2, 64><<<gM64, 256, 0, stream>>>(H, Wt_c4, nullptr, G, dinv, nullptr, nullptr, N, NG);
  agg_kernel<1><<<gA, 256, 0, stream>>>(G, ncnt, dense, dinv, bc4, g7, bn7, nullptr, nullptr, H, N);
  // gcn5 + final: out = xg[:, :128] + (agg + bco) * u
  mm_mfma<128, 128, 128, 128, 2, 64><<<gM64, 256, 0, stream>>>(H, Wt_co, nullptr, G, dinv, nullptr, nullptr, N, NG);
  agg_kernel<2><<<gA, 256, 0, stream>>>(G, ncnt, dense, dinv, bco, nullptr, nullptr, xg, u, d_out, N);
}